// Round 11
// baseline (208.746 us; speedup 1.0000x reference)
//
#include <hip/hip_runtime.h>
#include <cstdint>

typedef __attribute__((ext_vector_type(8))) short short8;
typedef __attribute__((ext_vector_type(4))) float f32x4;

// ---------- helpers ----------
__device__ __forceinline__ unsigned short f2bf(float x) {
  unsigned int u = __float_as_uint(x);
  u += 0x7FFFu + ((u >> 16) & 1u);   // round-to-nearest-even
  return (unsigned short)(u >> 16);
}

#define GLOAD16(gsrc, ldst)                                                        \
  __builtin_amdgcn_global_load_lds(                                                \
      (const __attribute__((address_space(1))) void*)(gsrc),                       \
      (__attribute__((address_space(3))) void*)(ldst), 16, 0, 0)

// ---------- 0b. WT[d][k] = bf16(W2[k][d]) ----------
__global__ __launch_bounds__(256) void k_wt(const float* __restrict__ W,
                                            unsigned short* __restrict__ WT) {
  __shared__ float t[64][68];
  const int k0 = blockIdx.y * 64, d0 = blockIdx.x * 64;
  for (int idx = threadIdx.x; idx < 4096; idx += 256) {
    int r = idx >> 6, c = idx & 63;
    t[r][c] = W[(size_t)(k0 + r) * 512 + d0 + c];
  }
  __syncthreads();
  for (int idx = threadIdx.x; idx < 4096; idx += 256) {
    int r = idx >> 6, c = idx & 63;     // r = d-local, c = k-local
    WT[(size_t)(d0 + r) * 512 + k0 + c] = f2bf(t[c][r]);
  }
}

// ---------- gate 1: rpart[t][kc][col][n] = partial (q @ W1[t]) ----------
__global__ __launch_bounds__(256) void k_gate1(const float* __restrict__ q,
                                               const float* __restrict__ W1,
                                               float* __restrict__ rpart) {
  const int c0 = blockIdx.x * 64;
  const int k0 = blockIdx.y * 128;
  const int t  = blockIdx.z;
  const int tid = threadIdx.x;
  const int lane = tid & 63;           // row n
  const int wcs = __builtin_amdgcn_readfirstlane(tid >> 6);
  __shared__ float qs[64][133];
  for (int idx = tid; idx < 2048; idx += 256) {
    int r = idx >> 5, c4 = (idx & 31) * 4;
    float4 f = *(const float4*)&q[(size_t)r * 512 + k0 + c4];
    qs[r][c4 + 0] = f.x; qs[r][c4 + 1] = f.y;
    qs[r][c4 + 2] = f.z; qs[r][c4 + 3] = f.w;
  }
  __syncthreads();
  const float* Wp = W1 + ((size_t)t * 512 + k0) * 1024 + c0 + wcs * 16;
  float acc[16] = {};
  for (int k = 0; k < 128; ++k) {
    float qr = qs[lane][k];
    const float* wr = Wp + (size_t)k * 1024;
    float4 w0 = *(const float4*)(wr);
    float4 w1 = *(const float4*)(wr + 4);
    float4 w2 = *(const float4*)(wr + 8);
    float4 w3 = *(const float4*)(wr + 12);
    acc[0]  = fmaf(qr, w0.x, acc[0]);  acc[1]  = fmaf(qr, w0.y, acc[1]);
    acc[2]  = fmaf(qr, w0.z, acc[2]);  acc[3]  = fmaf(qr, w0.w, acc[3]);
    acc[4]  = fmaf(qr, w1.x, acc[4]);  acc[5]  = fmaf(qr, w1.y, acc[5]);
    acc[6]  = fmaf(qr, w1.z, acc[6]);  acc[7]  = fmaf(qr, w1.w, acc[7]);
    acc[8]  = fmaf(qr, w2.x, acc[8]);  acc[9]  = fmaf(qr, w2.y, acc[9]);
    acc[10] = fmaf(qr, w2.z, acc[10]); acc[11] = fmaf(qr, w2.w, acc[11]);
    acc[12] = fmaf(qr, w3.x, acc[12]); acc[13] = fmaf(qr, w3.y, acc[13]);
    acc[14] = fmaf(qr, w3.z, acc[14]); acc[15] = fmaf(qr, w3.w, acc[15]);
  }
  float* rp = rpart + ((size_t)(t * 4 + blockIdx.y) * 1024 + c0 + wcs * 16) * 64 + lane;
#pragma unroll
  for (int cc = 0; cc < 16; ++cc) rp[(size_t)cc * 64] = acc[cc];
}

// ---------- gate 2: gpart[t][kc][col][n] = partial (relu(r) @ W2[t]) ----------
__global__ __launch_bounds__(256) void k_gate2(const float* __restrict__ rpart,
                                               const float* __restrict__ W2,
                                               float* __restrict__ gpart) {
  const int c0 = blockIdx.x * 64;
  const int k0 = blockIdx.y * 128;
  const int t  = blockIdx.z;
  const int tid = threadIdx.x;
  const int lane = tid & 63;
  const int wcs = __builtin_amdgcn_readfirstlane(tid >> 6);
  __shared__ float qs[64][133];
  for (int idx = tid; idx < 2048; idx += 256) {
    int kl = idx >> 4, n4 = (idx & 15) * 4;
    const float* rp = rpart + ((size_t)t * 4 * 1024 + k0 + kl) * 64 + n4;
    float4 a = *(const float4*)(rp);
    float4 b = *(const float4*)(rp + 65536);
    float4 c = *(const float4*)(rp + 131072);
    float4 d = *(const float4*)(rp + 196608);
    qs[n4 + 0][kl] = fmaxf(a.x + b.x + c.x + d.x, 0.f);
    qs[n4 + 1][kl] = fmaxf(a.y + b.y + c.y + d.y, 0.f);
    qs[n4 + 2][kl] = fmaxf(a.z + b.z + c.z + d.z, 0.f);
    qs[n4 + 3][kl] = fmaxf(a.w + b.w + c.w + d.w, 0.f);
  }
  __syncthreads();
  const float* Wp = W2 + ((size_t)t << 20) + (size_t)k0 * 1024 + c0 + wcs * 16;
  float acc[16] = {};
  for (int k = 0; k < 128; ++k) {
    float qr = qs[lane][k];
    const float* wr = Wp + (size_t)k * 1024;
    float4 w0 = *(const float4*)(wr);
    float4 w1 = *(const float4*)(wr + 4);
    float4 w2 = *(const float4*)(wr + 8);
    float4 w3 = *(const float4*)(wr + 12);
    acc[0]  = fmaf(qr, w0.x, acc[0]);  acc[1]  = fmaf(qr, w0.y, acc[1]);
    acc[2]  = fmaf(qr, w0.z, acc[2]);  acc[3]  = fmaf(qr, w0.w, acc[3]);
    acc[4]  = fmaf(qr, w1.x, acc[4]);  acc[5]  = fmaf(qr, w1.y, acc[5]);
    acc[6]  = fmaf(qr, w1.z, acc[6]);  acc[7]  = fmaf(qr, w1.w, acc[7]);
    acc[8]  = fmaf(qr, w2.x, acc[8]);  acc[9]  = fmaf(qr, w2.y, acc[9]);
    acc[10] = fmaf(qr, w2.z, acc[10]); acc[11] = fmaf(qr, w2.w, acc[11]);
    acc[12] = fmaf(qr, w3.x, acc[12]); acc[13] = fmaf(qr, w3.y, acc[13]);
    acc[14] = fmaf(qr, w3.z, acc[14]); acc[15] = fmaf(qr, w3.w, acc[15]);
  }
  float* gp = gpart + ((size_t)(t * 8 + blockIdx.y) * 1024 + c0 + wcs * 16) * 64 + lane;
#pragma unroll
  for (int cc = 0; cc < 16; ++cc) gp[(size_t)cc * 64] = acc[cc];
}

// ---------- gate fin: sigmoid(sum) * a -> galT/garT ----------
__global__ __launch_bounds__(256) void k_gate_fin(const float* __restrict__ gpart,
                                                  const float* __restrict__ a_type,
                                                  float* __restrict__ galT,
                                                  float* __restrict__ garT) {
  const int t = blockIdx.y;
  const int n = threadIdx.x & 63;
  const int mg = blockIdx.x * 4 + (threadIdx.x >> 6);
  float s = 0.f;
#pragma unroll
  for (int kc = 0; kc < 8; ++kc)
    s += gpart[((size_t)(t * 8 + kc) * 1024 + mg) * 64 + n];
  float g = 1.f / (1.f + __expf(-s));
  float ga = g * a_type[t * 1024 + mg];
  if (mg < 512) galT[((size_t)t * 512 + mg) * 64 + n] = ga;
  else          garT[((size_t)t * 512 + (mg - 512)) * 64 + n] = ga;
}

// ---------- 3. u,v split-d partials ----------
__global__ __launch_bounds__(256) void k_uvp(const float* __restrict__ W,
                                             const float* __restrict__ galT,
                                             const float* __restrict__ garT,
                                             float* __restrict__ upart,
                                             float* __restrict__ vpart) {
  const int k0 = blockIdx.x * 64;
  const int d0 = blockIdx.y * 64;
  const int t  = blockIdx.z;
  const int tid = threadIdx.x;
  const int lane = tid & 63;           // lane = n
  const int wk = (tid >> 6) * 16;      // wave's k-subtile
  __shared__ float gal_s[64][64];      // [d][n]
  __shared__ float gar_s[64][64];
  __shared__ float W_s[64][64];        // [k][d]
  for (int idx = tid; idx < 1024; idx += 256) {
    int d = idx >> 4, n4 = (idx & 15) * 4;
    *(float4*)&gal_s[d][n4] = *(const float4*)&galT[((size_t)t * 512 + d0 + d) * 64 + n4];
    *(float4*)&gar_s[d][n4] = *(const float4*)&garT[((size_t)t * 512 + d0 + d) * 64 + n4];
    int k = idx >> 4, d4 = (idx & 15) * 4;
    *(float4*)&W_s[k][d4] = *(const float4*)&W[((size_t)t * 512 + k0 + k) * 512 + d0 + d4];
  }
  __syncthreads();
  float au[16] = {}, av[16] = {};
  for (int dq = 0; dq < 64; dq += 4) {
    float g1[4], g2[4];
#pragma unroll
    for (int e = 0; e < 4; ++e) { g1[e] = gal_s[dq + e][lane]; g2[e] = gar_s[dq + e][lane]; }
#pragma unroll
    for (int kk = 0; kk < 16; ++kk) {
      float4 wv = *(const float4*)&W_s[wk + kk][dq];
      au[kk] = fmaf(wv.x, g1[0], fmaf(wv.y, g1[1], fmaf(wv.z, g1[2], fmaf(wv.w, g1[3], au[kk]))));
      av[kk] = fmaf(wv.x, g2[0], fmaf(wv.y, g2[1], fmaf(wv.z, g2[2], fmaf(wv.w, g2[3], av[kk]))));
    }
  }
  const size_t ob = ((size_t)((t * 8 + blockIdx.y) * 64 + lane)) * 512 + k0 + wk;
#pragma unroll
  for (int q = 0; q < 4; ++q) {
    *(float4*)&upart[ob + q * 4] = make_float4(au[q*4], au[q*4+1], au[q*4+2], au[q*4+3]);
    *(float4*)&vpart[ob + q * 4] = make_float4(av[q*4], av[q*4+1], av[q*4+2], av[q*4+3]);
  }
}

// ---------- 3b. sum uv partials -> uvbf[n][6][512] bf16 ----------
__global__ __launch_bounds__(256) void k_uvsum(const float* __restrict__ upart,
                                               const float* __restrict__ vpart,
                                               unsigned short* __restrict__ uvbf) {
  const int n = blockIdx.x;
  for (int idx = threadIdx.x; idx < 768; idx += 256) {
    int col = idx >> 7;              // 0..5
    int k4 = (idx & 127) * 4;
    const float* base = (col < 3)
        ? upart + ((size_t)(col * 8) * 64 + n) * 512 + k4
        : vpart + ((size_t)((col - 3) * 8) * 64 + n) * 512 + k4;
    float4 sv = {0.f, 0.f, 0.f, 0.f};
#pragma unroll
    for (int dc = 0; dc < 8; ++dc) {
      float4 t = *(const float4*)(base + (size_t)dc * 32768);
      sv.x += t.x; sv.y += t.y; sv.z += t.z; sv.w += t.w;
    }
    ushort4 o;
    o.x = f2bf(sv.x); o.y = f2bf(sv.y); o.z = f2bf(sv.z); o.w = f2bf(sv.w);
    *(ushort4*)&uvbf[((size_t)n * 6 + col) * 512 + k4] = o;
  }
}

// ---------- 4. k_lrm: single pass over X: f32->bf16 conversion + left/right via MFMA ----------
__global__ __launch_bounds__(256) void k_lrm(const float* __restrict__ x,
                                             const unsigned short* __restrict__ uvbf,
                                             float* __restrict__ left,
                                             float* __restrict__ right,
                                             unsigned short* __restrict__ Xbf) {
  const int n  = blockIdx.y;
  const int i0 = blockIdx.x * 64;
  const int tid = threadIdx.x;
  const int lane = tid & 63, wid = tid >> 6;
  __shared__ unsigned short uvs[16][520];
  __shared__ __attribute__((aligned(16))) char As[4096];

  for (int idx = tid; idx < 16 * 64; idx += 256) {
    int col = idx >> 6, k8 = (idx & 63) * 8;
    ushort4 z0 = {0, 0, 0, 0}, z1 = {0, 0, 0, 0};
    if (col < 6) {
      const unsigned short* p = uvbf + ((size_t)n * 6 + col) * 512 + k8;
      z0 = *(const ushort4*)p;
      z1 = *(const ushort4*)(p + 4);
    }
    *(ushort4*)&uvs[col][k8]     = z0;
    *(ushort4*)&uvs[col][k8 + 4] = z1;
  }
  const int row = tid >> 2, sub = tid & 3;
  const float* gp = x + ((size_t)n * 512 + i0 + row) * 512 + sub * 8;
  unsigned short* xp = Xbf + ((size_t)n * 512 + i0 + row) * 512 + sub * 8;
  const int lds_off = row * 64 + ((sub ^ (row & 3)) << 4);
  const int arow = wid * 16 + (lane & 15);
  const int a_off = arow * 64 + (((lane >> 4) ^ (arow & 3)) << 4);
  f32x4 acc = {0.f, 0.f, 0.f, 0.f};
  float4 f0 = *(const float4*)(gp);
  float4 f1 = *(const float4*)(gp + 4);
  __syncthreads();
  for (int s = 0; s < 16; ++s) {
    uint4 pk;
    pk.x = ((unsigned)f2bf(f0.y) << 16) | f2bf(f0.x);
    pk.y = ((unsigned)f2bf(f0.w) << 16) | f2bf(f0.z);
    pk.z = ((unsigned)f2bf(f1.y) << 16) | f2bf(f1.x);
    pk.w = ((unsigned)f2bf(f1.w) << 16) | f2bf(f1.z);
    if (s < 15) {
      f0 = *(const float4*)(gp + (s + 1) * 32);
      f1 = *(const float4*)(gp + (s + 1) * 32 + 4);
    }
    *(uint4*)(xp + s * 32) = pk;
    *(uint4*)(As + lds_off) = pk;
    __syncthreads();
    short8 a = *(const short8*)(As + a_off);
    short8 b = *(const short8*)&uvs[lane & 15][s * 32 + (lane >> 4) * 8];
    acc = __builtin_amdgcn_mfma_f32_16x16x32_bf16(a, b, acc, 0, 0, 0);
    __syncthreads();
  }
  const int col = lane & 15;
  if (col < 6) {
    float* dst = (col < 3) ? left : right;
    const int t = (col < 3) ? col : col - 3;
    const int i = i0 + wid * 16 + ((lane >> 4) << 2);
    float* p = dst + ((size_t)t * 64 + n) * 512 + i;
    p[0] = acc.x; p[1] = acc.y; p[2] = acc.z; p[3] = acc.w;
  }
}

// ---------- 5. k_z: adj pass -> mb[n][i] (bound-max) and invZ[n][i] ----------
// Row = 16 lanes x 32 j (proven k_smt geometry); no p stores, no transpose,
// no max butterfly (mb = max_t(l_t[i] + max_j r_t[j]) computed in-block).
__global__ __launch_bounds__(256) void k_z(const int* __restrict__ adj,
                                           const float* __restrict__ left,
                                           const float* __restrict__ right,
                                           float* __restrict__ mbg,
                                           float* __restrict__ izg) {
  const int n  = blockIdx.y;
  const int i0 = blockIdx.x * 16;
  const int tid = threadIdx.x;
  const int lane = tid & 63, wid = tid >> 6;
  const int l15 = lane & 15;
  const int il  = wid * 4 + (lane >> 4);     // row 0..15
  __shared__ float rs_s[32][49];
  __shared__ float ls[3][16];
  __shared__ float rmx[3][4];
  float lm0 = -3.0e38f, lm1 = -3.0e38f, lm2 = -3.0e38f;
  for (int idx = tid; idx < 1536; idx += 256) {
    int t = idx >> 9, j = idx & 511;
    float v = right[((size_t)t * 64 + n) * 512 + j];
    rs_s[j & 31][t * 16 + (j >> 5)] = v;
    lm0 = (t == 0) ? fmaxf(lm0, v) : lm0;
    lm1 = (t == 1) ? fmaxf(lm1, v) : lm1;
    lm2 = (t == 2) ? fmaxf(lm2, v) : lm2;
  }
  if (tid < 48) {
    int t = tid >> 4, ii = tid & 15;
    ls[t][ii] = left[((size_t)t * 64 + n) * 512 + i0 + ii];
  }
  for (int off = 32; off > 0; off >>= 1) {
    lm0 = fmaxf(lm0, __shfl_xor(lm0, off));
    lm1 = fmaxf(lm1, __shfl_xor(lm1, off));
    lm2 = fmaxf(lm2, __shfl_xor(lm2, off));
  }
  if (lane == 0) { rmx[0][wid] = lm0; rmx[1][wid] = lm1; rmx[2][wid] = lm2; }
  __syncthreads();
  const float r0m = fmaxf(fmaxf(rmx[0][0], rmx[0][1]), fmaxf(rmx[0][2], rmx[0][3]));
  const float r1m = fmaxf(fmaxf(rmx[1][0], rmx[1][1]), fmaxf(rmx[1][2], rmx[1][3]));
  const float r2m = fmaxf(fmaxf(rmx[2][0], rmx[2][1]), fmaxf(rmx[2][2], rmx[2][3]));
  const float l0 = ls[0][il], l1 = ls[1][il], l2 = ls[2][il];
  const float mb = fmaxf(fmaxf(l0 + r0m, l1 + r1m), l2 + r2m);
  const int* adjb = adj + ((size_t)(n * 512 + i0 + il)) * 512;
  int4 A[4], B[4];
#pragma unroll
  for (int q = 0; q < 4; ++q) {
    const int* p = adjb + q * 128 + l15 * 8;
    A[q] = *(const int4*)p;
    B[q] = *(const int4*)(p + 4);
  }
  const int base0 = ((l15 & 3) * 8) * 49 + (l15 >> 2);
  const float* rsf = (const float*)rs_s;
  float z = 0.f;
#pragma unroll
  for (int q = 0; q < 4; ++q) {
    int tv[8] = {A[q].x, A[q].y, A[q].z, A[q].w, B[q].x, B[q].y, B[q].z, B[q].w};
#pragma unroll
    for (int x = 0; x < 8; ++x) {
      int t = tv[x];
      int tt = (t > 0) ? (t - 1) : 0;
      float lv = (t >= 2) ? ((t == 3) ? l2 : l1) : l0;
      float r = rsf[base0 + tt * 16 + (x * 49 + q * 4)];
      float sv = lv + r;
      sv = (sv >= 0.f) ? sv : 0.2f * sv;
      sv = (t == 0) ? -9.0e15f : sv;
      z += __expf(sv - mb);
    }
  }
#pragma unroll
  for (int k = 1; k <= 8; k <<= 1) z += __shfl_xor(z, k);
  if (l15 == 0) {
    mbg[(size_t)n * 512 + i0 + il] = mb;
    izg[(size_t)n * 512 + i0 + il] = 1.f / z;
  }
}

// ---------- 6. MFMA GEMM1: h2T[n][d][i] = (X[n] @ W2)^T ; 2-phase dbuf pipeline ----------
__global__ __launch_bounds__(256) void k_gemm1(const unsigned short* __restrict__ X,
                                               const unsigned short* __restrict__ WT,
                                               unsigned short* __restrict__ h2T) {
  __shared__ __attribute__((aligned(16))) char smem[34816];  // dbuf 32K | Ct 34.8K union
  char* A0 = smem;
  char* A1 = smem + 8192;
  char* B0 = smem + 16384;
  char* B1 = smem + 24576;
  const int s = blockIdx.x;
  const int n  = ((s >> 7) << 3) | (s & 7);
  const int jj = (s >> 3) & 15;
  const int i0 = (jj >> 2) * 128;
  const int d0 = (jj & 3) * 128;
  const int tid = threadIdx.x;
  const int lane = tid & 63, w = tid >> 6;
  const int wm = w >> 1, wn = w & 1;
  const int srow = tid >> 2;
  const int kbp  = tid & 3;
  f32x4 acc[4][4];
#pragma unroll
  for (int a = 0; a < 4; ++a)
#pragma unroll
    for (int b = 0; b < 4; ++b) acc[a][b] = (f32x4){0.f, 0.f, 0.f, 0.f};

  const size_t xbase = (size_t)n * 262144;
  int ra[4], rb[4];
#pragma unroll
  for (int f = 0; f < 4; ++f) {
    int row = wm * 64 + f * 16 + (lane & 15);
    ra[f] = row * 64 + (((lane >> 4) ^ ((row >> 1) & 3)) << 4);
    int rowb = wn * 64 + f * 16 + (lane & 15);
    rb[f] = rowb * 64 + (((lane >> 4) ^ ((rowb >> 1) & 3)) << 4);
  }
  const int kl0 = (kbp ^ ((srow >> 1) & 3)) * 8;
  const int kl1 = (kbp ^ (((64 + srow) >> 1) & 3)) * 8;
  const unsigned short* xr0 = X + xbase + (size_t)(i0 + srow) * 512 + kl0;
  const unsigned short* xr1 = X + xbase + (size_t)(i0 + 64 + srow) * 512 + kl1;
  const unsigned short* wr0 = WT + (size_t)(d0 + srow) * 512 + kl0;
  const unsigned short* wr1 = WT + (size_t)(d0 + 64 + srow) * 512 + kl1;

  GLOAD16(xr0, A0 + tid * 16);
  GLOAD16(xr1, A0 + 4096 + tid * 16);
  GLOAD16(wr0, B0 + tid * 16);
  GLOAD16(wr1, B0 + 4096 + tid * 16);

#pragma unroll 2
  for (int t = 0; t < 16; ++t) {
    char* Ac = (t & 1) ? A1 : A0;
    char* Bc = (t & 1) ? B1 : B0;
    if (t < 15) {
      char* An = (t & 1) ? A0 : A1;
      char* Bn = (t & 1) ? B0 : B1;
      const int kc = (t + 1) * 32;
      GLOAD16(xr0 + kc, An + tid * 16);
      GLOAD16(xr1 + kc, An + 4096 + tid * 16);
      GLOAD16(wr0 + kc, Bn + tid * 16);
      GLOAD16(wr1 + kc, Bn + 4096 + tid * 16);
      asm volatile("s_waitcnt vmcnt(4)" ::: "memory");
    } else {
      asm volatile("s_waitcnt vmcnt(0)" ::: "memory");
    }
    __builtin_amdgcn_s_barrier();
    short8 a[4], b[4];
#pragma unroll
    for (int f = 0; f < 4; ++f) a[f] = *(const short8*)(Ac + ra[f]);
#pragma unroll
    for (int f = 0; f < 4; ++f) b[f] = *(const short8*)(Bc + rb[f]);
#pragma unroll
    for (int mf = 0; mf < 4; ++mf)
#pragma unroll
      for (int nf = 0; nf < 4; ++nf)
        acc[mf][nf] = __builtin_amdgcn_mfma_f32_16x16x32_bf16(a[mf], b[nf], acc[mf][nf], 0, 0, 0);
    asm volatile("s_waitcnt lgkmcnt(0)" ::: "memory");
    __builtin_amdgcn_sched_barrier(0);
    __builtin_amdgcn_s_barrier();
  }
  unsigned short (*Ct)[136] = (unsigned short (*)[136])smem;
#pragma unroll
  for (int mf = 0; mf < 4; ++mf)
#pragma unroll
    for (int nf = 0; nf < 4; ++nf) {
      f32x4 vv = acc[mf][nf];
      int dl = wn * 64 + nf * 16 + (lane & 15);
      int il = wm * 64 + mf * 16 + ((lane >> 4) << 2);
      ushort4 pk;
      pk.x = f2bf(vv.x); pk.y = f2bf(vv.y); pk.z = f2bf(vv.z); pk.w = f2bf(vv.w);
      *(ushort4*)&Ct[dl][il] = pk;
    }
  __syncthreads();
  const size_t obase = xbase + (size_t)d0 * 512 + i0;
#pragma unroll
  for (int q = 0; q < 8; ++q) {
    int f = q * 2048 + tid * 8;
    int dl = f >> 7, il = f & 127;
    *(uint4*)&h2T[obase + (size_t)dl * 512 + il] = *(const uint4*)&Ct[dl][il];
  }
}

// ---------- 7. MFMA GEMM2-fused: out[n][j][d] = sum_i p[i][j] * h2[i][d] ----------
// A-operand (p^T tile [128 j][32 i]) generated on the fly from adj + left/right
// + mb/invZ; B (h2T) staged via 2-phase gload_lds as before. No coefsT buffer.
__global__ __launch_bounds__(256) void k_gemm2f(const int* __restrict__ adj,
                                                const float* __restrict__ left,
                                                const float* __restrict__ right,
                                                const float* __restrict__ mbg,
                                                const float* __restrict__ izg,
                                                const unsigned short* __restrict__ H2T,
                                                float* __restrict__ out) {
  __shared__ __attribute__((aligned(16))) char As[8192];      // A tile: 128 rows x 64 B
  __shared__ __attribute__((aligned(16))) char B0[8192];
  __shared__ __attribute__((aligned(16))) char B1[8192];
  __shared__ float lmb[5][512];                               // l1,l2,l3,mb,invZ
  const int s = blockIdx.x;
  const int n  = ((s >> 7) << 3) | (s & 7);
  const int jj = (s >> 3) & 15;
  const int j0 = (jj >> 2) * 128;
  const int d0 = (jj & 3) * 128;
  const int tid = threadIdx.x;
  const int lane = tid & 63, w = tid >> 6;
  const int wm = w >> 1, wn = w & 1;
  const int srow = tid >> 2;
  const int kbp  = tid & 3;
  // stage lmb table
  for (int idx = tid; idx < 2560; idx += 256) {
    int rr = idx >> 9, i = idx & 511;
    float v;
    if (rr < 3)      v = left[((size_t)rr * 64 + n) * 512 + i];
    else if (rr == 3) v = mbg[(size_t)n * 512 + i];
    else              v = izg[(size_t)n * 512 + i];
    lmb[rr][i] = v;
  }
  // A-gen mapping: thread -> (row aj, i-half ih)
  const int aj = tid & 127;
  const int ih = tid >> 7;
  const float r1 = right[((size_t)0 * 64 + n) * 512 + j0 + aj];
  const float r2 = right[((size_t)1 * 64 + n) * 512 + j0 + aj];
  const float r3 = right[((size_t)2 * 64 + n) * 512 + j0 + aj];
  const int sxor = (aj >> 1) & 3;
  const int wa0 = aj * 64 + (((2 * ih + 0) ^ sxor) << 4);
  const int wa1 = aj * 64 + (((2 * ih + 1) ^ sxor) << 4);
  const int* adjp = adj + (size_t)n * 262144 + j0 + aj;

  f32x4 acc[4][4];
#pragma unroll
  for (int a = 0; a < 4; ++a)
#pragma unroll
    for (int b = 0; b < 4; ++b) acc[a][b] = (f32x4){0.f, 0.f, 0.f, 0.f};
  int ra[4], rb[4];
#pragma unroll
  for (int f = 0; f < 4; ++f) {
    int row = wm * 64 + f * 16 + (lane & 15);
    ra[f] = row * 64 + (((lane >> 4) ^ ((row >> 1) & 3)) << 4);
    int rowb = wn * 64 + f * 16 + (lane & 15);
    rb[f] = rowb * 64 + (((lane >> 4) ^ ((rowb >> 1) & 3)) << 4);
  }
  const int kl0 = (kbp ^ ((srow >> 1) & 3)) * 8;
  const int kl1 = (kbp ^ (((64 + srow) >> 1) & 3)) * 8;
  const size_t base = (size_t)n * 262144;
  const unsigned short* hr0 = H2T + base + (size_t)(d0 + srow) * 512 + kl0;
  const unsigned short* hr1 = H2T + base + (size_t)(d0 + 64 + srow) * 512 + kl1;

  // prologue: adj(0) into regs, B(0) into LDS
  int adjc[16];
#pragma unroll
  for (int m = 0; m < 16; ++m) adjc[m] = adjp[(size_t)(ih * 16 + m) * 512];
  GLOAD16(hr0, B0 + tid * 16);
  GLOAD16(hr1, B0 + 4096 + tid * 16);
  __syncthreads();   // lmb table staged

  for (int t = 0; t < 16; ++t) {
    char* Bc = (t & 1) ? B1 : B0;
    asm volatile("s_waitcnt vmcnt(0)" ::: "memory");   // adj(t) regs + B(t) LDS landed
    // generate A(t): p = exp(s - mb) * invZ, bf16, swizzled store
    uint4 pk0, pk1;
    {
      unsigned pw[8];
#pragma unroll
      for (int h = 0; h < 8; ++h) {
        unsigned lo = 0, hi = 0;
#pragma unroll
        for (int e = 0; e < 2; ++e) {
          int m = h * 2 + e;
          int tv = adjc[m];
          int tt = (tv > 0) ? (tv - 1) : 0;
          float rv = (tv == 1) ? r1 : ((tv == 2) ? r2 : r3);
          int ig = t * 32 + ih * 16 + m;
          float lv = lmb[tt][ig];
          float sv = lv + rv;
          sv = (sv >= 0.f) ? sv : 0.2f * sv;
          sv = (tv == 0) ? -9.0e15f : sv;
          float p = __expf(sv - lmb[3][ig]) * lmb[4][ig];
          if (e == 0) lo = f2bf(p); else hi = f2bf(p);
        }
        pw[h] = (hi << 16) | lo;
      }
      pk0.x = pw[0]; pk0.y = pw[1]; pk0.z = pw[2]; pk0.w = pw[3];
      pk1.x = pw[4]; pk1.y = pw[5]; pk1.z = pw[6]; pk1.w = pw[7];
    }
    *(uint4*)(As + wa0) = pk0;
    *(uint4*)(As + wa1) = pk1;
    asm volatile("s_waitcnt lgkmcnt(0)" ::: "memory");
    __builtin_amdgcn_s_barrier();
    // issue next tile's loads (hide under MFMA phase)
    if (t < 15) {
#pragma unroll
      for (int m = 0; m < 16; ++m)
        adjc[m] = adjp[(size_t)((t + 1) * 32 + ih * 16 + m) * 512];
      char* Bn = (t & 1) ? B0 : B1;
      GLOAD16(hr0 + (t + 1) * 32, Bn + tid * 16);
      GLOAD16(hr1 + (t + 1) * 32, Bn + 4096 + tid * 16);
    }
    short8 a[4], b[4];
#pragma unroll
    for (int f = 0; f < 4; ++f) a[f] = *(const short8*)(As + ra[f]);
#pragma unroll
    for (int f = 0; f < 4; ++f) b[f] = *(const short8*)(Bc + rb[f]);
#pragma unroll
    for (int mf = 0; mf < 4; ++mf)
#pragma unroll
      for (int nf = 0; nf < 4; ++nf)
        acc[mf][nf] = __builtin_amdgcn_mfma_f32_16x16x32_bf16(a[mf], b[nf], acc[mf][nf], 0, 0, 0);
    asm volatile("s_waitcnt lgkmcnt(0)" ::: "memory");
    __builtin_amdgcn_sched_barrier(0);
    __builtin_amdgcn_s_barrier();
  }
  const int jb = j0 + wm * 64 + (lane >> 4) * 4;
  const int db = d0 + wn * 64 + (lane & 15);
#pragma unroll
  for (int mf = 0; mf < 4; ++mf)
#pragma unroll
    for (int nf = 0; nf < 4; ++nf) {
      f32x4 vv = acc[mf][nf];
      float* op = out + base + (size_t)(jb + mf * 16) * 512 + db + nf * 16;
      op[0]    = vv.x;
      op[512]  = vv.y;
      op[1024] = vv.z;
      op[1536] = vv.w;
    }
}

extern "C" void kernel_launch(void* const* d_in, const int* in_sizes, int n_in,
                              void* d_out, int out_size, void* d_ws, size_t ws_size,
                              hipStream_t stream) {
  const float* input  = (const float*)d_in[0];
  const int*   adj    = (const int*)d_in[1];
  const float* query  = (const float*)d_in[3];
  const float* W_type = (const float*)d_in[4];
  const float* a_type = (const float*)d_in[5];
  const float* W1     = (const float*)d_in[6];
  const float* W2     = (const float*)d_in[7];
  float* out = (float*)d_out;

  char* ws = (char*)d_ws;
  float* galT  = (float*)(ws);                              //  393,216 B
  float* garT  = (float*)(ws + 393216);                     //  393,216 B
  unsigned short* uvbf = (unsigned short*)(ws + 786432);    //  393,216 B
  float* left  = (float*)(ws + 1179648);                    //  393,216 B
  float* right = (float*)(ws + 1572864);                    //  393,216 B
  unsigned short* Xbf = (unsigned short*)(ws + 2359296);    // 33,554,432 B
  unsigned short* h2T = (unsigned short*)(ws + 35913728);   // 33,554,432 B
  // partials alias h2T's region: all dead before k_gemm1 writes h2T
  float* rpart = (float*)(ws + 35913728);                   //  3,145,728 B
  float* gpart = (float*)(ws + 39059456);                   //  6,291,456 B
  float* upart = (float*)(ws + 45350912);                   //  3,145,728 B
  float* vpart = (float*)(ws + 48496640);                   //  3,145,728 B
  unsigned short* WT  = (unsigned short*)(ws + 69468160);   //    524,288 B
  float* mbg = (float*)(ws + 69992448);                     //    131,072 B
  float* izg = (float*)(ws + 70123520);                     //    131,072 B
  // total ws use: 70,254,592 B

  k_wt      <<<dim3(8, 8),      256, 0, stream>>>(W_type + (size_t)2 * 262144, WT);
  k_gate1   <<<dim3(16, 4, 3),  256, 0, stream>>>(query, W1, rpart);
  k_gate2   <<<dim3(16, 8, 3),  256, 0, stream>>>(rpart, W2, gpart);
  k_gate_fin<<<dim3(256, 3),    256, 0, stream>>>(gpart, a_type, galT, garT);
  k_uvp     <<<dim3(8, 8, 3),   256, 0, stream>>>(W_type, galT, garT, upart, vpart);
  k_uvsum   <<<dim3(64),        256, 0, stream>>>(upart, vpart, uvbf);
  k_lrm     <<<dim3(8, 64),     256, 0, stream>>>(input, uvbf, left, right, Xbf);
  k_z       <<<dim3(32, 64),    256, 0, stream>>>(adj, left, right, mbg, izg);
  k_gemm1   <<<dim3(1024),      256, 0, stream>>>(Xbf, WT, h2T);
  k_gemm2f  <<<dim3(1024),      256, 0, stream>>>(adj, left, right, mbg, izg, h2T, out);
}

// Round 12
// 199.706 us; speedup vs baseline: 1.0453x; 1.0453x over previous
//
#include <hip/hip_runtime.h>
#include <cstdint>

typedef __attribute__((ext_vector_type(8))) short short8;
typedef __attribute__((ext_vector_type(4))) float f32x4;

// ---------- helpers ----------
__device__ __forceinline__ unsigned short f2bf(float x) {
  unsigned int u = __float_as_uint(x);
  u += 0x7FFFu + ((u >> 16) & 1u);   // round-to-nearest-even
  return (unsigned short)(u >> 16);
}

#define GLOAD16(gsrc, ldst)                                                        \
  __builtin_amdgcn_global_load_lds(                                                \
      (const __attribute__((address_space(1))) void*)(gsrc),                       \
      (__attribute__((address_space(3))) void*)(ldst), 16, 0, 0)

// ---------- 0b. WT[d][k] = bf16(W2[k][d]) ----------
__global__ __launch_bounds__(256) void k_wt(const float* __restrict__ W,
                                            unsigned short* __restrict__ WT) {
  __shared__ float t[64][68];
  const int k0 = blockIdx.y * 64, d0 = blockIdx.x * 64;
  for (int idx = threadIdx.x; idx < 4096; idx += 256) {
    int r = idx >> 6, c = idx & 63;
    t[r][c] = W[(size_t)(k0 + r) * 512 + d0 + c];
  }
  __syncthreads();
  for (int idx = threadIdx.x; idx < 4096; idx += 256) {
    int r = idx >> 6, c = idx & 63;
    WT[(size_t)(d0 + r) * 512 + k0 + c] = f2bf(t[c][r]);
  }
}

// ---------- gate 1 ----------
__global__ __launch_bounds__(256) void k_gate1(const float* __restrict__ q,
                                               const float* __restrict__ W1,
                                               float* __restrict__ rpart) {
  const int c0 = blockIdx.x * 64;
  const int k0 = blockIdx.y * 128;
  const int t  = blockIdx.z;
  const int tid = threadIdx.x;
  const int lane = tid & 63;
  const int wcs = __builtin_amdgcn_readfirstlane(tid >> 6);
  __shared__ float qs[64][133];
  for (int idx = tid; idx < 2048; idx += 256) {
    int r = idx >> 5, c4 = (idx & 31) * 4;
    float4 f = *(const float4*)&q[(size_t)r * 512 + k0 + c4];
    qs[r][c4 + 0] = f.x; qs[r][c4 + 1] = f.y;
    qs[r][c4 + 2] = f.z; qs[r][c4 + 3] = f.w;
  }
  __syncthreads();
  const float* Wp = W1 + ((size_t)t * 512 + k0) * 1024 + c0 + wcs * 16;
  float acc[16] = {};
  for (int k = 0; k < 128; ++k) {
    float qr = qs[lane][k];
    const float* wr = Wp + (size_t)k * 1024;
    float4 w0 = *(const float4*)(wr);
    float4 w1 = *(const float4*)(wr + 4);
    float4 w2 = *(const float4*)(wr + 8);
    float4 w3 = *(const float4*)(wr + 12);
    acc[0]  = fmaf(qr, w0.x, acc[0]);  acc[1]  = fmaf(qr, w0.y, acc[1]);
    acc[2]  = fmaf(qr, w0.z, acc[2]);  acc[3]  = fmaf(qr, w0.w, acc[3]);
    acc[4]  = fmaf(qr, w1.x, acc[4]);  acc[5]  = fmaf(qr, w1.y, acc[5]);
    acc[6]  = fmaf(qr, w1.z, acc[6]);  acc[7]  = fmaf(qr, w1.w, acc[7]);
    acc[8]  = fmaf(qr, w2.x, acc[8]);  acc[9]  = fmaf(qr, w2.y, acc[9]);
    acc[10] = fmaf(qr, w2.z, acc[10]); acc[11] = fmaf(qr, w2.w, acc[11]);
    acc[12] = fmaf(qr, w3.x, acc[12]); acc[13] = fmaf(qr, w3.y, acc[13]);
    acc[14] = fmaf(qr, w3.z, acc[14]); acc[15] = fmaf(qr, w3.w, acc[15]);
  }
  float* rp = rpart + ((size_t)(t * 4 + blockIdx.y) * 1024 + c0 + wcs * 16) * 64 + lane;
#pragma unroll
  for (int cc = 0; cc < 16; ++cc) rp[(size_t)cc * 64] = acc[cc];
}

// ---------- gate 2 ----------
__global__ __launch_bounds__(256) void k_gate2(const float* __restrict__ rpart,
                                               const float* __restrict__ W2,
                                               float* __restrict__ gpart) {
  const int c0 = blockIdx.x * 64;
  const int k0 = blockIdx.y * 128;
  const int t  = blockIdx.z;
  const int tid = threadIdx.x;
  const int lane = tid & 63;
  const int wcs = __builtin_amdgcn_readfirstlane(tid >> 6);
  __shared__ float qs[64][133];
  for (int idx = tid; idx < 2048; idx += 256) {
    int kl = idx >> 4, n4 = (idx & 15) * 4;
    const float* rp = rpart + ((size_t)t * 4 * 1024 + k0 + kl) * 64 + n4;
    float4 a = *(const float4*)(rp);
    float4 b = *(const float4*)(rp + 65536);
    float4 c = *(const float4*)(rp + 131072);
    float4 d = *(const float4*)(rp + 196608);
    qs[n4 + 0][kl] = fmaxf(a.x + b.x + c.x + d.x, 0.f);
    qs[n4 + 1][kl] = fmaxf(a.y + b.y + c.y + d.y, 0.f);
    qs[n4 + 2][kl] = fmaxf(a.z + b.z + c.z + d.z, 0.f);
    qs[n4 + 3][kl] = fmaxf(a.w + b.w + c.w + d.w, 0.f);
  }
  __syncthreads();
  const float* Wp = W2 + ((size_t)t << 20) + (size_t)k0 * 1024 + c0 + wcs * 16;
  float acc[16] = {};
  for (int k = 0; k < 128; ++k) {
    float qr = qs[lane][k];
    const float* wr = Wp + (size_t)k * 1024;
    float4 w0 = *(const float4*)(wr);
    float4 w1 = *(const float4*)(wr + 4);
    float4 w2 = *(const float4*)(wr + 8);
    float4 w3 = *(const float4*)(wr + 12);
    acc[0]  = fmaf(qr, w0.x, acc[0]);  acc[1]  = fmaf(qr, w0.y, acc[1]);
    acc[2]  = fmaf(qr, w0.z, acc[2]);  acc[3]  = fmaf(qr, w0.w, acc[3]);
    acc[4]  = fmaf(qr, w1.x, acc[4]);  acc[5]  = fmaf(qr, w1.y, acc[5]);
    acc[6]  = fmaf(qr, w1.z, acc[6]);  acc[7]  = fmaf(qr, w1.w, acc[7]);
    acc[8]  = fmaf(qr, w2.x, acc[8]);  acc[9]  = fmaf(qr, w2.y, acc[9]);
    acc[10] = fmaf(qr, w2.z, acc[10]); acc[11] = fmaf(qr, w2.w, acc[11]);
    acc[12] = fmaf(qr, w3.x, acc[12]); acc[13] = fmaf(qr, w3.y, acc[13]);
    acc[14] = fmaf(qr, w3.z, acc[14]); acc[15] = fmaf(qr, w3.w, acc[15]);
  }
  float* gp = gpart + ((size_t)(t * 8 + blockIdx.y) * 1024 + c0 + wcs * 16) * 64 + lane;
#pragma unroll
  for (int cc = 0; cc < 16; ++cc) gp[(size_t)cc * 64] = acc[cc];
}

// ---------- gate fin ----------
__global__ __launch_bounds__(256) void k_gate_fin(const float* __restrict__ gpart,
                                                  const float* __restrict__ a_type,
                                                  float* __restrict__ galT,
                                                  float* __restrict__ garT) {
  const int t = blockIdx.y;
  const int n = threadIdx.x & 63;
  const int mg = blockIdx.x * 4 + (threadIdx.x >> 6);
  float s = 0.f;
#pragma unroll
  for (int kc = 0; kc < 8; ++kc)
    s += gpart[((size_t)(t * 8 + kc) * 1024 + mg) * 64 + n];
  float g = 1.f / (1.f + __expf(-s));
  float ga = g * a_type[t * 1024 + mg];
  if (mg < 512) galT[((size_t)t * 512 + mg) * 64 + n] = ga;
  else          garT[((size_t)t * 512 + (mg - 512)) * 64 + n] = ga;
}

// ---------- u,v split-d partials ----------
__global__ __launch_bounds__(256) void k_uvp(const float* __restrict__ W,
                                             const float* __restrict__ galT,
                                             const float* __restrict__ garT,
                                             float* __restrict__ upart,
                                             float* __restrict__ vpart) {
  const int k0 = blockIdx.x * 64;
  const int d0 = blockIdx.y * 64;
  const int t  = blockIdx.z;
  const int tid = threadIdx.x;
  const int lane = tid & 63;
  const int wk = (tid >> 6) * 16;
  __shared__ float gal_s[64][64];
  __shared__ float gar_s[64][64];
  __shared__ float W_s[64][64];
  for (int idx = tid; idx < 1024; idx += 256) {
    int d = idx >> 4, n4 = (idx & 15) * 4;
    *(float4*)&gal_s[d][n4] = *(const float4*)&galT[((size_t)t * 512 + d0 + d) * 64 + n4];
    *(float4*)&gar_s[d][n4] = *(const float4*)&garT[((size_t)t * 512 + d0 + d) * 64 + n4];
    int k = idx >> 4, d4 = (idx & 15) * 4;
    *(float4*)&W_s[k][d4] = *(const float4*)&W[((size_t)t * 512 + k0 + k) * 512 + d0 + d4];
  }
  __syncthreads();
  float au[16] = {}, av[16] = {};
  for (int dq = 0; dq < 64; dq += 4) {
    float g1[4], g2[4];
#pragma unroll
    for (int e = 0; e < 4; ++e) { g1[e] = gal_s[dq + e][lane]; g2[e] = gar_s[dq + e][lane]; }
#pragma unroll
    for (int kk = 0; kk < 16; ++kk) {
      float4 wv = *(const float4*)&W_s[wk + kk][dq];
      au[kk] = fmaf(wv.x, g1[0], fmaf(wv.y, g1[1], fmaf(wv.z, g1[2], fmaf(wv.w, g1[3], au[kk]))));
      av[kk] = fmaf(wv.x, g2[0], fmaf(wv.y, g2[1], fmaf(wv.z, g2[2], fmaf(wv.w, g2[3], av[kk]))));
    }
  }
  const size_t ob = ((size_t)((t * 8 + blockIdx.y) * 64 + lane)) * 512 + k0 + wk;
#pragma unroll
  for (int q = 0; q < 4; ++q) {
    *(float4*)&upart[ob + q * 4] = make_float4(au[q*4], au[q*4+1], au[q*4+2], au[q*4+3]);
    *(float4*)&vpart[ob + q * 4] = make_float4(av[q*4], av[q*4+1], av[q*4+2], av[q*4+3]);
  }
}

// ---------- sum uv partials -> uvbf ----------
__global__ __launch_bounds__(256) void k_uvsum(const float* __restrict__ upart,
                                               const float* __restrict__ vpart,
                                               unsigned short* __restrict__ uvbf) {
  const int n = blockIdx.x;
  for (int idx = threadIdx.x; idx < 768; idx += 256) {
    int col = idx >> 7;
    int k4 = (idx & 127) * 4;
    const float* base = (col < 3)
        ? upart + ((size_t)(col * 8) * 64 + n) * 512 + k4
        : vpart + ((size_t)((col - 3) * 8) * 64 + n) * 512 + k4;
    float4 sv = {0.f, 0.f, 0.f, 0.f};
#pragma unroll
    for (int dc = 0; dc < 8; ++dc) {
      float4 t = *(const float4*)(base + (size_t)dc * 32768);
      sv.x += t.x; sv.y += t.y; sv.z += t.z; sv.w += t.w;
    }
    ushort4 o;
    o.x = f2bf(sv.x); o.y = f2bf(sv.y); o.z = f2bf(sv.z); o.w = f2bf(sv.w);
    *(ushort4*)&uvbf[((size_t)n * 6 + col) * 512 + k4] = o;
  }
}

// ---------- k_lrm ----------
__global__ __launch_bounds__(256) void k_lrm(const float* __restrict__ x,
                                             const unsigned short* __restrict__ uvbf,
                                             float* __restrict__ left,
                                             float* __restrict__ right,
                                             unsigned short* __restrict__ Xbf) {
  const int n  = blockIdx.y;
  const int i0 = blockIdx.x * 64;
  const int tid = threadIdx.x;
  const int lane = tid & 63, wid = tid >> 6;
  __shared__ unsigned short uvs[16][520];
  __shared__ __attribute__((aligned(16))) char As[4096];

  for (int idx = tid; idx < 16 * 64; idx += 256) {
    int col = idx >> 6, k8 = (idx & 63) * 8;
    ushort4 z0 = {0, 0, 0, 0}, z1 = {0, 0, 0, 0};
    if (col < 6) {
      const unsigned short* p = uvbf + ((size_t)n * 6 + col) * 512 + k8;
      z0 = *(const ushort4*)p;
      z1 = *(const ushort4*)(p + 4);
    }
    *(ushort4*)&uvs[col][k8]     = z0;
    *(ushort4*)&uvs[col][k8 + 4] = z1;
  }
  const int row = tid >> 2, sub = tid & 3;
  const float* gp = x + ((size_t)n * 512 + i0 + row) * 512 + sub * 8;
  unsigned short* xp = Xbf + ((size_t)n * 512 + i0 + row) * 512 + sub * 8;
  const int lds_off = row * 64 + ((sub ^ (row & 3)) << 4);
  const int arow = wid * 16 + (lane & 15);
  const int a_off = arow * 64 + (((lane >> 4) ^ (arow & 3)) << 4);
  f32x4 acc = {0.f, 0.f, 0.f, 0.f};
  float4 f0 = *(const float4*)(gp);
  float4 f1 = *(const float4*)(gp + 4);
  __syncthreads();
  for (int s = 0; s < 16; ++s) {
    uint4 pk;
    pk.x = ((unsigned)f2bf(f0.y) << 16) | f2bf(f0.x);
    pk.y = ((unsigned)f2bf(f0.w) << 16) | f2bf(f0.z);
    pk.z = ((unsigned)f2bf(f1.y) << 16) | f2bf(f1.x);
    pk.w = ((unsigned)f2bf(f1.w) << 16) | f2bf(f1.z);
    if (s < 15) {
      f0 = *(const float4*)(gp + (s + 1) * 32);
      f1 = *(const float4*)(gp + (s + 1) * 32 + 4);
    }
    *(uint4*)(xp + s * 32) = pk;
    *(uint4*)(As + lds_off) = pk;
    __syncthreads();
    short8 a = *(const short8*)(As + a_off);
    short8 b = *(const short8*)&uvs[lane & 15][s * 32 + (lane >> 4) * 8];
    acc = __builtin_amdgcn_mfma_f32_16x16x32_bf16(a, b, acc, 0, 0, 0);
    __syncthreads();
  }
  const int col = lane & 15;
  if (col < 6) {
    float* dst = (col < 3) ? left : right;
    const int t = (col < 3) ? col : col - 3;
    const int i = i0 + wid * 16 + ((lane >> 4) << 2);
    float* p = dst + ((size_t)t * 64 + n) * 512 + i;
    p[0] = acc.x; p[1] = acc.y; p[2] = acc.z; p[3] = acc.w;
  }
}

// ---------- k_z: adj pass -> mb[n][i] (bound-max) and invZ[n][i] ----------
__global__ __launch_bounds__(256) void k_z(const int* __restrict__ adj,
                                           const float* __restrict__ left,
                                           const float* __restrict__ right,
                                           float* __restrict__ mbg,
                                           float* __restrict__ izg) {
  const int n  = blockIdx.y;
  const int i0 = blockIdx.x * 16;
  const int tid = threadIdx.x;
  const int lane = tid & 63, wid = tid >> 6;
  const int l15 = lane & 15;
  const int il  = wid * 4 + (lane >> 4);
  __shared__ float rs_s[32][49];
  __shared__ float ls[3][16];
  __shared__ float rmx[3][4];
  float lm0 = -3.0e38f, lm1 = -3.0e38f, lm2 = -3.0e38f;
  for (int idx = tid; idx < 1536; idx += 256) {
    int t = idx >> 9, j = idx & 511;
    float v = right[((size_t)t * 64 + n) * 512 + j];
    rs_s[j & 31][t * 16 + (j >> 5)] = v;
    lm0 = (t == 0) ? fmaxf(lm0, v) : lm0;
    lm1 = (t == 1) ? fmaxf(lm1, v) : lm1;
    lm2 = (t == 2) ? fmaxf(lm2, v) : lm2;
  }
  if (tid < 48) {
    int t = tid >> 4, ii = tid & 15;
    ls[t][ii] = left[((size_t)t * 64 + n) * 512 + i0 + ii];
  }
  for (int off = 32; off > 0; off >>= 1) {
    lm0 = fmaxf(lm0, __shfl_xor(lm0, off));
    lm1 = fmaxf(lm1, __shfl_xor(lm1, off));
    lm2 = fmaxf(lm2, __shfl_xor(lm2, off));
  }
  if (lane == 0) { rmx[0][wid] = lm0; rmx[1][wid] = lm1; rmx[2][wid] = lm2; }
  __syncthreads();
  const float r0m = fmaxf(fmaxf(rmx[0][0], rmx[0][1]), fmaxf(rmx[0][2], rmx[0][3]));
  const float r1m = fmaxf(fmaxf(rmx[1][0], rmx[1][1]), fmaxf(rmx[1][2], rmx[1][3]));
  const float r2m = fmaxf(fmaxf(rmx[2][0], rmx[2][1]), fmaxf(rmx[2][2], rmx[2][3]));
  const float l0 = ls[0][il], l1 = ls[1][il], l2 = ls[2][il];
  const float mb = fmaxf(fmaxf(l0 + r0m, l1 + r1m), l2 + r2m);
  const int* adjb = adj + ((size_t)(n * 512 + i0 + il)) * 512;
  int4 A[4], B[4];
#pragma unroll
  for (int q = 0; q < 4; ++q) {
    const int* p = adjb + q * 128 + l15 * 8;
    A[q] = *(const int4*)p;
    B[q] = *(const int4*)(p + 4);
  }
  const int base0 = ((l15 & 3) * 8) * 49 + (l15 >> 2);
  const float* rsf = (const float*)rs_s;
  float z = 0.f;
#pragma unroll
  for (int q = 0; q < 4; ++q) {
    int tv[8] = {A[q].x, A[q].y, A[q].z, A[q].w, B[q].x, B[q].y, B[q].z, B[q].w};
#pragma unroll
    for (int x = 0; x < 8; ++x) {
      int t = tv[x];
      int tt = (t > 0) ? (t - 1) : 0;
      float lv = (t >= 2) ? ((t == 3) ? l2 : l1) : l0;
      float r = rsf[base0 + tt * 16 + (x * 49 + q * 4)];
      float sv = lv + r;
      sv = (sv >= 0.f) ? sv : 0.2f * sv;
      sv = (t == 0) ? -9.0e15f : sv;
      z += __expf(sv - mb);
    }
  }
#pragma unroll
  for (int k = 1; k <= 8; k <<= 1) z += __shfl_xor(z, k);
  if (l15 == 0) {
    mbg[(size_t)n * 512 + i0 + il] = mb;
    izg[(size_t)n * 512 + i0 + il] = 1.f / z;
  }
}

// ---------- MFMA GEMM1: h2T[n][d][i] = (X[n] @ W2)^T ; 2-phase dbuf pipeline ----------
__global__ __launch_bounds__(256) void k_gemm1(const unsigned short* __restrict__ X,
                                               const unsigned short* __restrict__ WT,
                                               unsigned short* __restrict__ h2T) {
  __shared__ __attribute__((aligned(16))) char smem[34816];
  char* A0 = smem;
  char* A1 = smem + 8192;
  char* B0 = smem + 16384;
  char* B1 = smem + 24576;
  const int s = blockIdx.x;
  const int n  = ((s >> 7) << 3) | (s & 7);
  const int jj = (s >> 3) & 15;
  const int i0 = (jj >> 2) * 128;
  const int d0 = (jj & 3) * 128;
  const int tid = threadIdx.x;
  const int lane = tid & 63, w = tid >> 6;
  const int wm = w >> 1, wn = w & 1;
  const int srow = tid >> 2;
  const int kbp  = tid & 3;
  f32x4 acc[4][4];
#pragma unroll
  for (int a = 0; a < 4; ++a)
#pragma unroll
    for (int b = 0; b < 4; ++b) acc[a][b] = (f32x4){0.f, 0.f, 0.f, 0.f};

  const size_t xbase = (size_t)n * 262144;
  int ra[4], rb[4];
#pragma unroll
  for (int f = 0; f < 4; ++f) {
    int row = wm * 64 + f * 16 + (lane & 15);
    ra[f] = row * 64 + (((lane >> 4) ^ ((row >> 1) & 3)) << 4);
    int rowb = wn * 64 + f * 16 + (lane & 15);
    rb[f] = rowb * 64 + (((lane >> 4) ^ ((rowb >> 1) & 3)) << 4);
  }
  const int kl0 = (kbp ^ ((srow >> 1) & 3)) * 8;
  const int kl1 = (kbp ^ (((64 + srow) >> 1) & 3)) * 8;
  const unsigned short* xr0 = X + xbase + (size_t)(i0 + srow) * 512 + kl0;
  const unsigned short* xr1 = X + xbase + (size_t)(i0 + 64 + srow) * 512 + kl1;
  const unsigned short* wr0 = WT + (size_t)(d0 + srow) * 512 + kl0;
  const unsigned short* wr1 = WT + (size_t)(d0 + 64 + srow) * 512 + kl1;

  GLOAD16(xr0, A0 + tid * 16);
  GLOAD16(xr1, A0 + 4096 + tid * 16);
  GLOAD16(wr0, B0 + tid * 16);
  GLOAD16(wr1, B0 + 4096 + tid * 16);

#pragma unroll 2
  for (int t = 0; t < 16; ++t) {
    char* Ac = (t & 1) ? A1 : A0;
    char* Bc = (t & 1) ? B1 : B0;
    if (t < 15) {
      char* An = (t & 1) ? A0 : A1;
      char* Bn = (t & 1) ? B0 : B1;
      const int kc = (t + 1) * 32;
      GLOAD16(xr0 + kc, An + tid * 16);
      GLOAD16(xr1 + kc, An + 4096 + tid * 16);
      GLOAD16(wr0 + kc, Bn + tid * 16);
      GLOAD16(wr1 + kc, Bn + 4096 + tid * 16);
      asm volatile("s_waitcnt vmcnt(4)" ::: "memory");
    } else {
      asm volatile("s_waitcnt vmcnt(0)" ::: "memory");
    }
    __builtin_amdgcn_s_barrier();
    short8 a[4], b[4];
#pragma unroll
    for (int f = 0; f < 4; ++f) a[f] = *(const short8*)(Ac + ra[f]);
#pragma unroll
    for (int f = 0; f < 4; ++f) b[f] = *(const short8*)(Bc + rb[f]);
#pragma unroll
    for (int mf = 0; mf < 4; ++mf)
#pragma unroll
      for (int nf = 0; nf < 4; ++nf)
        acc[mf][nf] = __builtin_amdgcn_mfma_f32_16x16x32_bf16(a[mf], b[nf], acc[mf][nf], 0, 0, 0);
    asm volatile("s_waitcnt lgkmcnt(0)" ::: "memory");
    __builtin_amdgcn_sched_barrier(0);
    __builtin_amdgcn_s_barrier();
  }
  unsigned short (*Ct)[136] = (unsigned short (*)[136])smem;
#pragma unroll
  for (int mf = 0; mf < 4; ++mf)
#pragma unroll
    for (int nf = 0; nf < 4; ++nf) {
      f32x4 vv = acc[mf][nf];
      int dl = wn * 64 + nf * 16 + (lane & 15);
      int il = wm * 64 + mf * 16 + ((lane >> 4) << 2);
      ushort4 pk;
      pk.x = f2bf(vv.x); pk.y = f2bf(vv.y); pk.z = f2bf(vv.z); pk.w = f2bf(vv.w);
      *(ushort4*)&Ct[dl][il] = pk;
    }
  __syncthreads();
  const size_t obase = xbase + (size_t)d0 * 512 + i0;
#pragma unroll
  for (int q = 0; q < 8; ++q) {
    int f = q * 2048 + tid * 8;
    int dl = f >> 7, il = f & 127;
    *(uint4*)&h2T[obase + (size_t)dl * 512 + il] = *(const uint4*)&Ct[dl][il];
  }
}

// ---------- MFMA GEMM2-fused v2: out[n][j][d] = sum_i p[i][j] * h2[i][d] ----------
// 512 blocks = n(64) x 8 j-tiles of 64 (same-n -> same XCD: s = n + 64*jt).
// 512 thr / 8 waves (wm = w>>2 over 64j, wn = w&3 over 512d). Per K-step:
// A (64j x 32i) generated ONCE by waves 0-3 (4 elems/lane), linear ds_write
// with source-side chunk swizzle; B (512d x 32i) = 32KB h2T slab, dbuf gload.
__global__ __launch_bounds__(512) void k_gemm2f2(const int* __restrict__ adj,
                                                 const float* __restrict__ left,
                                                 const float* __restrict__ right,
                                                 const float* __restrict__ mbg,
                                                 const float* __restrict__ izg,
                                                 const unsigned short* __restrict__ H2T,
                                                 float* __restrict__ out) {
  __shared__ __attribute__((aligned(16))) char A_s[4096];
  __shared__ __attribute__((aligned(16))) char B0[32768];
  __shared__ __attribute__((aligned(16))) char B1[32768];
  __shared__ float lmb[5][512];     // l1,l2,l3,mb,invZ
  const int s = blockIdx.x;
  const int n  = s & 63;            // same-n blocks share XCD (s%8 == n%8)
  const int j0 = (s >> 6) * 64;
  const int tid = threadIdx.x;
  const int lane = tid & 63;
  const int w = __builtin_amdgcn_readfirstlane(tid >> 6);
  const int wm = w >> 2, wn = w & 3;
  const size_t base = (size_t)n * 262144;

  for (int idx = tid; idx < 2560; idx += 512) {
    int rr = idx >> 9, i = idx & 511;
    float v;
    if (rr < 3)       v = left[((size_t)rr * 64 + n) * 512 + i];
    else if (rr == 3) v = mbg[(size_t)n * 512 + i];
    else              v = izg[(size_t)n * 512 + i];
    lmb[rr][i] = v;
  }

  // ---- A-gen setup (waves 0-3 only; tid < 256) ----
  const int ajl = (w & 3) * 16 + (lane >> 2);          // j-local 0..63
  const int ac  = lane & 3;                            // physical chunk
  const int aoff = ((ac ^ ((ajl >> 1) & 3)) << 3);     // logical i-chunk base
  const float r1 = right[((size_t)0 * 64 + n) * 512 + j0 + ajl];
  const float r2 = right[((size_t)1 * 64 + n) * 512 + j0 + ajl];
  const float r3 = right[((size_t)2 * 64 + n) * 512 + j0 + ajl];
  const int* adjq = adj + base + j0 + ajl;             // + i*512 per elem

  // ---- B setup: 4 gloads/thread cover 512 rows x 64B ----
  int dloc[4];
  const unsigned short* hsrc[4];
#pragma unroll
  for (int q = 0; q < 4; ++q) {
    dloc[q] = q * 128 + w * 16 + (lane >> 2);
    hsrc[q] = H2T + base + (size_t)dloc[q] * 512 + (((lane & 3) ^ ((dloc[q] >> 1) & 3)) << 3);
  }

  f32x4 acc[2][8];
#pragma unroll
  for (int a = 0; a < 2; ++a)
#pragma unroll
    for (int b = 0; b < 8; ++b) acc[a][b] = (f32x4){0.f, 0.f, 0.f, 0.f};
  int ra[2], rb[8];
#pragma unroll
  for (int f = 0; f < 2; ++f) {
    int row = wm * 32 + f * 16 + (lane & 15);
    ra[f] = row * 64 + (((lane >> 4) ^ ((row >> 1) & 3)) << 4);
  }
#pragma unroll
  for (int f = 0; f < 8; ++f) {
    int rowd = wn * 128 + f * 16 + (lane & 15);
    rb[f] = rowd * 64 + (((lane >> 4) ^ ((rowd >> 1) & 3)) << 4);
  }

  // prologue: adj(0) regs + B(0)
  int adjc[8];
  if (tid < 256) {
#pragma unroll
    for (int e = 0; e < 8; ++e) adjc[e] = adjq[(size_t)(aoff + e) * 512];
  }
#pragma unroll
  for (int q = 0; q < 4; ++q)
    GLOAD16(hsrc[q], B0 + q * 8192 + w * 1024 + (lane << 4));
  __syncthreads();   // lmb staged

  for (int t = 0; t < 16; ++t) {
    char* Bc = (t & 1) ? B1 : B0;
    asm volatile("s_waitcnt vmcnt(0)" ::: "memory");   // adj(t) + B(t) landed
    if (tid < 256) {
      unsigned pw[4];
#pragma unroll
      for (int h = 0; h < 4; ++h) {
        unsigned lo = 0, hi = 0;
#pragma unroll
        for (int e = 0; e < 2; ++e) {
          int m = h * 2 + e;
          int tv = adjc[m];
          int tt = (tv > 0) ? (tv - 1) : 0;
          float rv = (tv == 1) ? r1 : ((tv == 2) ? r2 : r3);
          int ig = t * 32 + aoff + m;
          float sv = lmb[tt][ig] + rv;
          sv = fmaxf(sv, 0.2f * sv);                   // leaky-relu
          float p = (tv == 0) ? 0.f : __expf(sv - lmb[3][ig]) * lmb[4][ig];
          if (e == 0) lo = f2bf(p); else hi = f2bf(p);
        }
        pw[h] = (hi << 16) | lo;
      }
      uint4 pk; pk.x = pw[0]; pk.y = pw[1]; pk.z = pw[2]; pk.w = pw[3];
      *(uint4*)(A_s + ajl * 64 + ac * 16) = pk;        // linear write: conflict-free
    }
    asm volatile("s_waitcnt lgkmcnt(0)" ::: "memory");
    __builtin_amdgcn_s_barrier();
    if (t < 15) {
      if (tid < 256) {
#pragma unroll
        for (int e = 0; e < 8; ++e)
          adjc[e] = adjq[(size_t)((t + 1) * 32 + aoff + e) * 512];
      }
      char* Bn = (t & 1) ? B0 : B1;
#pragma unroll
      for (int q = 0; q < 4; ++q)
        GLOAD16(hsrc[q] + (t + 1) * 32, Bn + q * 8192 + w * 1024 + (lane << 4));
    }
    short8 a[2], b[8];
#pragma unroll
    for (int f = 0; f < 2; ++f) a[f] = *(const short8*)(A_s + ra[f]);
#pragma unroll
    for (int f = 0; f < 8; ++f) b[f] = *(const short8*)(Bc + rb[f]);
#pragma unroll
    for (int mf = 0; mf < 2; ++mf)
#pragma unroll
      for (int nf = 0; nf < 8; ++nf)
        acc[mf][nf] = __builtin_amdgcn_mfma_f32_16x16x32_bf16(a[mf], b[nf], acc[mf][nf], 0, 0, 0);
    asm volatile("s_waitcnt lgkmcnt(0)" ::: "memory");
    __builtin_amdgcn_sched_barrier(0);
    __builtin_amdgcn_s_barrier();
  }
  const int jb = j0 + wm * 32 + (lane >> 4) * 4;
  const int db = wn * 128 + (lane & 15);
#pragma unroll
  for (int mf = 0; mf < 2; ++mf)
#pragma unroll
    for (int nf = 0; nf < 8; ++nf) {
      f32x4 vv = acc[mf][nf];
      float* op = out + base + (size_t)(jb + mf * 16) * 512 + db + nf * 16;
      op[0]    = vv.x;
      op[512]  = vv.y;
      op[1024] = vv.z;
      op[1536] = vv.w;
    }
}

extern "C" void kernel_launch(void* const* d_in, const int* in_sizes, int n_in,
                              void* d_out, int out_size, void* d_ws, size_t ws_size,
                              hipStream_t stream) {
  const float* input  = (const float*)d_in[0];
  const int*   adj    = (const int*)d_in[1];
  const float* query  = (const float*)d_in[3];
  const float* W_type = (const float*)d_in[4];
  const float* a_type = (const float*)d_in[5];
  const float* W1     = (const float*)d_in[6];
  const float* W2     = (const float*)d_in[7];
  float* out = (float*)d_out;

  char* ws = (char*)d_ws;
  float* galT  = (float*)(ws);                              //  393,216 B
  float* garT  = (float*)(ws + 393216);                     //  393,216 B
  unsigned short* uvbf = (unsigned short*)(ws + 786432);    //  393,216 B
  float* left  = (float*)(ws + 1179648);                    //  393,216 B
  float* right = (float*)(ws + 1572864);                    //  393,216 B
  unsigned short* Xbf = (unsigned short*)(ws + 2359296);    // 33,554,432 B
  unsigned short* h2T = (unsigned short*)(ws + 35913728);   // 33,554,432 B
  float* rpart = (float*)(ws + 35913728);                   //  3,145,728 B (aliases h2T, dead before gemm1)
  float* gpart = (float*)(ws + 39059456);                   //  6,291,456 B
  float* upart = (float*)(ws + 45350912);                   //  3,145,728 B
  float* vpart = (float*)(ws + 48496640);                   //  3,145,728 B
  unsigned short* WT  = (unsigned short*)(ws + 69468160);   //    524,288 B
  float* mbg = (float*)(ws + 69992448);                     //    131,072 B
  float* izg = (float*)(ws + 70123520);                     //    131,072 B
  // total ws use: 70,254,592 B

  k_wt      <<<dim3(8, 8),      256, 0, stream>>>(W_type + (size_t)2 * 262144, WT);
  k_gate1   <<<dim3(16, 4, 3),  256, 0, stream>>>(query, W1, rpart);
  k_gate2   <<<dim3(16, 8, 3),  256, 0, stream>>>(rpart, W2, gpart);
  k_gate_fin<<<dim3(256, 3),    256, 0, stream>>>(gpart, a_type, galT, garT);
  k_uvp     <<<dim3(8, 8, 3),   256, 0, stream>>>(W_type, galT, garT, upart, vpart);
  k_uvsum   <<<dim3(64),        256, 0, stream>>>(upart, vpart, uvbf);
  k_lrm     <<<dim3(8, 64),     256, 0, stream>>>(input, uvbf, left, right, Xbf);
  k_z       <<<dim3(32, 64),    256, 0, stream>>>(adj, left, right, mbg, izg);
  k_gemm1   <<<dim3(1024),      256, 0, stream>>>(Xbf, WT, h2T);
  k_gemm2f2 <<<dim3(512),       512, 0, stream>>>(adj, left, right, mbg, izg, h2T, out);
}

// Round 13
// 188.881 us; speedup vs baseline: 1.1052x; 1.0573x over previous
//
#include <hip/hip_runtime.h>
#include <cstdint>

typedef __attribute__((ext_vector_type(8))) short short8;
typedef __attribute__((ext_vector_type(4))) float f32x4;

// ---------- helpers ----------
__device__ __forceinline__ unsigned short f2bf(float x) {
  unsigned int u = __float_as_uint(x);
  u += 0x7FFFu + ((u >> 16) & 1u);   // round-to-nearest-even
  return (unsigned short)(u >> 16);
}

#define GLOAD16(gsrc, ldst)                                                        \
  __builtin_amdgcn_global_load_lds(                                                \
      (const __attribute__((address_space(1))) void*)(gsrc),                       \
      (__attribute__((address_space(3))) void*)(ldst), 16, 0, 0)

// ---------- 0b. WT[d][k] = bf16(W2[k][d]) ----------
__global__ __launch_bounds__(256) void k_wt(const float* __restrict__ W,
                                            unsigned short* __restrict__ WT) {
  __shared__ float t[64][68];
  const int k0 = blockIdx.y * 64, d0 = blockIdx.x * 64;
  for (int idx = threadIdx.x; idx < 4096; idx += 256) {
    int r = idx >> 6, c = idx & 63;
    t[r][c] = W[(size_t)(k0 + r) * 512 + d0 + c];
  }
  __syncthreads();
  for (int idx = threadIdx.x; idx < 4096; idx += 256) {
    int r = idx >> 6, c = idx & 63;
    WT[(size_t)(d0 + r) * 512 + k0 + c] = f2bf(t[c][r]);
  }
}

// ---------- gate 1 ----------
__global__ __launch_bounds__(256) void k_gate1(const float* __restrict__ q,
                                               const float* __restrict__ W1,
                                               float* __restrict__ rpart) {
  const int c0 = blockIdx.x * 64;
  const int k0 = blockIdx.y * 128;
  const int t  = blockIdx.z;
  const int tid = threadIdx.x;
  const int lane = tid & 63;
  const int wcs = __builtin_amdgcn_readfirstlane(tid >> 6);
  __shared__ float qs[64][133];
  for (int idx = tid; idx < 2048; idx += 256) {
    int r = idx >> 5, c4 = (idx & 31) * 4;
    float4 f = *(const float4*)&q[(size_t)r * 512 + k0 + c4];
    qs[r][c4 + 0] = f.x; qs[r][c4 + 1] = f.y;
    qs[r][c4 + 2] = f.z; qs[r][c4 + 3] = f.w;
  }
  __syncthreads();
  const float* Wp = W1 + ((size_t)t * 512 + k0) * 1024 + c0 + wcs * 16;
  float acc[16] = {};
  for (int k = 0; k < 128; ++k) {
    float qr = qs[lane][k];
    const float* wr = Wp + (size_t)k * 1024;
    float4 w0 = *(const float4*)(wr);
    float4 w1 = *(const float4*)(wr + 4);
    float4 w2 = *(const float4*)(wr + 8);
    float4 w3 = *(const float4*)(wr + 12);
    acc[0]  = fmaf(qr, w0.x, acc[0]);  acc[1]  = fmaf(qr, w0.y, acc[1]);
    acc[2]  = fmaf(qr, w0.z, acc[2]);  acc[3]  = fmaf(qr, w0.w, acc[3]);
    acc[4]  = fmaf(qr, w1.x, acc[4]);  acc[5]  = fmaf(qr, w1.y, acc[5]);
    acc[6]  = fmaf(qr, w1.z, acc[6]);  acc[7]  = fmaf(qr, w1.w, acc[7]);
    acc[8]  = fmaf(qr, w2.x, acc[8]);  acc[9]  = fmaf(qr, w2.y, acc[9]);
    acc[10] = fmaf(qr, w2.z, acc[10]); acc[11] = fmaf(qr, w2.w, acc[11]);
    acc[12] = fmaf(qr, w3.x, acc[12]); acc[13] = fmaf(qr, w3.y, acc[13]);
    acc[14] = fmaf(qr, w3.z, acc[14]); acc[15] = fmaf(qr, w3.w, acc[15]);
  }
  float* rp = rpart + ((size_t)(t * 4 + blockIdx.y) * 1024 + c0 + wcs * 16) * 64 + lane;
#pragma unroll
  for (int cc = 0; cc < 16; ++cc) rp[(size_t)cc * 64] = acc[cc];
}

// ---------- gate 2 ----------
__global__ __launch_bounds__(256) void k_gate2(const float* __restrict__ rpart,
                                               const float* __restrict__ W2,
                                               float* __restrict__ gpart) {
  const int c0 = blockIdx.x * 64;
  const int k0 = blockIdx.y * 128;
  const int t  = blockIdx.z;
  const int tid = threadIdx.x;
  const int lane = tid & 63;
  const int wcs = __builtin_amdgcn_readfirstlane(tid >> 6);
  __shared__ float qs[64][133];
  for (int idx = tid; idx < 2048; idx += 256) {
    int kl = idx >> 4, n4 = (idx & 15) * 4;
    const float* rp = rpart + ((size_t)t * 4 * 1024 + k0 + kl) * 64 + n4;
    float4 a = *(const float4*)(rp);
    float4 b = *(const float4*)(rp + 65536);
    float4 c = *(const float4*)(rp + 131072);
    float4 d = *(const float4*)(rp + 196608);
    qs[n4 + 0][kl] = fmaxf(a.x + b.x + c.x + d.x, 0.f);
    qs[n4 + 1][kl] = fmaxf(a.y + b.y + c.y + d.y, 0.f);
    qs[n4 + 2][kl] = fmaxf(a.z + b.z + c.z + d.z, 0.f);
    qs[n4 + 3][kl] = fmaxf(a.w + b.w + c.w + d.w, 0.f);
  }
  __syncthreads();
  const float* Wp = W2 + ((size_t)t << 20) + (size_t)k0 * 1024 + c0 + wcs * 16;
  float acc[16] = {};
  for (int k = 0; k < 128; ++k) {
    float qr = qs[lane][k];
    const float* wr = Wp + (size_t)k * 1024;
    float4 w0 = *(const float4*)(wr);
    float4 w1 = *(const float4*)(wr + 4);
    float4 w2 = *(const float4*)(wr + 8);
    float4 w3 = *(const float4*)(wr + 12);
    acc[0]  = fmaf(qr, w0.x, acc[0]);  acc[1]  = fmaf(qr, w0.y, acc[1]);
    acc[2]  = fmaf(qr, w0.z, acc[2]);  acc[3]  = fmaf(qr, w0.w, acc[3]);
    acc[4]  = fmaf(qr, w1.x, acc[4]);  acc[5]  = fmaf(qr, w1.y, acc[5]);
    acc[6]  = fmaf(qr, w1.z, acc[6]);  acc[7]  = fmaf(qr, w1.w, acc[7]);
    acc[8]  = fmaf(qr, w2.x, acc[8]);  acc[9]  = fmaf(qr, w2.y, acc[9]);
    acc[10] = fmaf(qr, w2.z, acc[10]); acc[11] = fmaf(qr, w2.w, acc[11]);
    acc[12] = fmaf(qr, w3.x, acc[12]); acc[13] = fmaf(qr, w3.y, acc[13]);
    acc[14] = fmaf(qr, w3.z, acc[14]); acc[15] = fmaf(qr, w3.w, acc[15]);
  }
  float* gp = gpart + ((size_t)(t * 8 + blockIdx.y) * 1024 + c0 + wcs * 16) * 64 + lane;
#pragma unroll
  for (int cc = 0; cc < 16; ++cc) gp[(size_t)cc * 64] = acc[cc];
}

// ---------- gate fin ----------
__global__ __launch_bounds__(256) void k_gate_fin(const float* __restrict__ gpart,
                                                  const float* __restrict__ a_type,
                                                  float* __restrict__ galT,
                                                  float* __restrict__ garT) {
  const int t = blockIdx.y;
  const int n = threadIdx.x & 63;
  const int mg = blockIdx.x * 4 + (threadIdx.x >> 6);
  float s = 0.f;
#pragma unroll
  for (int kc = 0; kc < 8; ++kc)
    s += gpart[((size_t)(t * 8 + kc) * 1024 + mg) * 64 + n];
  float g = 1.f / (1.f + __expf(-s));
  float ga = g * a_type[t * 1024 + mg];
  if (mg < 512) galT[((size_t)t * 512 + mg) * 64 + n] = ga;
  else          garT[((size_t)t * 512 + (mg - 512)) * 64 + n] = ga;
}

// ---------- u,v split-d partials ----------
__global__ __launch_bounds__(256) void k_uvp(const float* __restrict__ W,
                                             const float* __restrict__ galT,
                                             const float* __restrict__ garT,
                                             float* __restrict__ upart,
                                             float* __restrict__ vpart) {
  const int k0 = blockIdx.x * 64;
  const int d0 = blockIdx.y * 64;
  const int t  = blockIdx.z;
  const int tid = threadIdx.x;
  const int lane = tid & 63;
  const int wk = (tid >> 6) * 16;
  __shared__ float gal_s[64][64];
  __shared__ float gar_s[64][64];
  __shared__ float W_s[64][64];
  for (int idx = tid; idx < 1024; idx += 256) {
    int d = idx >> 4, n4 = (idx & 15) * 4;
    *(float4*)&gal_s[d][n4] = *(const float4*)&galT[((size_t)t * 512 + d0 + d) * 64 + n4];
    *(float4*)&gar_s[d][n4] = *(const float4*)&garT[((size_t)t * 512 + d0 + d) * 64 + n4];
    int k = idx >> 4, d4 = (idx & 15) * 4;
    *(float4*)&W_s[k][d4] = *(const float4*)&W[((size_t)t * 512 + k0 + k) * 512 + d0 + d4];
  }
  __syncthreads();
  float au[16] = {}, av[16] = {};
  for (int dq = 0; dq < 64; dq += 4) {
    float g1[4], g2[4];
#pragma unroll
    for (int e = 0; e < 4; ++e) { g1[e] = gal_s[dq + e][lane]; g2[e] = gar_s[dq + e][lane]; }
#pragma unroll
    for (int kk = 0; kk < 16; ++kk) {
      float4 wv = *(const float4*)&W_s[wk + kk][dq];
      au[kk] = fmaf(wv.x, g1[0], fmaf(wv.y, g1[1], fmaf(wv.z, g1[2], fmaf(wv.w, g1[3], au[kk]))));
      av[kk] = fmaf(wv.x, g2[0], fmaf(wv.y, g2[1], fmaf(wv.z, g2[2], fmaf(wv.w, g2[3], av[kk]))));
    }
  }
  const size_t ob = ((size_t)((t * 8 + blockIdx.y) * 64 + lane)) * 512 + k0 + wk;
#pragma unroll
  for (int q = 0; q < 4; ++q) {
    *(float4*)&upart[ob + q * 4] = make_float4(au[q*4], au[q*4+1], au[q*4+2], au[q*4+3]);
    *(float4*)&vpart[ob + q * 4] = make_float4(av[q*4], av[q*4+1], av[q*4+2], av[q*4+3]);
  }
}

// ---------- sum uv partials -> uvbf ----------
__global__ __launch_bounds__(256) void k_uvsum(const float* __restrict__ upart,
                                               const float* __restrict__ vpart,
                                               unsigned short* __restrict__ uvbf) {
  const int n = blockIdx.x;
  for (int idx = threadIdx.x; idx < 768; idx += 256) {
    int col = idx >> 7;
    int k4 = (idx & 127) * 4;
    const float* base = (col < 3)
        ? upart + ((size_t)(col * 8) * 64 + n) * 512 + k4
        : vpart + ((size_t)((col - 3) * 8) * 64 + n) * 512 + k4;
    float4 sv = {0.f, 0.f, 0.f, 0.f};
#pragma unroll
    for (int dc = 0; dc < 8; ++dc) {
      float4 t = *(const float4*)(base + (size_t)dc * 32768);
      sv.x += t.x; sv.y += t.y; sv.z += t.z; sv.w += t.w;
    }
    ushort4 o;
    o.x = f2bf(sv.x); o.y = f2bf(sv.y); o.z = f2bf(sv.z); o.w = f2bf(sv.w);
    *(ushort4*)&uvbf[((size_t)n * 6 + col) * 512 + k4] = o;
  }
}

// ---------- k_lrm ----------
__global__ __launch_bounds__(256) void k_lrm(const float* __restrict__ x,
                                             const unsigned short* __restrict__ uvbf,
                                             float* __restrict__ left,
                                             float* __restrict__ right,
                                             unsigned short* __restrict__ Xbf) {
  const int n  = blockIdx.y;
  const int i0 = blockIdx.x * 64;
  const int tid = threadIdx.x;
  const int lane = tid & 63, wid = tid >> 6;
  __shared__ unsigned short uvs[16][520];
  __shared__ __attribute__((aligned(16))) char As[4096];

  for (int idx = tid; idx < 16 * 64; idx += 256) {
    int col = idx >> 6, k8 = (idx & 63) * 8;
    ushort4 z0 = {0, 0, 0, 0}, z1 = {0, 0, 0, 0};
    if (col < 6) {
      const unsigned short* p = uvbf + ((size_t)n * 6 + col) * 512 + k8;
      z0 = *(const ushort4*)p;
      z1 = *(const ushort4*)(p + 4);
    }
    *(ushort4*)&uvs[col][k8]     = z0;
    *(ushort4*)&uvs[col][k8 + 4] = z1;
  }
  const int row = tid >> 2, sub = tid & 3;
  const float* gp = x + ((size_t)n * 512 + i0 + row) * 512 + sub * 8;
  unsigned short* xp = Xbf + ((size_t)n * 512 + i0 + row) * 512 + sub * 8;
  const int lds_off = row * 64 + ((sub ^ (row & 3)) << 4);
  const int arow = wid * 16 + (lane & 15);
  const int a_off = arow * 64 + (((lane >> 4) ^ (arow & 3)) << 4);
  f32x4 acc = {0.f, 0.f, 0.f, 0.f};
  float4 f0 = *(const float4*)(gp);
  float4 f1 = *(const float4*)(gp + 4);
  __syncthreads();
  for (int s = 0; s < 16; ++s) {
    uint4 pk;
    pk.x = ((unsigned)f2bf(f0.y) << 16) | f2bf(f0.x);
    pk.y = ((unsigned)f2bf(f0.w) << 16) | f2bf(f0.z);
    pk.z = ((unsigned)f2bf(f1.y) << 16) | f2bf(f1.x);
    pk.w = ((unsigned)f2bf(f1.w) << 16) | f2bf(f1.z);
    if (s < 15) {
      f0 = *(const float4*)(gp + (s + 1) * 32);
      f1 = *(const float4*)(gp + (s + 1) * 32 + 4);
    }
    *(uint4*)(xp + s * 32) = pk;
    *(uint4*)(As + lds_off) = pk;
    __syncthreads();
    short8 a = *(const short8*)(As + a_off);
    short8 b = *(const short8*)&uvs[lane & 15][s * 32 + (lane >> 4) * 8];
    acc = __builtin_amdgcn_mfma_f32_16x16x32_bf16(a, b, acc, 0, 0, 0);
    __syncthreads();
  }
  const int col = lane & 15;
  if (col < 6) {
    float* dst = (col < 3) ? left : right;
    const int t = (col < 3) ? col : col - 3;
    const int i = i0 + wid * 16 + ((lane >> 4) << 2);
    float* p = dst + ((size_t)t * 64 + n) * 512 + i;
    p[0] = acc.x; p[1] = acc.y; p[2] = acc.z; p[3] = acc.w;
  }
}

// ---------- union member A: GEMM1 body (2-phase dbuf pipeline) ----------
__device__ __forceinline__ void gemm1_body(int s, char* smem,
                                           const unsigned short* __restrict__ X,
                                           const unsigned short* __restrict__ WT,
                                           unsigned short* __restrict__ h2T) {
  char* A0 = smem;
  char* A1 = smem + 8192;
  char* B0 = smem + 16384;
  char* B1 = smem + 24576;
  const int n  = ((s >> 7) << 3) | (s & 7);
  const int jj = (s >> 3) & 15;
  const int i0 = (jj >> 2) * 128;
  const int d0 = (jj & 3) * 128;
  const int tid = threadIdx.x;
  const int lane = tid & 63, w = tid >> 6;
  const int wm = w >> 1, wn = w & 1;
  const int srow = tid >> 2;
  const int kbp  = tid & 3;
  f32x4 acc[4][4];
#pragma unroll
  for (int a = 0; a < 4; ++a)
#pragma unroll
    for (int b = 0; b < 4; ++b) acc[a][b] = (f32x4){0.f, 0.f, 0.f, 0.f};

  const size_t xbase = (size_t)n * 262144;
  int ra[4], rb[4];
#pragma unroll
  for (int f = 0; f < 4; ++f) {
    int row = wm * 64 + f * 16 + (lane & 15);
    ra[f] = row * 64 + (((lane >> 4) ^ ((row >> 1) & 3)) << 4);
    int rowb = wn * 64 + f * 16 + (lane & 15);
    rb[f] = rowb * 64 + (((lane >> 4) ^ ((rowb >> 1) & 3)) << 4);
  }
  const int kl0 = (kbp ^ ((srow >> 1) & 3)) * 8;
  const int kl1 = (kbp ^ (((64 + srow) >> 1) & 3)) * 8;
  const unsigned short* xr0 = X + xbase + (size_t)(i0 + srow) * 512 + kl0;
  const unsigned short* xr1 = X + xbase + (size_t)(i0 + 64 + srow) * 512 + kl1;
  const unsigned short* wr0 = WT + (size_t)(d0 + srow) * 512 + kl0;
  const unsigned short* wr1 = WT + (size_t)(d0 + 64 + srow) * 512 + kl1;

  GLOAD16(xr0, A0 + tid * 16);
  GLOAD16(xr1, A0 + 4096 + tid * 16);
  GLOAD16(wr0, B0 + tid * 16);
  GLOAD16(wr1, B0 + 4096 + tid * 16);

#pragma unroll 2
  for (int t = 0; t < 16; ++t) {
    char* Ac = (t & 1) ? A1 : A0;
    char* Bc = (t & 1) ? B1 : B0;
    if (t < 15) {
      char* An = (t & 1) ? A0 : A1;
      char* Bn = (t & 1) ? B0 : B1;
      const int kc = (t + 1) * 32;
      GLOAD16(xr0 + kc, An + tid * 16);
      GLOAD16(xr1 + kc, An + 4096 + tid * 16);
      GLOAD16(wr0 + kc, Bn + tid * 16);
      GLOAD16(wr1 + kc, Bn + 4096 + tid * 16);
      asm volatile("s_waitcnt vmcnt(4)" ::: "memory");
    } else {
      asm volatile("s_waitcnt vmcnt(0)" ::: "memory");
    }
    __builtin_amdgcn_s_barrier();
    short8 a[4], b[4];
#pragma unroll
    for (int f = 0; f < 4; ++f) a[f] = *(const short8*)(Ac + ra[f]);
#pragma unroll
    for (int f = 0; f < 4; ++f) b[f] = *(const short8*)(Bc + rb[f]);
#pragma unroll
    for (int mf = 0; mf < 4; ++mf)
#pragma unroll
      for (int nf = 0; nf < 4; ++nf)
        acc[mf][nf] = __builtin_amdgcn_mfma_f32_16x16x32_bf16(a[mf], b[nf], acc[mf][nf], 0, 0, 0);
    asm volatile("s_waitcnt lgkmcnt(0)" ::: "memory");
    __builtin_amdgcn_sched_barrier(0);
    __builtin_amdgcn_s_barrier();
  }
  unsigned short (*Ct)[136] = (unsigned short (*)[136])smem;
#pragma unroll
  for (int mf = 0; mf < 4; ++mf)
#pragma unroll
    for (int nf = 0; nf < 4; ++nf) {
      f32x4 vv = acc[mf][nf];
      int dl = wn * 64 + nf * 16 + (lane & 15);
      int il = wm * 64 + mf * 16 + ((lane >> 4) << 2);
      ushort4 pk;
      pk.x = f2bf(vv.x); pk.y = f2bf(vv.y); pk.z = f2bf(vv.z); pk.w = f2bf(vv.w);
      *(ushort4*)&Ct[dl][il] = pk;
    }
  __syncthreads();
  const size_t obase = xbase + (size_t)d0 * 512 + i0;
#pragma unroll
  for (int q = 0; q < 8; ++q) {
    int f = q * 2048 + tid * 8;
    int dl = f >> 7, il = f & 127;
    *(uint4*)&h2T[obase + (size_t)dl * 512 + il] = *(const uint4*)&Ct[dl][il];
  }
}

// ---------- union member B: fused softmax+transpose body (online softmax) ----------
__device__ __forceinline__ void smt_body(int m, char* smem,
                                         const int* __restrict__ adj,
                                         const float* __restrict__ left,
                                         const float* __restrict__ right,
                                         unsigned short* __restrict__ ct) {
  float (*rs_s)[49] = (float (*)[49])smem;                        //  6272 B
  float (*ls)[16]   = (float (*)[16])(smem + 6272);               //   192 B
  unsigned short (*tile)[520] = (unsigned short (*)[520])(smem + 6464);  // 16640 B
  const int n  = m >> 5;
  const int i0 = (m & 31) * 16;
  const int tid = threadIdx.x;
  const int lane = tid & 63, wid = tid >> 6;
  const int l15 = lane & 15;
  const int il  = wid * 4 + (lane >> 4);
  for (int idx = tid; idx < 1536; idx += 256) {
    int t = idx >> 9, j = idx & 511;
    rs_s[j & 31][t * 16 + (j >> 5)] = right[((size_t)t * 64 + n) * 512 + j];
  }
  if (tid < 48) {
    int t = tid >> 4, ii = tid & 15;
    ls[t][ii] = left[((size_t)t * 64 + n) * 512 + i0 + ii];
  }
  __syncthreads();
  const int* adjb = adj + ((size_t)(n * 512 + i0 + il)) * 512;
  int4 A[4], B[4];
#pragma unroll
  for (int q = 0; q < 4; ++q) {
    const int* p = adjb + q * 128 + l15 * 8;
    A[q] = *(const int4*)p;
    B[q] = *(const int4*)(p + 4);
  }
  const float l0 = ls[0][il], l1 = ls[1][il], l2 = ls[2][il];
  const int base0 = ((l15 & 3) * 8) * 49 + (l15 >> 2);
  const float* rsf = (const float*)rs_s;
  float s[4][8];
  float mloc = -3.0e38f;
#pragma unroll
  for (int q = 0; q < 4; ++q) {
    int tv[8] = {A[q].x, A[q].y, A[q].z, A[q].w, B[q].x, B[q].y, B[q].z, B[q].w};
#pragma unroll
    for (int x = 0; x < 8; ++x) {
      int t = tv[x];
      int tt = (t > 0) ? (t - 1) : 0;
      float lv = (t >= 2) ? ((t == 3) ? l2 : l1) : l0;
      float r = rsf[base0 + tt * 16 + (x * 49 + q * 4)];
      float sv = lv + r;
      sv = (sv >= 0.f) ? sv : 0.2f * sv;
      sv = (t == 0) ? -9.0e15f : sv;
      s[q][x] = sv;
      mloc = fmaxf(mloc, sv);
    }
  }
  float z = 0.f;
#pragma unroll
  for (int q = 0; q < 4; ++q)
#pragma unroll
    for (int x = 0; x < 8; ++x) {
      float e = __expf(s[q][x] - mloc);
      s[q][x] = e;
      z += e;
    }
  float mm = mloc;
#pragma unroll
  for (int k = 1; k <= 8; k <<= 1) {
    float mo = __shfl_xor(mm, k);
    float zo = __shfl_xor(z, k);
    float mn = fmaxf(mm, mo);
    z = z * __expf(mm - mn) + zo * __expf(mo - mn);
    mm = mn;
  }
  const float factor = __expf(mloc - mm) / z;
#pragma unroll
  for (int q = 0; q < 4; ++q) {
    uint4 pk;
    pk.x = ((unsigned)f2bf(s[q][1] * factor) << 16) | f2bf(s[q][0] * factor);
    pk.y = ((unsigned)f2bf(s[q][3] * factor) << 16) | f2bf(s[q][2] * factor);
    pk.z = ((unsigned)f2bf(s[q][5] * factor) << 16) | f2bf(s[q][4] * factor);
    pk.w = ((unsigned)f2bf(s[q][7] * factor) << 16) | f2bf(s[q][6] * factor);
    *(uint4*)&tile[il][q * 128 + l15 * 8] = pk;
  }
  __syncthreads();
  unsigned short* ob = ct + (size_t)n * 262144 + i0;
#pragma unroll
  for (int pass = 0; pass < 4; ++pass) {
    int j = pass * 128 + (tid >> 1);
    int i8 = (tid & 1) * 8;
    uint4 o;
    o.x = (unsigned)tile[i8 + 0][j] | ((unsigned)tile[i8 + 1][j] << 16);
    o.y = (unsigned)tile[i8 + 2][j] | ((unsigned)tile[i8 + 3][j] << 16);
    o.z = (unsigned)tile[i8 + 4][j] | ((unsigned)tile[i8 + 5][j] << 16);
    o.w = (unsigned)tile[i8 + 6][j] | ((unsigned)tile[i8 + 7][j] << 16);
    *(uint4*)&ob[(size_t)j * 512 + i8] = o;
  }
}

// ---------- union kernel: 3072 blocks, bid%3==0 -> gemm1, else -> smt ----------
// 1:2 interleave co-schedules MFMA-heavy gemm1 with latency-bound smt on each CU.
// Same-n gemm1 blocks (g%8 = n&7) land on XCD (3*(n&7))%8 (3 coprime 8 -> bijective).
__global__ __launch_bounds__(256) void k_g1smt(const unsigned short* __restrict__ X,
                                               const unsigned short* __restrict__ WT,
                                               unsigned short* __restrict__ h2T,
                                               const int* __restrict__ adj,
                                               const float* __restrict__ left,
                                               const float* __restrict__ right,
                                               unsigned short* __restrict__ ct) {
  __shared__ __attribute__((aligned(16))) char smem[34816];
  const int bid = blockIdx.x;
  const int g = bid / 3;
  const int r = bid - g * 3;
  if (r == 0) gemm1_body(g, smem, X, WT, h2T);
  else        smt_body(g * 2 + (r - 1), smem, adj, left, right, ct);
}

// ---------- GEMM2: out[n][j][d] = coefsT[n] @ h2T[n]^T ; 2-phase dbuf pipeline ----------
// n-map tweaked: n&7 = 3*(s&7) mod 8 so h2T[n] (written on XCD 3*(n&7)%8 by the
// union kernel) is read XCD-locally.
__global__ __launch_bounds__(256) void k_gemm2(const unsigned short* __restrict__ CT,
                                               const unsigned short* __restrict__ H2T,
                                               float* __restrict__ out) {
  __shared__ __attribute__((aligned(16))) char smem[32768];
  char* A0 = smem;
  char* A1 = smem + 8192;
  char* B0 = smem + 16384;
  char* B1 = smem + 24576;
  const int s = blockIdx.x;
  const int n  = ((s >> 7) << 3) | ((3 * (s & 7)) & 7);
  const int jj = (s >> 3) & 15;
  const int j0 = (jj >> 2) * 128;
  const int d0 = (jj & 3) * 128;
  const int tid = threadIdx.x;
  const int lane = tid & 63, w = tid >> 6;
  const int wm = w >> 1, wn = w & 1;
  const int srow = tid >> 2;
  const int kbp  = tid & 3;
  f32x4 acc[4][4];
#pragma unroll
  for (int a = 0; a < 4; ++a)
#pragma unroll
    for (int b = 0; b < 4; ++b) acc[a][b] = (f32x4){0.f, 0.f, 0.f, 0.f};

  const size_t base = (size_t)n * 262144;
  int ra[4], rb[4];
#pragma unroll
  for (int f = 0; f < 4; ++f) {
    int row = wm * 64 + f * 16 + (lane & 15);
    ra[f] = row * 64 + (((lane >> 4) ^ ((row >> 1) & 3)) << 4);
    int rowb = wn * 64 + f * 16 + (lane & 15);
    rb[f] = rowb * 64 + (((lane >> 4) ^ ((rowb >> 1) & 3)) << 4);
  }
  const int kl0 = (kbp ^ ((srow >> 1) & 3)) * 8;
  const int kl1 = (kbp ^ (((64 + srow) >> 1) & 3)) * 8;
  const unsigned short* cr0 = CT + base + (size_t)(j0 + srow) * 512 + kl0;
  const unsigned short* cr1 = CT + base + (size_t)(j0 + 64 + srow) * 512 + kl1;
  const unsigned short* hr0 = H2T + base + (size_t)(d0 + srow) * 512 + kl0;
  const unsigned short* hr1 = H2T + base + (size_t)(d0 + 64 + srow) * 512 + kl1;

  GLOAD16(cr0, A0 + tid * 16);
  GLOAD16(cr1, A0 + 4096 + tid * 16);
  GLOAD16(hr0, B0 + tid * 16);
  GLOAD16(hr1, B0 + 4096 + tid * 16);

#pragma unroll 2
  for (int t = 0; t < 16; ++t) {
    char* Ac = (t & 1) ? A1 : A0;
    char* Bc = (t & 1) ? B1 : B0;
    if (t < 15) {
      char* An = (t & 1) ? A0 : A1;
      char* Bn = (t & 1) ? B0 : B1;
      const int kc = (t + 1) * 32;
      GLOAD16(cr0 + kc, An + tid * 16);
      GLOAD16(cr1 + kc, An + 4096 + tid * 16);
      GLOAD16(hr0 + kc, Bn + tid * 16);
      GLOAD16(hr1 + kc, Bn + 4096 + tid * 16);
      asm volatile("s_waitcnt vmcnt(4)" ::: "memory");
    } else {
      asm volatile("s_waitcnt vmcnt(0)" ::: "memory");
    }
    __builtin_amdgcn_s_barrier();
    short8 a[4], b[4];
#pragma unroll
    for (int f = 0; f < 4; ++f) a[f] = *(const short8*)(Ac + ra[f]);
#pragma unroll
    for (int f = 0; f < 4; ++f) b[f] = *(const short8*)(Bc + rb[f]);
#pragma unroll
    for (int mf = 0; mf < 4; ++mf)
#pragma unroll
      for (int nf = 0; nf < 4; ++nf)
        acc[mf][nf] = __builtin_amdgcn_mfma_f32_16x16x32_bf16(a[mf], b[nf], acc[mf][nf], 0, 0, 0);
    asm volatile("s_waitcnt lgkmcnt(0)" ::: "memory");
    __builtin_amdgcn_sched_barrier(0);
    __builtin_amdgcn_s_barrier();
  }
  const int jb = j0 + wm * 64 + (lane >> 4) * 4;
  const int db = d0 + wn * 64 + (lane & 15);
#pragma unroll
  for (int mf = 0; mf < 4; ++mf)
#pragma unroll
    for (int nf = 0; nf < 4; ++nf) {
      f32x4 vv = acc[mf][nf];
      float* op = out + base + (size_t)(jb + mf * 16) * 512 + db + nf * 16;
      op[0]    = vv.x;
      op[512]  = vv.y;
      op[1024] = vv.z;
      op[1536] = vv.w;
    }
}

extern "C" void kernel_launch(void* const* d_in, const int* in_sizes, int n_in,
                              void* d_out, int out_size, void* d_ws, size_t ws_size,
                              hipStream_t stream) {
  const float* input  = (const float*)d_in[0];
  const int*   adj    = (const int*)d_in[1];
  const float* query  = (const float*)d_in[3];
  const float* W_type = (const float*)d_in[4];
  const float* a_type = (const float*)d_in[5];
  const float* W1     = (const float*)d_in[6];
  const float* W2     = (const float*)d_in[7];
  float* out = (float*)d_out;

  char* ws = (char*)d_ws;
  float* galT  = (float*)(ws);                              //  393,216 B
  float* garT  = (float*)(ws + 393216);                     //  393,216 B
  unsigned short* uvbf = (unsigned short*)(ws + 786432);    //  393,216 B
  float* left  = (float*)(ws + 1179648);                    //  393,216 B
  float* right = (float*)(ws + 1572864);                    //  393,216 B
  unsigned short* Xbf = (unsigned short*)(ws + 2359296);    // 33,554,432 B
  unsigned short* h2T = (unsigned short*)(ws + 35913728);   // 33,554,432 B
  // partials alias h2T's region: all dead before the union kernel writes h2T
  float* rpart = (float*)(ws + 35913728);                   //  3,145,728 B
  float* gpart = (float*)(ws + 39059456);                   //  6,291,456 B
  float* upart = (float*)(ws + 45350912);                   //  3,145,728 B
  float* vpart = (float*)(ws + 48496640);                   //  3,145,728 B
  unsigned short* WT  = (unsigned short*)(ws + 69468160);   //    524,288 B
  // coefsT: its OWN region now (Xbf stays live for gemm1 inside the union kernel)
  unsigned short* coefsT = (unsigned short*)(ws + 69992448); // 33,554,432 B
  // total ws use: 103,546,880 B

  k_wt      <<<dim3(8, 8),      256, 0, stream>>>(W_type + (size_t)2 * 262144, WT);
  k_gate1   <<<dim3(16, 4, 3),  256, 0, stream>>>(query, W1, rpart);
  k_gate2   <<<dim3(16, 8, 3),  256, 0, stream>>>(rpart, W2, gpart);
  k_gate_fin<<<dim3(256, 3),    256, 0, stream>>>(gpart, a_type, galT, garT);
  k_uvp     <<<dim3(8, 8, 3),   256, 0, stream>>>(W_type, galT, garT, upart, vpart);
  k_uvsum   <<<dim3(64),        256, 0, stream>>>(upart, vpart, uvbf);
  k_lrm     <<<dim3(8, 64),     256, 0, stream>>>(input, uvbf, left, right, Xbf);
  k_g1smt   <<<dim3(3072),      256, 0, stream>>>(Xbf, WT, h2T, adj, left, right, coefsT);
  k_gemm2   <<<dim3(1024),      256, 0, stream>>>(coefsT, h2T, out);
}

// Round 14
// 188.093 us; speedup vs baseline: 1.1098x; 1.0042x over previous
//
#include <hip/hip_runtime.h>
#include <cstdint>

typedef __attribute__((ext_vector_type(8))) short short8;
typedef __attribute__((ext_vector_type(4))) float f32x4;

// ---------- helpers ----------
__device__ __forceinline__ unsigned short f2bf(float x) {
  unsigned int u = __float_as_uint(x);
  u += 0x7FFFu + ((u >> 16) & 1u);   // round-to-nearest-even
  return (unsigned short)(u >> 16);
}

#define GLOAD16(gsrc, ldst)                                                        \
  __builtin_amdgcn_global_load_lds(                                                \
      (const __attribute__((address_space(1))) void*)(gsrc),                       \
      (__attribute__((address_space(3))) void*)(ldst), 16, 0, 0)

// ---------- 0b. WT[d][k] = bf16(W2[k][d]) ----------
__global__ __launch_bounds__(256) void k_wt(const float* __restrict__ W,
                                            unsigned short* __restrict__ WT) {
  __shared__ float t[64][68];
  const int k0 = blockIdx.y * 64, d0 = blockIdx.x * 64;
  for (int idx = threadIdx.x; idx < 4096; idx += 256) {
    int r = idx >> 6, c = idx & 63;
    t[r][c] = W[(size_t)(k0 + r) * 512 + d0 + c];
  }
  __syncthreads();
  for (int idx = threadIdx.x; idx < 4096; idx += 256) {
    int r = idx >> 6, c = idx & 63;
    WT[(size_t)(d0 + r) * 512 + k0 + c] = f2bf(t[c][r]);
  }
}

// ---------- gate 1 ----------
__global__ __launch_bounds__(256) void k_gate1(const float* __restrict__ q,
                                               const float* __restrict__ W1,
                                               float* __restrict__ rpart) {
  const int c0 = blockIdx.x * 64;
  const int k0 = blockIdx.y * 128;
  const int t  = blockIdx.z;
  const int tid = threadIdx.x;
  const int lane = tid & 63;
  const int wcs = __builtin_amdgcn_readfirstlane(tid >> 6);
  __shared__ float qs[64][133];
  for (int idx = tid; idx < 2048; idx += 256) {
    int r = idx >> 5, c4 = (idx & 31) * 4;
    float4 f = *(const float4*)&q[(size_t)r * 512 + k0 + c4];
    qs[r][c4 + 0] = f.x; qs[r][c4 + 1] = f.y;
    qs[r][c4 + 2] = f.z; qs[r][c4 + 3] = f.w;
  }
  __syncthreads();
  const float* Wp = W1 + ((size_t)t * 512 + k0) * 1024 + c0 + wcs * 16;
  float acc[16] = {};
  for (int k = 0; k < 128; ++k) {
    float qr = qs[lane][k];
    const float* wr = Wp + (size_t)k * 1024;
    float4 w0 = *(const float4*)(wr);
    float4 w1 = *(const float4*)(wr + 4);
    float4 w2 = *(const float4*)(wr + 8);
    float4 w3 = *(const float4*)(wr + 12);
    acc[0]  = fmaf(qr, w0.x, acc[0]);  acc[1]  = fmaf(qr, w0.y, acc[1]);
    acc[2]  = fmaf(qr, w0.z, acc[2]);  acc[3]  = fmaf(qr, w0.w, acc[3]);
    acc[4]  = fmaf(qr, w1.x, acc[4]);  acc[5]  = fmaf(qr, w1.y, acc[5]);
    acc[6]  = fmaf(qr, w1.z, acc[6]);  acc[7]  = fmaf(qr, w1.w, acc[7]);
    acc[8]  = fmaf(qr, w2.x, acc[8]);  acc[9]  = fmaf(qr, w2.y, acc[9]);
    acc[10] = fmaf(qr, w2.z, acc[10]); acc[11] = fmaf(qr, w2.w, acc[11]);
    acc[12] = fmaf(qr, w3.x, acc[12]); acc[13] = fmaf(qr, w3.y, acc[13]);
    acc[14] = fmaf(qr, w3.z, acc[14]); acc[15] = fmaf(qr, w3.w, acc[15]);
  }
  float* rp = rpart + ((size_t)(t * 4 + blockIdx.y) * 1024 + c0 + wcs * 16) * 64 + lane;
#pragma unroll
  for (int cc = 0; cc < 16; ++cc) rp[(size_t)cc * 64] = acc[cc];
}

// ---------- gate 2 ----------
__global__ __launch_bounds__(256) void k_gate2(const float* __restrict__ rpart,
                                               const float* __restrict__ W2,
                                               float* __restrict__ gpart) {
  const int c0 = blockIdx.x * 64;
  const int k0 = blockIdx.y * 128;
  const int t  = blockIdx.z;
  const int tid = threadIdx.x;
  const int lane = tid & 63;
  const int wcs = __builtin_amdgcn_readfirstlane(tid >> 6);
  __shared__ float qs[64][133];
  for (int idx = tid; idx < 2048; idx += 256) {
    int kl = idx >> 4, n4 = (idx & 15) * 4;
    const float* rp = rpart + ((size_t)t * 4 * 1024 + k0 + kl) * 64 + n4;
    float4 a = *(const float4*)(rp);
    float4 b = *(const float4*)(rp + 65536);
    float4 c = *(const float4*)(rp + 131072);
    float4 d = *(const float4*)(rp + 196608);
    qs[n4 + 0][kl] = fmaxf(a.x + b.x + c.x + d.x, 0.f);
    qs[n4 + 1][kl] = fmaxf(a.y + b.y + c.y + d.y, 0.f);
    qs[n4 + 2][kl] = fmaxf(a.z + b.z + c.z + d.z, 0.f);
    qs[n4 + 3][kl] = fmaxf(a.w + b.w + c.w + d.w, 0.f);
  }
  __syncthreads();
  const float* Wp = W2 + ((size_t)t << 20) + (size_t)k0 * 1024 + c0 + wcs * 16;
  float acc[16] = {};
  for (int k = 0; k < 128; ++k) {
    float qr = qs[lane][k];
    const float* wr = Wp + (size_t)k * 1024;
    float4 w0 = *(const float4*)(wr);
    float4 w1 = *(const float4*)(wr + 4);
    float4 w2 = *(const float4*)(wr + 8);
    float4 w3 = *(const float4*)(wr + 12);
    acc[0]  = fmaf(qr, w0.x, acc[0]);  acc[1]  = fmaf(qr, w0.y, acc[1]);
    acc[2]  = fmaf(qr, w0.z, acc[2]);  acc[3]  = fmaf(qr, w0.w, acc[3]);
    acc[4]  = fmaf(qr, w1.x, acc[4]);  acc[5]  = fmaf(qr, w1.y, acc[5]);
    acc[6]  = fmaf(qr, w1.z, acc[6]);  acc[7]  = fmaf(qr, w1.w, acc[7]);
    acc[8]  = fmaf(qr, w2.x, acc[8]);  acc[9]  = fmaf(qr, w2.y, acc[9]);
    acc[10] = fmaf(qr, w2.z, acc[10]); acc[11] = fmaf(qr, w2.w, acc[11]);
    acc[12] = fmaf(qr, w3.x, acc[12]); acc[13] = fmaf(qr, w3.y, acc[13]);
    acc[14] = fmaf(qr, w3.z, acc[14]); acc[15] = fmaf(qr, w3.w, acc[15]);
  }
  float* gp = gpart + ((size_t)(t * 8 + blockIdx.y) * 1024 + c0 + wcs * 16) * 64 + lane;
#pragma unroll
  for (int cc = 0; cc < 16; ++cc) gp[(size_t)cc * 64] = acc[cc];
}

// ---------- gate fin ----------
__global__ __launch_bounds__(256) void k_gate_fin(const float* __restrict__ gpart,
                                                  const float* __restrict__ a_type,
                                                  float* __restrict__ galT,
                                                  float* __restrict__ garT) {
  const int t = blockIdx.y;
  const int n = threadIdx.x & 63;
  const int mg = blockIdx.x * 4 + (threadIdx.x >> 6);
  float s = 0.f;
#pragma unroll
  for (int kc = 0; kc < 8; ++kc)
    s += gpart[((size_t)(t * 8 + kc) * 1024 + mg) * 64 + n];
  float g = 1.f / (1.f + __expf(-s));
  float ga = g * a_type[t * 1024 + mg];
  if (mg < 512) galT[((size_t)t * 512 + mg) * 64 + n] = ga;
  else          garT[((size_t)t * 512 + (mg - 512)) * 64 + n] = ga;
}

// ---------- u,v split-d partials ----------
__global__ __launch_bounds__(256) void k_uvp(const float* __restrict__ W,
                                             const float* __restrict__ galT,
                                             const float* __restrict__ garT,
                                             float* __restrict__ upart,
                                             float* __restrict__ vpart) {
  const int k0 = blockIdx.x * 64;
  const int d0 = blockIdx.y * 64;
  const int t  = blockIdx.z;
  const int tid = threadIdx.x;
  const int lane = tid & 63;
  const int wk = (tid >> 6) * 16;
  __shared__ float gal_s[64][64];
  __shared__ float gar_s[64][64];
  __shared__ float W_s[64][64];
  for (int idx = tid; idx < 1024; idx += 256) {
    int d = idx >> 4, n4 = (idx & 15) * 4;
    *(float4*)&gal_s[d][n4] = *(const float4*)&galT[((size_t)t * 512 + d0 + d) * 64 + n4];
    *(float4*)&gar_s[d][n4] = *(const float4*)&garT[((size_t)t * 512 + d0 + d) * 64 + n4];
    int k = idx >> 4, d4 = (idx & 15) * 4;
    *(float4*)&W_s[k][d4] = *(const float4*)&W[((size_t)t * 512 + k0 + k) * 512 + d0 + d4];
  }
  __syncthreads();
  float au[16] = {}, av[16] = {};
  for (int dq = 0; dq < 64; dq += 4) {
    float g1[4], g2[4];
#pragma unroll
    for (int e = 0; e < 4; ++e) { g1[e] = gal_s[dq + e][lane]; g2[e] = gar_s[dq + e][lane]; }
#pragma unroll
    for (int kk = 0; kk < 16; ++kk) {
      float4 wv = *(const float4*)&W_s[wk + kk][dq];
      au[kk] = fmaf(wv.x, g1[0], fmaf(wv.y, g1[1], fmaf(wv.z, g1[2], fmaf(wv.w, g1[3], au[kk]))));
      av[kk] = fmaf(wv.x, g2[0], fmaf(wv.y, g2[1], fmaf(wv.z, g2[2], fmaf(wv.w, g2[3], av[kk]))));
    }
  }
  const size_t ob = ((size_t)((t * 8 + blockIdx.y) * 64 + lane)) * 512 + k0 + wk;
#pragma unroll
  for (int q = 0; q < 4; ++q) {
    *(float4*)&upart[ob + q * 4] = make_float4(au[q*4], au[q*4+1], au[q*4+2], au[q*4+3]);
    *(float4*)&vpart[ob + q * 4] = make_float4(av[q*4], av[q*4+1], av[q*4+2], av[q*4+3]);
  }
}

// ---------- sum uv partials -> uvbf ----------
__global__ __launch_bounds__(256) void k_uvsum(const float* __restrict__ upart,
                                               const float* __restrict__ vpart,
                                               unsigned short* __restrict__ uvbf) {
  const int n = blockIdx.x;
  for (int idx = threadIdx.x; idx < 768; idx += 256) {
    int col = idx >> 7;
    int k4 = (idx & 127) * 4;
    const float* base = (col < 3)
        ? upart + ((size_t)(col * 8) * 64 + n) * 512 + k4
        : vpart + ((size_t)((col - 3) * 8) * 64 + n) * 512 + k4;
    float4 sv = {0.f, 0.f, 0.f, 0.f};
#pragma unroll
    for (int dc = 0; dc < 8; ++dc) {
      float4 t = *(const float4*)(base + (size_t)dc * 32768);
      sv.x += t.x; sv.y += t.y; sv.z += t.z; sv.w += t.w;
    }
    ushort4 o;
    o.x = f2bf(sv.x); o.y = f2bf(sv.y); o.z = f2bf(sv.z); o.w = f2bf(sv.w);
    *(ushort4*)&uvbf[((size_t)n * 6 + col) * 512 + k4] = o;
  }
}

// ---------- k_lrm ----------
__global__ __launch_bounds__(256) void k_lrm(const float* __restrict__ x,
                                             const unsigned short* __restrict__ uvbf,
                                             float* __restrict__ left,
                                             float* __restrict__ right,
                                             unsigned short* __restrict__ Xbf) {
  const int n  = blockIdx.y;
  const int i0 = blockIdx.x * 64;
  const int tid = threadIdx.x;
  const int lane = tid & 63, wid = tid >> 6;
  __shared__ unsigned short uvs[16][520];
  __shared__ __attribute__((aligned(16))) char As[4096];

  for (int idx = tid; idx < 16 * 64; idx += 256) {
    int col = idx >> 6, k8 = (idx & 63) * 8;
    ushort4 z0 = {0, 0, 0, 0}, z1 = {0, 0, 0, 0};
    if (col < 6) {
      const unsigned short* p = uvbf + ((size_t)n * 6 + col) * 512 + k8;
      z0 = *(const ushort4*)p;
      z1 = *(const ushort4*)(p + 4);
    }
    *(ushort4*)&uvs[col][k8]     = z0;
    *(ushort4*)&uvs[col][k8 + 4] = z1;
  }
  const int row = tid >> 2, sub = tid & 3;
  const float* gp = x + ((size_t)n * 512 + i0 + row) * 512 + sub * 8;
  unsigned short* xp = Xbf + ((size_t)n * 512 + i0 + row) * 512 + sub * 8;
  const int lds_off = row * 64 + ((sub ^ (row & 3)) << 4);
  const int arow = wid * 16 + (lane & 15);
  const int a_off = arow * 64 + (((lane >> 4) ^ (arow & 3)) << 4);
  f32x4 acc = {0.f, 0.f, 0.f, 0.f};
  float4 f0 = *(const float4*)(gp);
  float4 f1 = *(const float4*)(gp + 4);
  __syncthreads();
  for (int s = 0; s < 16; ++s) {
    uint4 pk;
    pk.x = ((unsigned)f2bf(f0.y) << 16) | f2bf(f0.x);
    pk.y = ((unsigned)f2bf(f0.w) << 16) | f2bf(f0.z);
    pk.z = ((unsigned)f2bf(f1.y) << 16) | f2bf(f1.x);
    pk.w = ((unsigned)f2bf(f1.w) << 16) | f2bf(f1.z);
    if (s < 15) {
      f0 = *(const float4*)(gp + (s + 1) * 32);
      f1 = *(const float4*)(gp + (s + 1) * 32 + 4);
    }
    *(uint4*)(xp + s * 32) = pk;
    *(uint4*)(As + lds_off) = pk;
    __syncthreads();
    short8 a = *(const short8*)(As + a_off);
    short8 b = *(const short8*)&uvs[lane & 15][s * 32 + (lane >> 4) * 8];
    acc = __builtin_amdgcn_mfma_f32_16x16x32_bf16(a, b, acc, 0, 0, 0);
    __syncthreads();
  }
  const int col = lane & 15;
  if (col < 6) {
    float* dst = (col < 3) ? left : right;
    const int t = (col < 3) ? col : col - 3;
    const int i = i0 + wid * 16 + ((lane >> 4) << 2);
    float* p = dst + ((size_t)t * 64 + n) * 512 + i;
    p[0] = acc.x; p[1] = acc.y; p[2] = acc.z; p[3] = acc.w;
  }
}

// ---------- union member A: GEMM1 body (2-phase dbuf pipeline) ----------
// n-map permuted so this block's XCD (= 3*bid_g mod 8 under bid%8 round-robin)
// equals n&7 — matching where round-10-style gemm2 reads h2T[n].
__device__ __forceinline__ void gemm1_body(int s, char* smem,
                                           const unsigned short* __restrict__ X,
                                           const unsigned short* __restrict__ WT,
                                           unsigned short* __restrict__ h2T) {
  char* A0 = smem;
  char* A1 = smem + 8192;
  char* B0 = smem + 16384;
  char* B1 = smem + 24576;
  const int n  = ((s >> 7) << 3) | ((3 * (s & 7)) & 7);
  const int jj = (s >> 3) & 15;
  const int i0 = (jj >> 2) * 128;
  const int d0 = (jj & 3) * 128;
  const int tid = threadIdx.x;
  const int lane = tid & 63, w = tid >> 6;
  const int wm = w >> 1, wn = w & 1;
  const int srow = tid >> 2;
  const int kbp  = tid & 3;
  f32x4 acc[4][4];
#pragma unroll
  for (int a = 0; a < 4; ++a)
#pragma unroll
    for (int b = 0; b < 4; ++b) acc[a][b] = (f32x4){0.f, 0.f, 0.f, 0.f};

  const size_t xbase = (size_t)n * 262144;
  int ra[4], rb[4];
#pragma unroll
  for (int f = 0; f < 4; ++f) {
    int row = wm * 64 + f * 16 + (lane & 15);
    ra[f] = row * 64 + (((lane >> 4) ^ ((row >> 1) & 3)) << 4);
    int rowb = wn * 64 + f * 16 + (lane & 15);
    rb[f] = rowb * 64 + (((lane >> 4) ^ ((rowb >> 1) & 3)) << 4);
  }
  const int kl0 = (kbp ^ ((srow >> 1) & 3)) * 8;
  const int kl1 = (kbp ^ (((64 + srow) >> 1) & 3)) * 8;
  const unsigned short* xr0 = X + xbase + (size_t)(i0 + srow) * 512 + kl0;
  const unsigned short* xr1 = X + xbase + (size_t)(i0 + 64 + srow) * 512 + kl1;
  const unsigned short* wr0 = WT + (size_t)(d0 + srow) * 512 + kl0;
  const unsigned short* wr1 = WT + (size_t)(d0 + 64 + srow) * 512 + kl1;

  GLOAD16(xr0, A0 + tid * 16);
  GLOAD16(xr1, A0 + 4096 + tid * 16);
  GLOAD16(wr0, B0 + tid * 16);
  GLOAD16(wr1, B0 + 4096 + tid * 16);

#pragma unroll 2
  for (int t = 0; t < 16; ++t) {
    char* Ac = (t & 1) ? A1 : A0;
    char* Bc = (t & 1) ? B1 : B0;
    if (t < 15) {
      char* An = (t & 1) ? A0 : A1;
      char* Bn = (t & 1) ? B0 : B1;
      const int kc = (t + 1) * 32;
      GLOAD16(xr0 + kc, An + tid * 16);
      GLOAD16(xr1 + kc, An + 4096 + tid * 16);
      GLOAD16(wr0 + kc, Bn + tid * 16);
      GLOAD16(wr1 + kc, Bn + 4096 + tid * 16);
      asm volatile("s_waitcnt vmcnt(4)" ::: "memory");
    } else {
      asm volatile("s_waitcnt vmcnt(0)" ::: "memory");
    }
    __builtin_amdgcn_s_barrier();
    short8 a[4], b[4];
#pragma unroll
    for (int f = 0; f < 4; ++f) a[f] = *(const short8*)(Ac + ra[f]);
#pragma unroll
    for (int f = 0; f < 4; ++f) b[f] = *(const short8*)(Bc + rb[f]);
#pragma unroll
    for (int mf = 0; mf < 4; ++mf)
#pragma unroll
      for (int nf = 0; nf < 4; ++nf)
        acc[mf][nf] = __builtin_amdgcn_mfma_f32_16x16x32_bf16(a[mf], b[nf], acc[mf][nf], 0, 0, 0);
    asm volatile("s_waitcnt lgkmcnt(0)" ::: "memory");
    __builtin_amdgcn_sched_barrier(0);
    __builtin_amdgcn_s_barrier();
  }
  unsigned short (*Ct)[136] = (unsigned short (*)[136])smem;
#pragma unroll
  for (int mf = 0; mf < 4; ++mf)
#pragma unroll
    for (int nf = 0; nf < 4; ++nf) {
      f32x4 vv = acc[mf][nf];
      int dl = wn * 64 + nf * 16 + (lane & 15);
      int il = wm * 64 + mf * 16 + ((lane >> 4) << 2);
      ushort4 pk;
      pk.x = f2bf(vv.x); pk.y = f2bf(vv.y); pk.z = f2bf(vv.z); pk.w = f2bf(vv.w);
      *(ushort4*)&Ct[dl][il] = pk;
    }
  __syncthreads();
  const size_t obase = xbase + (size_t)d0 * 512 + i0;
#pragma unroll
  for (int q = 0; q < 8; ++q) {
    int f = q * 2048 + tid * 8;
    int dl = f >> 7, il = f & 127;
    *(uint4*)&h2T[obase + (size_t)dl * 512 + il] = *(const uint4*)&Ct[dl][il];
  }
}

// ---------- union member B: fused softmax+transpose body (online softmax) ----------
__device__ __forceinline__ void smt_body(int m, char* smem,
                                         const int* __restrict__ adj,
                                         const float* __restrict__ left,
                                         const float* __restrict__ right,
                                         unsigned short* __restrict__ ct) {
  float (*rs_s)[49] = (float (*)[49])smem;
  float (*ls)[16]   = (float (*)[16])(smem + 6272);
  unsigned short (*tile)[520] = (unsigned short (*)[520])(smem + 6464);
  const int n  = m >> 5;
  const int i0 = (m & 31) * 16;
  const int tid = threadIdx.x;
  const int lane = tid & 63, wid = tid >> 6;
  const int l15 = lane & 15;
  const int il  = wid * 4 + (lane >> 4);
  for (int idx = tid; idx < 1536; idx += 256) {
    int t = idx >> 9, j = idx & 511;
    rs_s[j & 31][t * 16 + (j >> 5)] = right[((size_t)t * 64 + n) * 512 + j];
  }
  if (tid < 48) {
    int t = tid >> 4, ii = tid & 15;
    ls[t][ii] = left[((size_t)t * 64 + n) * 512 + i0 + ii];
  }
  __syncthreads();
  const int* adjb = adj + ((size_t)(n * 512 + i0 + il)) * 512;
  int4 A[4], B[4];
#pragma unroll
  for (int q = 0; q < 4; ++q) {
    const int* p = adjb + q * 128 + l15 * 8;
    A[q] = *(const int4*)p;
    B[q] = *(const int4*)(p + 4);
  }
  const float l0 = ls[0][il], l1 = ls[1][il], l2 = ls[2][il];
  const int base0 = ((l15 & 3) * 8) * 49 + (l15 >> 2);
  const float* rsf = (const float*)rs_s;
  float s[4][8];
  float mloc = -3.0e38f;
#pragma unroll
  for (int q = 0; q < 4; ++q) {
    int tv[8] = {A[q].x, A[q].y, A[q].z, A[q].w, B[q].x, B[q].y, B[q].z, B[q].w};
#pragma unroll
    for (int x = 0; x < 8; ++x) {
      int t = tv[x];
      int tt = (t > 0) ? (t - 1) : 0;
      float lv = (t >= 2) ? ((t == 3) ? l2 : l1) : l0;
      float r = rsf[base0 + tt * 16 + (x * 49 + q * 4)];
      float sv = lv + r;
      sv = (sv >= 0.f) ? sv : 0.2f * sv;
      sv = (t == 0) ? -9.0e15f : sv;
      s[q][x] = sv;
      mloc = fmaxf(mloc, sv);
    }
  }
  float z = 0.f;
#pragma unroll
  for (int q = 0; q < 4; ++q)
#pragma unroll
    for (int x = 0; x < 8; ++x) {
      float e = __expf(s[q][x] - mloc);
      s[q][x] = e;
      z += e;
    }
  float mm = mloc;
#pragma unroll
  for (int k = 1; k <= 8; k <<= 1) {
    float mo = __shfl_xor(mm, k);
    float zo = __shfl_xor(z, k);
    float mn = fmaxf(mm, mo);
    z = z * __expf(mm - mn) + zo * __expf(mo - mn);
    mm = mn;
  }
  const float factor = __expf(mloc - mm) / z;
#pragma unroll
  for (int q = 0; q < 4; ++q) {
    uint4 pk;
    pk.x = ((unsigned)f2bf(s[q][1] * factor) << 16) | f2bf(s[q][0] * factor);
    pk.y = ((unsigned)f2bf(s[q][3] * factor) << 16) | f2bf(s[q][2] * factor);
    pk.z = ((unsigned)f2bf(s[q][5] * factor) << 16) | f2bf(s[q][4] * factor);
    pk.w = ((unsigned)f2bf(s[q][7] * factor) << 16) | f2bf(s[q][6] * factor);
    *(uint4*)&tile[il][q * 128 + l15 * 8] = pk;
  }
  __syncthreads();
  unsigned short* ob = ct + (size_t)n * 262144 + i0;
#pragma unroll
  for (int pass = 0; pass < 4; ++pass) {
    int j = pass * 128 + (tid >> 1);
    int i8 = (tid & 1) * 8;
    uint4 o;
    o.x = (unsigned)tile[i8 + 0][j] | ((unsigned)tile[i8 + 1][j] << 16);
    o.y = (unsigned)tile[i8 + 2][j] | ((unsigned)tile[i8 + 3][j] << 16);
    o.z = (unsigned)tile[i8 + 4][j] | ((unsigned)tile[i8 + 5][j] << 16);
    o.w = (unsigned)tile[i8 + 6][j] | ((unsigned)tile[i8 + 7][j] << 16);
    *(uint4*)&ob[(size_t)j * 512 + i8] = o;
  }
}

// ---------- union kernel: 3072 blocks, bid%3==0 -> gemm1, else -> smt ----------
__global__ __launch_bounds__(256) void k_g1smt(const unsigned short* __restrict__ X,
                                               const unsigned short* __restrict__ WT,
                                               unsigned short* __restrict__ h2T,
                                               const int* __restrict__ adj,
                                               const float* __restrict__ left,
                                               const float* __restrict__ right,
                                               unsigned short* __restrict__ ct) {
  __shared__ __attribute__((aligned(16))) char smem[34816];
  const int bid = blockIdx.x;
  const int g = bid / 3;
  const int r = bid - g * 3;
  if (r == 0) gemm1_body(g, smem, X, WT, h2T);
  else        smt_body(g * 2 + (r - 1), smem, adj, left, right, ct);
}

// ---------- GEMM2: out[n][j][d] = coefsT[n] @ h2T[n]^T ; round-10 mapping ----------
__global__ __launch_bounds__(256) void k_gemm2(const unsigned short* __restrict__ CT,
                                               const unsigned short* __restrict__ H2T,
                                               float* __restrict__ out) {
  __shared__ __attribute__((aligned(16))) char smem[32768];
  char* A0 = smem;
  char* A1 = smem + 8192;
  char* B0 = smem + 16384;
  char* B1 = smem + 24576;
  const int s = blockIdx.x;
  const int n  = ((s >> 7) << 3) | (s & 7);
  const int jj = (s >> 3) & 15;
  const int j0 = (jj >> 2) * 128;
  const int d0 = (jj & 3) * 128;
  const int tid = threadIdx.x;
  const int lane = tid & 63, w = tid >> 6;
  const int wm = w >> 1, wn = w & 1;
  const int srow = tid >> 2;
  const int kbp  = tid & 3;
  f32x4 acc[4][4];
#pragma unroll
  for (int a = 0; a < 4; ++a)
#pragma unroll
    for (int b = 0; b < 4; ++b) acc[a][b] = (f32x4){0.f, 0.f, 0.f, 0.f};

  const size_t base = (size_t)n * 262144;
  int ra[4], rb[4];
#pragma unroll
  for (int f = 0; f < 4; ++f) {
    int row = wm * 64 + f * 16 + (lane & 15);
    ra[f] = row * 64 + (((lane >> 4) ^ ((row >> 1) & 3)) << 4);
    int rowb = wn * 64 + f * 16 + (lane & 15);
    rb[f] = rowb * 64 + (((lane >> 4) ^ ((rowb >> 1) & 3)) << 4);
  }
  const int kl0 = (kbp ^ ((srow >> 1) & 3)) * 8;
  const int kl1 = (kbp ^ (((64 + srow) >> 1) & 3)) * 8;
  const unsigned short* cr0 = CT + base + (size_t)(j0 + srow) * 512 + kl0;
  const unsigned short* cr1 = CT + base + (size_t)(j0 + 64 + srow) * 512 + kl1;
  const unsigned short* hr0 = H2T + base + (size_t)(d0 + srow) * 512 + kl0;
  const unsigned short* hr1 = H2T + base + (size_t)(d0 + 64 + srow) * 512 + kl1;

  GLOAD16(cr0, A0 + tid * 16);
  GLOAD16(cr1, A0 + 4096 + tid * 16);
  GLOAD16(hr0, B0 + tid * 16);
  GLOAD16(hr1, B0 + 4096 + tid * 16);

#pragma unroll 2
  for (int t = 0; t < 16; ++t) {
    char* Ac = (t & 1) ? A1 : A0;
    char* Bc = (t & 1) ? B1 : B0;
    if (t < 15) {
      char* An = (t & 1) ? A0 : A1;
      char* Bn = (t & 1) ? B0 : B1;
      const int kc = (t + 1) * 32;
      GLOAD16(cr0 + kc, An + tid * 16);
      GLOAD16(cr1 + kc, An + 4096 + tid * 16);
      GLOAD16(hr0 + kc, Bn + tid * 16);
      GLOAD16(hr1 + kc, Bn + 4096 + tid * 16);
      asm volatile("s_waitcnt vmcnt(4)" ::: "memory");
    } else {
      asm volatile("s_waitcnt vmcnt(0)" ::: "memory");
    }
    __builtin_amdgcn_s_barrier();
    short8 a[4], b[4];
#pragma unroll
    for (int f = 0; f < 4; ++f) a[f] = *(const short8*)(Ac + ra[f]);
#pragma unroll
    for (int f = 0; f < 4; ++f) b[f] = *(const short8*)(Bc + rb[f]);
#pragma unroll
    for (int mf = 0; mf < 4; ++mf)
#pragma unroll
      for (int nf = 0; nf < 4; ++nf)
        acc[mf][nf] = __builtin_amdgcn_mfma_f32_16x16x32_bf16(a[mf], b[nf], acc[mf][nf], 0, 0, 0);
    asm volatile("s_waitcnt lgkmcnt(0)" ::: "memory");
    __builtin_amdgcn_sched_barrier(0);
    __builtin_amdgcn_s_barrier();
  }
  const int jb = j0 + wm * 64 + (lane >> 4) * 4;
  const int db = d0 + wn * 64 + (lane & 15);
#pragma unroll
  for (int mf = 0; mf < 4; ++mf)
#pragma unroll
    for (int nf = 0; nf < 4; ++nf) {
      f32x4 vv = acc[mf][nf];
      float* op = out + base + (size_t)(jb + mf * 16) * 512 + db + nf * 16;
      op[0]    = vv.x;
      op[512]  = vv.y;
      op[1024] = vv.z;
      op[1536] = vv.w;
    }
}

extern "C" void kernel_launch(void* const* d_in, const int* in_sizes, int n_in,
                              void* d_out, int out_size, void* d_ws, size_t ws_size,
                              hipStream_t stream) {
  const float* input  = (const float*)d_in[0];
  const int*   adj    = (const int*)d_in[1];
  const float* query  = (const float*)d_in[3];
  const float* W_type = (const float*)d_in[4];
  const float* a_type = (const float*)d_in[5];
  const float* W1     = (const float*)d_in[6];
  const float* W2     = (const float*)d_in[7];
  float* out = (float*)d_out;

  char* ws = (char*)d_ws;
  float* galT  = (float*)(ws);                              //  393,216 B
  float* garT  = (float*)(ws + 393216);                     //  393,216 B
  unsigned short* uvbf = (unsigned short*)(ws + 786432);    //  393,216 B
  float* left  = (float*)(ws + 1179648);                    //  393,216 B
  float* right = (float*)(ws + 1572864);                    //  393,216 B
  unsigned short* Xbf = (unsigned short*)(ws + 2359296);    // 33,554,432 B
  unsigned short* h2T = (unsigned short*)(ws + 35913728);   // 33,554,432 B
  // partials alias h2T's region: all dead before the union kernel writes h2T
  float* rpart = (float*)(ws + 35913728);                   //  3,145,728 B
  float* gpart = (float*)(ws + 39059456);                   //  6,291,456 B
  float* upart = (float*)(ws + 45350912);                   //  3,145,728 B
  float* vpart = (float*)(ws + 48496640);                   //  3,145,728 B
  unsigned short* WT  = (unsigned short*)(ws + 69468160);   //    524,288 B
  unsigned short* coefsT = (unsigned short*)(ws + 69992448); // 33,554,432 B
  // total ws use: 103,546,880 B

  k_wt      <<<dim3(8, 8),      256, 0, stream>>>(W_type + (size_t)2 * 262144, WT);
  k_gate1   <<<dim3(16, 4, 3),  256, 0, stream>>>(query, W1, rpart);
  k_gate2   <<<dim3(16, 8, 3),  256, 0, stream>>>(rpart, W2, gpart);
  k_gate_fin<<<dim3(256, 3),    256, 0, stream>>>(gpart, a_type, galT, garT);
  k_uvp     <<<dim3(8, 8, 3),   256, 0, stream>>>(W_type, galT, garT, upart, vpart);
  k_uvsum   <<<dim3(64),        256, 0, stream>>>(upart, vpart, uvbf);
  k_lrm     <<<dim3(8, 64),     256, 0, stream>>>(input, uvbf, left, right, Xbf);
  k_g1smt   <<<dim3(3072),      256, 0, stream>>>(Xbf, WT, h2T, adj, left, right, coefsT);
  k_gemm2   <<<dim3(1024),      256, 0, stream>>>(coefsT, h2T, out);
}

// Round 16
// 183.947 us; speedup vs baseline: 1.1348x; 1.0225x over previous
//
#include <hip/hip_runtime.h>
#include <cstdint>

typedef __attribute__((ext_vector_type(8))) short short8;
typedef __attribute__((ext_vector_type(4))) float f32x4;

// ---------- helpers ----------
__device__ __forceinline__ unsigned short f2bf(float x) {
  unsigned int u = __float_as_uint(x);
  u += 0x7FFFu + ((u >> 16) & 1u);   // round-to-nearest-even
  return (unsigned short)(u >> 16);
}

#define GLOAD16(gsrc, ldst)                                                        \
  __builtin_amdgcn_global_load_lds(                                                \
      (const __attribute__((address_space(1))) void*)(gsrc),                       \
      (__attribute__((address_space(3))) void*)(ldst), 16, 0, 0)

// ---------- 0b. WT[d][k] = bf16(W2[k][d]) ----------
__global__ __launch_bounds__(256) void k_wt(const float* __restrict__ W,
                                            unsigned short* __restrict__ WT) {
  __shared__ float t[64][68];
  const int k0 = blockIdx.y * 64, d0 = blockIdx.x * 64;
  for (int idx = threadIdx.x; idx < 4096; idx += 256) {
    int r = idx >> 6, c = idx & 63;
    t[r][c] = W[(size_t)(k0 + r) * 512 + d0 + c];
  }
  __syncthreads();
  for (int idx = threadIdx.x; idx < 4096; idx += 256) {
    int r = idx >> 6, c = idx & 63;
    WT[(size_t)(d0 + r) * 512 + k0 + c] = f2bf(t[c][r]);
  }
}

// ---------- gate 1 ----------
// __launch_bounds__(256,4): VGPR cap 128 so acc[16]+w[16] stay in registers.
__global__ __launch_bounds__(256, 4) void k_gate1(const float* __restrict__ q,
                                                  const float* __restrict__ W1,
                                                  float* __restrict__ rpart) {
  const int c0 = blockIdx.x * 64;
  const int k0 = blockIdx.y * 128;
  const int t  = blockIdx.z;
  const int tid = threadIdx.x;
  const int lane = tid & 63;
  const int wcs = __builtin_amdgcn_readfirstlane(tid >> 6);
  __shared__ float qs[64][133];
  for (int idx = tid; idx < 2048; idx += 256) {
    int r = idx >> 5, c4 = (idx & 31) * 4;
    float4 f = *(const float4*)&q[(size_t)r * 512 + k0 + c4];
    qs[r][c4 + 0] = f.x; qs[r][c4 + 1] = f.y;
    qs[r][c4 + 2] = f.z; qs[r][c4 + 3] = f.w;
  }
  __syncthreads();
  const float* Wp = W1 + ((size_t)t * 512 + k0) * 1024 + c0 + wcs * 16;
  float acc[16] = {};
  for (int k = 0; k < 128; ++k) {
    float qr = qs[lane][k];
    const float* wr = Wp + (size_t)k * 1024;
    float4 w0 = *(const float4*)(wr);
    float4 w1 = *(const float4*)(wr + 4);
    float4 w2 = *(const float4*)(wr + 8);
    float4 w3 = *(const float4*)(wr + 12);
    acc[0]  = fmaf(qr, w0.x, acc[0]);  acc[1]  = fmaf(qr, w0.y, acc[1]);
    acc[2]  = fmaf(qr, w0.z, acc[2]);  acc[3]  = fmaf(qr, w0.w, acc[3]);
    acc[4]  = fmaf(qr, w1.x, acc[4]);  acc[5]  = fmaf(qr, w1.y, acc[5]);
    acc[6]  = fmaf(qr, w1.z, acc[6]);  acc[7]  = fmaf(qr, w1.w, acc[7]);
    acc[8]  = fmaf(qr, w2.x, acc[8]);  acc[9]  = fmaf(qr, w2.y, acc[9]);
    acc[10] = fmaf(qr, w2.z, acc[10]); acc[11] = fmaf(qr, w2.w, acc[11]);
    acc[12] = fmaf(qr, w3.x, acc[12]); acc[13] = fmaf(qr, w3.y, acc[13]);
    acc[14] = fmaf(qr, w3.z, acc[14]); acc[15] = fmaf(qr, w3.w, acc[15]);
  }
  float* rp = rpart + ((size_t)(t * 4 + blockIdx.y) * 1024 + c0 + wcs * 16) * 64 + lane;
#pragma unroll
  for (int cc = 0; cc < 16; ++cc) rp[(size_t)cc * 64] = acc[cc];
}

// ---------- gate 2 ----------
__global__ __launch_bounds__(256, 4) void k_gate2(const float* __restrict__ rpart,
                                                  const float* __restrict__ W2,
                                                  float* __restrict__ gpart) {
  const int c0 = blockIdx.x * 64;
  const int k0 = blockIdx.y * 128;
  const int t  = blockIdx.z;
  const int tid = threadIdx.x;
  const int lane = tid & 63;
  const int wcs = __builtin_amdgcn_readfirstlane(tid >> 6);
  __shared__ float qs[64][133];
  for (int idx = tid; idx < 2048; idx += 256) {
    int kl = idx >> 4, n4 = (idx & 15) * 4;
    const float* rp = rpart + ((size_t)t * 4 * 1024 + k0 + kl) * 64 + n4;
    float4 a = *(const float4*)(rp);
    float4 b = *(const float4*)(rp + 65536);
    float4 c = *(const float4*)(rp + 131072);
    float4 d = *(const float4*)(rp + 196608);
    qs[n4 + 0][kl] = fmaxf(a.x + b.x + c.x + d.x, 0.f);
    qs[n4 + 1][kl] = fmaxf(a.y + b.y + c.y + d.y, 0.f);
    qs[n4 + 2][kl] = fmaxf(a.z + b.z + c.z + d.z, 0.f);
    qs[n4 + 3][kl] = fmaxf(a.w + b.w + c.w + d.w, 0.f);
  }
  __syncthreads();
  const float* Wp = W2 + ((size_t)t << 20) + (size_t)k0 * 1024 + c0 + wcs * 16;
  float acc[16] = {};
  for (int k = 0; k < 128; ++k) {
    float qr = qs[lane][k];
    const float* wr = Wp + (size_t)k * 1024;
    float4 w0 = *(const float4*)(wr);
    float4 w1 = *(const float4*)(wr + 4);
    float4 w2 = *(const float4*)(wr + 8);
    float4 w3 = *(const float4*)(wr + 12);
    acc[0]  = fmaf(qr, w0.x, acc[0]);  acc[1]  = fmaf(qr, w0.y, acc[1]);
    acc[2]  = fmaf(qr, w0.z, acc[2]);  acc[3]  = fmaf(qr, w0.w, acc[3]);
    acc[4]  = fmaf(qr, w1.x, acc[4]);  acc[5]  = fmaf(qr, w1.y, acc[5]);
    acc[6]  = fmaf(qr, w1.z, acc[6]);  acc[7]  = fmaf(qr, w1.w, acc[7]);
    acc[8]  = fmaf(qr, w2.x, acc[8]);  acc[9]  = fmaf(qr, w2.y, acc[9]);
    acc[10] = fmaf(qr, w2.z, acc[10]); acc[11] = fmaf(qr, w2.w, acc[11]);
    acc[12] = fmaf(qr, w3.x, acc[12]); acc[13] = fmaf(qr, w3.y, acc[13]);
    acc[14] = fmaf(qr, w3.z, acc[14]); acc[15] = fmaf(qr, w3.w, acc[15]);
  }
  float* gp = gpart + ((size_t)(t * 8 + blockIdx.y) * 1024 + c0 + wcs * 16) * 64 + lane;
#pragma unroll
  for (int cc = 0; cc < 16; ++cc) gp[(size_t)cc * 64] = acc[cc];
}

// ---------- gate fin ----------
__global__ __launch_bounds__(256) void k_gate_fin(const float* __restrict__ gpart,
                                                  const float* __restrict__ a_type,
                                                  float* __restrict__ galT,
                                                  float* __restrict__ garT) {
  const int t = blockIdx.y;
  const int n = threadIdx.x & 63;
  const int mg = blockIdx.x * 4 + (threadIdx.x >> 6);
  float s = 0.f;
#pragma unroll
  for (int kc = 0; kc < 8; ++kc)
    s += gpart[((size_t)(t * 8 + kc) * 1024 + mg) * 64 + n];
  float g = 1.f / (1.f + __expf(-s));
  float ga = g * a_type[t * 1024 + mg];
  if (mg < 512) galT[((size_t)t * 512 + mg) * 64 + n] = ga;
  else          garT[((size_t)t * 512 + (mg - 512)) * 64 + n] = ga;
}

// ---------- u,v split-d partials ----------
__global__ __launch_bounds__(256, 4) void k_uvp(const float* __restrict__ W,
                                                const float* __restrict__ galT,
                                                const float* __restrict__ garT,
                                                float* __restrict__ upart,
                                                float* __restrict__ vpart) {
  const int k0 = blockIdx.x * 64;
  const int d0 = blockIdx.y * 64;
  const int t  = blockIdx.z;
  const int tid = threadIdx.x;
  const int lane = tid & 63;
  const int wk = (tid >> 6) * 16;
  __shared__ float gal_s[64][64];
  __shared__ float gar_s[64][64];
  __shared__ float W_s[64][64];
  for (int idx = tid; idx < 1024; idx += 256) {
    int d = idx >> 4, n4 = (idx & 15) * 4;
    *(float4*)&gal_s[d][n4] = *(const float4*)&galT[((size_t)t * 512 + d0 + d) * 64 + n4];
    *(float4*)&gar_s[d][n4] = *(const float4*)&garT[((size_t)t * 512 + d0 + d) * 64 + n4];
    int k = idx >> 4, d4 = (idx & 15) * 4;
    *(float4*)&W_s[k][d4] = *(const float4*)&W[((size_t)t * 512 + k0 + k) * 512 + d0 + d4];
  }
  __syncthreads();
  float au[16] = {}, av[16] = {};
  for (int dq = 0; dq < 64; dq += 4) {
    float g1[4], g2[4];
#pragma unroll
    for (int e = 0; e < 4; ++e) { g1[e] = gal_s[dq + e][lane]; g2[e] = gar_s[dq + e][lane]; }
#pragma unroll
    for (int kk = 0; kk < 16; ++kk) {
      float4 wv = *(const float4*)&W_s[wk + kk][dq];
      au[kk] = fmaf(wv.x, g1[0], fmaf(wv.y, g1[1], fmaf(wv.z, g1[2], fmaf(wv.w, g1[3], au[kk]))));
      av[kk] = fmaf(wv.x, g2[0], fmaf(wv.y, g2[1], fmaf(wv.z, g2[2], fmaf(wv.w, g2[3], av[kk]))));
    }
  }
  const size_t ob = ((size_t)((t * 8 + blockIdx.y) * 64 + lane)) * 512 + k0 + wk;
#pragma unroll
  for (int q = 0; q < 4; ++q) {
    *(float4*)&upart[ob + q * 4] = make_float4(au[q*4], au[q*4+1], au[q*4+2], au[q*4+3]);
    *(float4*)&vpart[ob + q * 4] = make_float4(av[q*4], av[q*4+1], av[q*4+2], av[q*4+3]);
  }
}

// ---------- sum uv partials -> uvbf ----------
__global__ __launch_bounds__(256) void k_uvsum(const float* __restrict__ upart,
                                               const float* __restrict__ vpart,
                                               unsigned short* __restrict__ uvbf) {
  const int n = blockIdx.x;
  for (int idx = threadIdx.x; idx < 768; idx += 256) {
    int col = idx >> 7;
    int k4 = (idx & 127) * 4;
    const float* base = (col < 3)
        ? upart + ((size_t)(col * 8) * 64 + n) * 512 + k4
        : vpart + ((size_t)((col - 3) * 8) * 64 + n) * 512 + k4;
    float4 sv = {0.f, 0.f, 0.f, 0.f};
#pragma unroll
    for (int dc = 0; dc < 8; ++dc) {
      float4 t = *(const float4*)(base + (size_t)dc * 32768);
      sv.x += t.x; sv.y += t.y; sv.z += t.z; sv.w += t.w;
    }
    ushort4 o;
    o.x = f2bf(sv.x); o.y = f2bf(sv.y); o.z = f2bf(sv.z); o.w = f2bf(sv.w);
    *(ushort4*)&uvbf[((size_t)n * 6 + col) * 512 + k4] = o;
  }
}

// ---------- k_lrm ----------
__global__ __launch_bounds__(256, 4) void k_lrm(const float* __restrict__ x,
                                                const unsigned short* __restrict__ uvbf,
                                                float* __restrict__ left,
                                                float* __restrict__ right,
                                                unsigned short* __restrict__ Xbf) {
  const int n  = blockIdx.y;
  const int i0 = blockIdx.x * 64;
  const int tid = threadIdx.x;
  const int lane = tid & 63, wid = tid >> 6;
  __shared__ unsigned short uvs[16][520];
  __shared__ __attribute__((aligned(16))) char As[4096];

  for (int idx = tid; idx < 16 * 64; idx += 256) {
    int col = idx >> 6, k8 = (idx & 63) * 8;
    ushort4 z0 = {0, 0, 0, 0}, z1 = {0, 0, 0, 0};
    if (col < 6) {
      const unsigned short* p = uvbf + ((size_t)n * 6 + col) * 512 + k8;
      z0 = *(const ushort4*)p;
      z1 = *(const ushort4*)(p + 4);
    }
    *(ushort4*)&uvs[col][k8]     = z0;
    *(ushort4*)&uvs[col][k8 + 4] = z1;
  }
  const int row = tid >> 2, sub = tid & 3;
  const float* gp = x + ((size_t)n * 512 + i0 + row) * 512 + sub * 8;
  unsigned short* xp = Xbf + ((size_t)n * 512 + i0 + row) * 512 + sub * 8;
  const int lds_off = row * 64 + ((sub ^ (row & 3)) << 4);
  const int arow = wid * 16 + (lane & 15);
  const int a_off = arow * 64 + (((lane >> 4) ^ (arow & 3)) << 4);
  f32x4 acc = {0.f, 0.f, 0.f, 0.f};
  float4 f0 = *(const float4*)(gp);
  float4 f1 = *(const float4*)(gp + 4);
  __syncthreads();
  for (int s = 0; s < 16; ++s) {
    uint4 pk;
    pk.x = ((unsigned)f2bf(f0.y) << 16) | f2bf(f0.x);
    pk.y = ((unsigned)f2bf(f0.w) << 16) | f2bf(f0.z);
    pk.z = ((unsigned)f2bf(f1.y) << 16) | f2bf(f1.x);
    pk.w = ((unsigned)f2bf(f1.w) << 16) | f2bf(f1.z);
    if (s < 15) {
      f0 = *(const float4*)(gp + (s + 1) * 32);
      f1 = *(const float4*)(gp + (s + 1) * 32 + 4);
    }
    *(uint4*)(xp + s * 32) = pk;
    *(uint4*)(As + lds_off) = pk;
    __syncthreads();
    short8 a = *(const short8*)(As + a_off);
    short8 b = *(const short8*)&uvs[lane & 15][s * 32 + (lane >> 4) * 8];
    acc = __builtin_amdgcn_mfma_f32_16x16x32_bf16(a, b, acc, 0, 0, 0);
    __syncthreads();
  }
  const int col = lane & 15;
  if (col < 6) {
    float* dst = (col < 3) ? left : right;
    const int t = (col < 3) ? col : col - 3;
    const int i = i0 + wid * 16 + ((lane >> 4) << 2);
    float* p = dst + ((size_t)t * 64 + n) * 512 + i;
    p[0] = acc.x; p[1] = acc.y; p[2] = acc.z; p[3] = acc.w;
  }
}

// ---------- MFMA GEMM1: h2T[n][d][i] = (X[n] @ W2)^T ; 2-phase dbuf pipeline ----------
__global__ __launch_bounds__(256) void k_gemm1(const unsigned short* __restrict__ X,
                                               const unsigned short* __restrict__ WT,
                                               unsigned short* __restrict__ h2T) {
  __shared__ __attribute__((aligned(16))) char smem[34816];
  char* A0 = smem;
  char* A1 = smem + 8192;
  char* B0 = smem + 16384;
  char* B1 = smem + 24576;
  const int s = blockIdx.x;
  const int n  = ((s >> 7) << 3) | (s & 7);
  const int jj = (s >> 3) & 15;
  const int i0 = (jj >> 2) * 128;
  const int d0 = (jj & 3) * 128;
  const int tid = threadIdx.x;
  const int lane = tid & 63, w = tid >> 6;
  const int wm = w >> 1, wn = w & 1;
  const int srow = tid >> 2;
  const int kbp  = tid & 3;
  f32x4 acc[4][4];
#pragma unroll
  for (int a = 0; a < 4; ++a)
#pragma unroll
    for (int b = 0; b < 4; ++b) acc[a][b] = (f32x4){0.f, 0.f, 0.f, 0.f};

  const size_t xbase = (size_t)n * 262144;
  int ra[4], rb[4];
#pragma unroll
  for (int f = 0; f < 4; ++f) {
    int row = wm * 64 + f * 16 + (lane & 15);
    ra[f] = row * 64 + (((lane >> 4) ^ ((row >> 1) & 3)) << 4);
    int rowb = wn * 64 + f * 16 + (lane & 15);
    rb[f] = rowb * 64 + (((lane >> 4) ^ ((rowb >> 1) & 3)) << 4);
  }
  const int kl0 = (kbp ^ ((srow >> 1) & 3)) * 8;
  const int kl1 = (kbp ^ (((64 + srow) >> 1) & 3)) * 8;
  const unsigned short* xr0 = X + xbase + (size_t)(i0 + srow) * 512 + kl0;
  const unsigned short* xr1 = X + xbase + (size_t)(i0 + 64 + srow) * 512 + kl1;
  const unsigned short* wr0 = WT + (size_t)(d0 + srow) * 512 + kl0;
  const unsigned short* wr1 = WT + (size_t)(d0 + 64 + srow) * 512 + kl1;

  GLOAD16(xr0, A0 + tid * 16);
  GLOAD16(xr1, A0 + 4096 + tid * 16);
  GLOAD16(wr0, B0 + tid * 16);
  GLOAD16(wr1, B0 + 4096 + tid * 16);

#pragma unroll 2
  for (int t = 0; t < 16; ++t) {
    char* Ac = (t & 1) ? A1 : A0;
    char* Bc = (t & 1) ? B1 : B0;
    if (t < 15) {
      char* An = (t & 1) ? A0 : A1;
      char* Bn = (t & 1) ? B0 : B1;
      const int kc = (t + 1) * 32;
      GLOAD16(xr0 + kc, An + tid * 16);
      GLOAD16(xr1 + kc, An + 4096 + tid * 16);
      GLOAD16(wr0 + kc, Bn + tid * 16);
      GLOAD16(wr1 + kc, Bn + 4096 + tid * 16);
      asm volatile("s_waitcnt vmcnt(4)" ::: "memory");
    } else {
      asm volatile("s_waitcnt vmcnt(0)" ::: "memory");
    }
    __builtin_amdgcn_s_barrier();
    short8 a[4], b[4];
#pragma unroll
    for (int f = 0; f < 4; ++f) a[f] = *(const short8*)(Ac + ra[f]);
#pragma unroll
    for (int f = 0; f < 4; ++f) b[f] = *(const short8*)(Bc + rb[f]);
#pragma unroll
    for (int mf = 0; mf < 4; ++mf)
#pragma unroll
      for (int nf = 0; nf < 4; ++nf)
        acc[mf][nf] = __builtin_amdgcn_mfma_f32_16x16x32_bf16(a[mf], b[nf], acc[mf][nf], 0, 0, 0);
    asm volatile("s_waitcnt lgkmcnt(0)" ::: "memory");
    __builtin_amdgcn_sched_barrier(0);
    __builtin_amdgcn_s_barrier();
  }
  unsigned short (*Ct)[136] = (unsigned short (*)[136])smem;
#pragma unroll
  for (int mf = 0; mf < 4; ++mf)
#pragma unroll
    for (int nf = 0; nf < 4; ++nf) {
      f32x4 vv = acc[mf][nf];
      int dl = wn * 64 + nf * 16 + (lane & 15);
      int il = wm * 64 + mf * 16 + ((lane >> 4) << 2);
      ushort4 pk;
      pk.x = f2bf(vv.x); pk.y = f2bf(vv.y); pk.z = f2bf(vv.z); pk.w = f2bf(vv.w);
      *(ushort4*)&Ct[dl][il] = pk;
    }
  __syncthreads();
  const size_t obase = xbase + (size_t)d0 * 512 + i0;
#pragma unroll
  for (int q = 0; q < 8; ++q) {
    int f = q * 2048 + tid * 8;
    int dl = f >> 7, il = f & 127;
    *(uint4*)&h2T[obase + (size_t)dl * 512 + il] = *(const uint4*)&Ct[dl][il];
  }
}

// ---------- fused masked softmax + transpose -> coefsT[n][j][i] bf16 ----------
// Row = 16 lanes x 32 j; per-lane online softmax + one joint (m,z) butterfly.
// __launch_bounds__(256,4): keep s[4][8]+adj regs resident (was 36 VGPR -> spill).
__global__ __launch_bounds__(256, 4) void k_smt(const int* __restrict__ adj,
                                                const float* __restrict__ left,
                                                const float* __restrict__ right,
                                                unsigned short* __restrict__ ct) {
  const int n  = blockIdx.y;
  const int i0 = blockIdx.x * 16;
  const int tid = threadIdx.x;
  const int lane = tid & 63, wid = tid >> 6;
  const int l15 = lane & 15;
  const int il  = wid * 4 + (lane >> 4);     // row 0..15
  __shared__ float rs_s[32][49];
  __shared__ float ls[3][16];
  __shared__ unsigned short tile[16][520];
  for (int idx = tid; idx < 1536; idx += 256) {
    int t = idx >> 9, j = idx & 511;
    rs_s[j & 31][t * 16 + (j >> 5)] = right[((size_t)t * 64 + n) * 512 + j];
  }
  if (tid < 48) {
    int t = tid >> 4, ii = tid & 15;
    ls[t][ii] = left[((size_t)t * 64 + n) * 512 + i0 + ii];
  }
  __syncthreads();
  const int* adjb = adj + ((size_t)(n * 512 + i0 + il)) * 512;
  int4 A[4], B[4];
#pragma unroll
  for (int q = 0; q < 4; ++q) {
    const int* p = adjb + q * 128 + l15 * 8;
    A[q] = *(const int4*)p;
    B[q] = *(const int4*)(p + 4);
  }
  const float l0 = ls[0][il], l1 = ls[1][il], l2 = ls[2][il];
  const int base0 = ((l15 & 3) * 8) * 49 + (l15 >> 2);
  const float* rsf = (const float*)rs_s;
  float s[4][8];
  float mloc = -3.0e38f;
#pragma unroll
  for (int q = 0; q < 4; ++q) {
    int tv[8] = {A[q].x, A[q].y, A[q].z, A[q].w, B[q].x, B[q].y, B[q].z, B[q].w};
#pragma unroll
    for (int x = 0; x < 8; ++x) {
      int t = tv[x];
      int tt = (t > 0) ? (t - 1) : 0;
      float lv = (t >= 2) ? ((t == 3) ? l2 : l1) : l0;
      float r = rsf[base0 + tt * 16 + (x * 49 + q * 4)];
      float sv = lv + r;
      sv = (sv >= 0.f) ? sv : 0.2f * sv;
      sv = (t == 0) ? -9.0e15f : sv;
      s[q][x] = sv;
      mloc = fmaxf(mloc, sv);
    }
  }
  float z = 0.f;
#pragma unroll
  for (int q = 0; q < 4; ++q)
#pragma unroll
    for (int x = 0; x < 8; ++x) {
      float e = __expf(s[q][x] - mloc);
      s[q][x] = e;
      z += e;
    }
  float m = mloc;
#pragma unroll
  for (int k = 1; k <= 8; k <<= 1) {
    float mo = __shfl_xor(m, k);
    float zo = __shfl_xor(z, k);
    float mn = fmaxf(m, mo);
    z = z * __expf(m - mn) + zo * __expf(mo - mn);
    m = mn;
  }
  const float factor = __expf(mloc - m) / z;
#pragma unroll
  for (int q = 0; q < 4; ++q) {
    uint4 pk;
    pk.x = ((unsigned)f2bf(s[q][1] * factor) << 16) | f2bf(s[q][0] * factor);
    pk.y = ((unsigned)f2bf(s[q][3] * factor) << 16) | f2bf(s[q][2] * factor);
    pk.z = ((unsigned)f2bf(s[q][5] * factor) << 16) | f2bf(s[q][4] * factor);
    pk.w = ((unsigned)f2bf(s[q][7] * factor) << 16) | f2bf(s[q][6] * factor);
    *(uint4*)&tile[il][q * 128 + l15 * 8] = pk;   // row-10 correct index
  }
  __syncthreads();
  unsigned short* ob = ct + (size_t)n * 262144 + i0;
#pragma unroll
  for (int pass = 0; pass < 4; ++pass) {
    int j = pass * 128 + (tid >> 1);
    int i8 = (tid & 1) * 8;
    uint4 o;
    o.x = (unsigned)tile[i8 + 0][j] | ((unsigned)tile[i8 + 1][j] << 16);
    o.y = (unsigned)tile[i8 + 2][j] | ((unsigned)tile[i8 + 3][j] << 16);
    o.z = (unsigned)tile[i8 + 4][j] | ((unsigned)tile[i8 + 5][j] << 16);
    o.w = (unsigned)tile[i8 + 6][j] | ((unsigned)tile[i8 + 7][j] << 16);
    *(uint4*)&ob[(size_t)j * 512 + i8] = o;
  }
}

// ---------- MFMA GEMM2: out[n][j][d] = coefsT[n] @ h2T[n]^T ; 2-phase dbuf ----------
__global__ __launch_bounds__(256) void k_gemm2(const unsigned short* __restrict__ CT,
                                               const unsigned short* __restrict__ H2T,
                                               float* __restrict__ out) {
  __shared__ __attribute__((aligned(16))) char smem[32768];
  char* A0 = smem;
  char* A1 = smem + 8192;
  char* B0 = smem + 16384;
  char* B1 = smem + 24576;
  const int s = blockIdx.x;
  const int n  = ((s >> 7) << 3) | (s & 7);
  const int jj = (s >> 3) & 15;
  const int j0 = (jj >> 2) * 128;
  const int d0 = (jj & 3) * 128;
  const int tid = threadIdx.x;
  const int lane = tid & 63, w = tid >> 6;
  const int wm = w >> 1, wn = w & 1;
  const int srow = tid >> 2;
  const int kbp  = tid & 3;
  f32x4 acc[4][4];
#pragma unroll
  for (int a = 0; a < 4; ++a)
#pragma unroll
    for (int b = 0; b < 4; ++b) acc[a][b] = (f32x4){0.f, 0.f, 0.f, 0.f};

  const size_t base = (size_t)n * 262144;
  int ra[4], rb[4];
#pragma unroll
  for (int f = 0; f < 4; ++f) {
    int row = wm * 64 + f * 16 + (lane & 15);
    ra[f] = row * 64 + (((lane >> 4) ^ ((row >> 1) & 3)) << 4);
    int rowb = wn * 64 + f * 16 + (lane & 15);
    rb[f] = rowb * 64 + (((lane >> 4) ^ ((rowb >> 1) & 3)) << 4);
  }
  const int kl0 = (kbp ^ ((srow >> 1) & 3)) * 8;
  const int kl1 = (kbp ^ (((64 + srow) >> 1) & 3)) * 8;
  const unsigned short* cr0 = CT + base + (size_t)(j0 + srow) * 512 + kl0;
  const unsigned short* cr1 = CT + base + (size_t)(j0 + 64 + srow) * 512 + kl1;
  const unsigned short* hr0 = H2T + base + (size_t)(d0 + srow) * 512 + kl0;
  const unsigned short* hr1 = H2T + base + (size_t)(d0 + 64 + srow) * 512 + kl1;

  GLOAD16(cr0, A0 + tid * 16);
  GLOAD16(cr1, A0 + 4096 + tid * 16);
  GLOAD16(hr0, B0 + tid * 16);
  GLOAD16(hr1, B0 + 4096 + tid * 16);

#pragma unroll 2
  for (int t = 0; t < 16; ++t) {
    char* Ac = (t & 1) ? A1 : A0;
    char* Bc = (t & 1) ? B1 : B0;
    if (t < 15) {
      char* An = (t & 1) ? A0 : A1;
      char* Bn = (t & 1) ? B0 : B1;
      const int kc = (t + 1) * 32;
      GLOAD16(cr0 + kc, An + tid * 16);
      GLOAD16(cr1 + kc, An + 4096 + tid * 16);
      GLOAD16(hr0 + kc, Bn + tid * 16);
      GLOAD16(hr1 + kc, Bn + 4096 + tid * 16);
      asm volatile("s_waitcnt vmcnt(4)" ::: "memory");
    } else {
      asm volatile("s_waitcnt vmcnt(0)" ::: "memory");
    }
    __builtin_amdgcn_s_barrier();
    short8 a[4], b[4];
#pragma unroll
    for (int f = 0; f < 4; ++f) a[f] = *(const short8*)(Ac + ra[f]);
#pragma unroll
    for (int f = 0; f < 4; ++f) b[f] = *(const short8*)(Bc + rb[f]);
#pragma unroll
    for (int mf = 0; mf < 4; ++mf)
#pragma unroll
      for (int nf = 0; nf < 4; ++nf)
        acc[mf][nf] = __builtin_amdgcn_mfma_f32_16x16x32_bf16(a[mf], b[nf], acc[mf][nf], 0, 0, 0);
    asm volatile("s_waitcnt lgkmcnt(0)" ::: "memory");
    __builtin_amdgcn_sched_barrier(0);
    __builtin_amdgcn_s_barrier();
  }
  const int jb = j0 + wm * 64 + (lane >> 4) * 4;
  const int db = d0 + wn * 64 + (lane & 15);
#pragma unroll
  for (int mf = 0; mf < 4; ++mf)
#pragma unroll
    for (int nf = 0; nf < 4; ++nf) {
      f32x4 vv = acc[mf][nf];
      float* op = out + base + (size_t)(jb + mf * 16) * 512 + db + nf * 16;
      op[0]    = vv.x;
      op[512]  = vv.y;
      op[1024] = vv.z;
      op[1536] = vv.w;
    }
}

extern "C" void kernel_launch(void* const* d_in, const int* in_sizes, int n_in,
                              void* d_out, int out_size, void* d_ws, size_t ws_size,
                              hipStream_t stream) {
  const float* input  = (const float*)d_in[0];
  const int*   adj    = (const int*)d_in[1];
  const float* query  = (const float*)d_in[3];
  const float* W_type = (const float*)d_in[4];
  const float* a_type = (const float*)d_in[5];
  const float* W1     = (const float*)d_in[6];
  const float* W2     = (const float*)d_in[7];
  float* out = (float*)d_out;

  char* ws = (char*)d_ws;
  float* galT  = (float*)(ws);                              //  393,216 B
  float* garT  = (float*)(ws + 393216);                     //  393,216 B
  unsigned short* uvbf = (unsigned short*)(ws + 786432);    //  393,216 B
  float* left  = (float*)(ws + 1179648);                    //  393,216 B
  float* right = (float*)(ws + 1572864);                    //  393,216 B
  unsigned short* Xbf = (unsigned short*)(ws + 2359296);    // 33,554,432 B (reused as coefsT)
  unsigned short* h2T = (unsigned short*)(ws + 35913728);   // 33,554,432 B
  // partials alias h2T's region: all dead before k_gemm1 writes h2T
  float* rpart = (float*)(ws + 35913728);                   //  3,145,728 B
  float* gpart = (float*)(ws + 39059456);                   //  6,291,456 B
  float* upart = (float*)(ws + 45350912);                   //  3,145,728 B
  float* vpart = (float*)(ws + 48496640);                   //  3,145,728 B
  unsigned short* WT  = (unsigned short*)(ws + 69468160);   //    524,288 B
  // total ws use: 69,992,448 B
  unsigned short* coefsT = Xbf;   // Xbf dead after k_gemm1; k_smt writes it, k_gemm2 reads it

  k_wt      <<<dim3(8, 8),      256, 0, stream>>>(W_type + (size_t)2 * 262144, WT);
  k_gate1   <<<dim3(16, 4, 3),  256, 0, stream>>>(query, W1, rpart);
  k_gate2   <<<dim3(16, 8, 3),  256, 0, stream>>>(rpart, W2, gpart);
  k_gate_fin<<<dim3(256, 3),    256, 0, stream>>>(gpart, a_type, galT, garT);
  k_uvp     <<<dim3(8, 8, 3),   256, 0, stream>>>(W_type, galT, garT, upart, vpart);
  k_uvsum   <<<dim3(64),        256, 0, stream>>>(upart, vpart, uvbf);
  k_lrm     <<<dim3(8, 64),     256, 0, stream>>>(input, uvbf, left, right, Xbf);
  k_gemm1   <<<dim3(1024),      256, 0, stream>>>(Xbf, WT, h2T);
  k_smt     <<<dim3(32, 64),    256, 0, stream>>>(adj, left, right, coefsT);
  k_gemm2   <<<dim3(1024),      256, 0, stream>>>(coefsT, h2T, out);
}

// Round 17
// 171.404 us; speedup vs baseline: 1.2179x; 1.0732x over previous
//
#include <hip/hip_runtime.h>
#include <cstdint>

typedef __attribute__((ext_vector_type(8))) short short8;
typedef __attribute__((ext_vector_type(4))) float f32x4;

// ---------- helpers ----------
__device__ __forceinline__ unsigned short f2bf(float x) {
  unsigned int u = __float_as_uint(x);
  u += 0x7FFFu + ((u >> 16) & 1u);   // round-to-nearest-even
  return (unsigned short)(u >> 16);
}

#define GLOAD16(gsrc, ldst)                                                        \
  __builtin_amdgcn_global_load_lds(                                                \
      (const __attribute__((address_space(1))) void*)(gsrc),                       \
      (__attribute__((address_space(3))) void*)(ldst), 16, 0, 0)

// ---------- merged: k_wt (blocks 0..63) + gate1 (blocks 64..255) ----------
__global__ __launch_bounds__(256, 4) void k_wtg1(const float* __restrict__ W,
                                                 unsigned short* __restrict__ WT,
                                                 const float* __restrict__ q,
                                                 const float* __restrict__ W1,
                                                 float* __restrict__ rpart) {
  __shared__ float qs[64][133];     // gate1 tile; k_wt reuses the first 64*68 floats
  const int bid = blockIdx.x;
  const int tid = threadIdx.x;
  if (bid < 64) {
    // ---- WT[d][k] = bf16(W2[k][d]) ----
    float (*t)[68] = (float (*)[68])qs;
    const int d0 = (bid & 7) * 64, k0 = (bid >> 3) * 64;
    for (int idx = tid; idx < 4096; idx += 256) {
      int r = idx >> 6, c = idx & 63;
      t[r][c] = W[(size_t)(k0 + r) * 512 + d0 + c];
    }
    __syncthreads();
    for (int idx = tid; idx < 4096; idx += 256) {
      int r = idx >> 6, c = idx & 63;
      WT[(size_t)(d0 + r) * 512 + k0 + c] = f2bf(t[c][r]);
    }
    return;
  }
  // ---- gate 1: rpart[t][kc][col][n] = partial (q @ W1[t]) ----
  const int g  = bid - 64;
  const int c0 = (g & 15) * 64;
  const int k0 = ((g >> 4) & 3) * 128;
  const int t  = g >> 6;
  const int lane = tid & 63;
  const int wcs = __builtin_amdgcn_readfirstlane(tid >> 6);
  for (int idx = tid; idx < 2048; idx += 256) {
    int r = idx >> 5, c4 = (idx & 31) * 4;
    float4 f = *(const float4*)&q[(size_t)r * 512 + k0 + c4];
    qs[r][c4 + 0] = f.x; qs[r][c4 + 1] = f.y;
    qs[r][c4 + 2] = f.z; qs[r][c4 + 3] = f.w;
  }
  __syncthreads();
  const float* Wp = W1 + ((size_t)t * 512 + k0) * 1024 + c0 + wcs * 16;
  float acc[16] = {};
  for (int k = 0; k < 128; ++k) {
    float qr = qs[lane][k];
    const float* wr = Wp + (size_t)k * 1024;
    float4 w0 = *(const float4*)(wr);
    float4 w1 = *(const float4*)(wr + 4);
    float4 w2 = *(const float4*)(wr + 8);
    float4 w3 = *(const float4*)(wr + 12);
    acc[0]  = fmaf(qr, w0.x, acc[0]);  acc[1]  = fmaf(qr, w0.y, acc[1]);
    acc[2]  = fmaf(qr, w0.z, acc[2]);  acc[3]  = fmaf(qr, w0.w, acc[3]);
    acc[4]  = fmaf(qr, w1.x, acc[4]);  acc[5]  = fmaf(qr, w1.y, acc[5]);
    acc[6]  = fmaf(qr, w1.z, acc[6]);  acc[7]  = fmaf(qr, w1.w, acc[7]);
    acc[8]  = fmaf(qr, w2.x, acc[8]);  acc[9]  = fmaf(qr, w2.y, acc[9]);
    acc[10] = fmaf(qr, w2.z, acc[10]); acc[11] = fmaf(qr, w2.w, acc[11]);
    acc[12] = fmaf(qr, w3.x, acc[12]); acc[13] = fmaf(qr, w3.y, acc[13]);
    acc[14] = fmaf(qr, w3.z, acc[14]); acc[15] = fmaf(qr, w3.w, acc[15]);
  }
  float* rp = rpart + ((size_t)(t * 4 + ((g >> 4) & 3)) * 1024 + c0 + wcs * 16) * 64 + lane;
#pragma unroll
  for (int cc = 0; cc < 16; ++cc) rp[(size_t)cc * 64] = acc[cc];
}

// ---------- gate 2 ----------
__global__ __launch_bounds__(256, 4) void k_gate2(const float* __restrict__ rpart,
                                                  const float* __restrict__ W2,
                                                  float* __restrict__ gpart) {
  const int c0 = blockIdx.x * 64;
  const int k0 = blockIdx.y * 128;
  const int t  = blockIdx.z;
  const int tid = threadIdx.x;
  const int lane = tid & 63;
  const int wcs = __builtin_amdgcn_readfirstlane(tid >> 6);
  __shared__ float qs[64][133];
  for (int idx = tid; idx < 2048; idx += 256) {
    int kl = idx >> 4, n4 = (idx & 15) * 4;
    const float* rp = rpart + ((size_t)t * 4 * 1024 + k0 + kl) * 64 + n4;
    float4 a = *(const float4*)(rp);
    float4 b = *(const float4*)(rp + 65536);
    float4 c = *(const float4*)(rp + 131072);
    float4 d = *(const float4*)(rp + 196608);
    qs[n4 + 0][kl] = fmaxf(a.x + b.x + c.x + d.x, 0.f);
    qs[n4 + 1][kl] = fmaxf(a.y + b.y + c.y + d.y, 0.f);
    qs[n4 + 2][kl] = fmaxf(a.z + b.z + c.z + d.z, 0.f);
    qs[n4 + 3][kl] = fmaxf(a.w + b.w + c.w + d.w, 0.f);
  }
  __syncthreads();
  const float* Wp = W2 + ((size_t)t << 20) + (size_t)k0 * 1024 + c0 + wcs * 16;
  float acc[16] = {};
  for (int k = 0; k < 128; ++k) {
    float qr = qs[lane][k];
    const float* wr = Wp + (size_t)k * 1024;
    float4 w0 = *(const float4*)(wr);
    float4 w1 = *(const float4*)(wr + 4);
    float4 w2 = *(const float4*)(wr + 8);
    float4 w3 = *(const float4*)(wr + 12);
    acc[0]  = fmaf(qr, w0.x, acc[0]);  acc[1]  = fmaf(qr, w0.y, acc[1]);
    acc[2]  = fmaf(qr, w0.z, acc[2]);  acc[3]  = fmaf(qr, w0.w, acc[3]);
    acc[4]  = fmaf(qr, w1.x, acc[4]);  acc[5]  = fmaf(qr, w1.y, acc[5]);
    acc[6]  = fmaf(qr, w1.z, acc[6]);  acc[7]  = fmaf(qr, w1.w, acc[7]);
    acc[8]  = fmaf(qr, w2.x, acc[8]);  acc[9]  = fmaf(qr, w2.y, acc[9]);
    acc[10] = fmaf(qr, w2.z, acc[10]); acc[11] = fmaf(qr, w2.w, acc[11]);
    acc[12] = fmaf(qr, w3.x, acc[12]); acc[13] = fmaf(qr, w3.y, acc[13]);
    acc[14] = fmaf(qr, w3.z, acc[14]); acc[15] = fmaf(qr, w3.w, acc[15]);
  }
  float* gp = gpart + ((size_t)(t * 8 + blockIdx.y) * 1024 + c0 + wcs * 16) * 64 + lane;
#pragma unroll
  for (int cc = 0; cc < 16; ++cc) gp[(size_t)cc * 64] = acc[cc];
}

// ---------- gate fin ----------
__global__ __launch_bounds__(256) void k_gate_fin(const float* __restrict__ gpart,
                                                  const float* __restrict__ a_type,
                                                  float* __restrict__ galT,
                                                  float* __restrict__ garT) {
  const int t = blockIdx.y;
  const int n = threadIdx.x & 63;
  const int mg = blockIdx.x * 4 + (threadIdx.x >> 6);
  float s = 0.f;
#pragma unroll
  for (int kc = 0; kc < 8; ++kc)
    s += gpart[((size_t)(t * 8 + kc) * 1024 + mg) * 64 + n];
  float g = 1.f / (1.f + __expf(-s));
  float ga = g * a_type[t * 1024 + mg];
  if (mg < 512) galT[((size_t)t * 512 + mg) * 64 + n] = ga;
  else          garT[((size_t)t * 512 + (mg - 512)) * 64 + n] = ga;
}

// ---------- u,v split-d partials ----------
__global__ __launch_bounds__(256, 4) void k_uvp(const float* __restrict__ W,
                                                const float* __restrict__ galT,
                                                const float* __restrict__ garT,
                                                float* __restrict__ upart,
                                                float* __restrict__ vpart) {
  const int k0 = blockIdx.x * 64;
  const int d0 = blockIdx.y * 64;
  const int t  = blockIdx.z;
  const int tid = threadIdx.x;
  const int lane = tid & 63;
  const int wk = (tid >> 6) * 16;
  __shared__ float gal_s[64][64];
  __shared__ float gar_s[64][64];
  __shared__ float W_s[64][64];
  for (int idx = tid; idx < 1024; idx += 256) {
    int d = idx >> 4, n4 = (idx & 15) * 4;
    *(float4*)&gal_s[d][n4] = *(const float4*)&galT[((size_t)t * 512 + d0 + d) * 64 + n4];
    *(float4*)&gar_s[d][n4] = *(const float4*)&garT[((size_t)t * 512 + d0 + d) * 64 + n4];
    int k = idx >> 4, d4 = (idx & 15) * 4;
    *(float4*)&W_s[k][d4] = *(const float4*)&W[((size_t)t * 512 + k0 + k) * 512 + d0 + d4];
  }
  __syncthreads();
  float au[16] = {}, av[16] = {};
  for (int dq = 0; dq < 64; dq += 4) {
    float g1[4], g2[4];
#pragma unroll
    for (int e = 0; e < 4; ++e) { g1[e] = gal_s[dq + e][lane]; g2[e] = gar_s[dq + e][lane]; }
#pragma unroll
    for (int kk = 0; kk < 16; ++kk) {
      float4 wv = *(const float4*)&W_s[wk + kk][dq];
      au[kk] = fmaf(wv.x, g1[0], fmaf(wv.y, g1[1], fmaf(wv.z, g1[2], fmaf(wv.w, g1[3], au[kk]))));
      av[kk] = fmaf(wv.x, g2[0], fmaf(wv.y, g2[1], fmaf(wv.z, g2[2], fmaf(wv.w, g2[3], av[kk]))));
    }
  }
  const size_t ob = ((size_t)((t * 8 + blockIdx.y) * 64 + lane)) * 512 + k0 + wk;
#pragma unroll
  for (int q = 0; q < 4; ++q) {
    *(float4*)&upart[ob + q * 4] = make_float4(au[q*4], au[q*4+1], au[q*4+2], au[q*4+3]);
    *(float4*)&vpart[ob + q * 4] = make_float4(av[q*4], av[q*4+1], av[q*4+2], av[q*4+3]);
  }
}

// ---------- sum uv partials -> uvbf ----------
__global__ __launch_bounds__(256) void k_uvsum(const float* __restrict__ upart,
                                               const float* __restrict__ vpart,
                                               unsigned short* __restrict__ uvbf) {
  const int n = blockIdx.x;
  for (int idx = threadIdx.x; idx < 768; idx += 256) {
    int col = idx >> 7;
    int k4 = (idx & 127) * 4;
    const float* base = (col < 3)
        ? upart + ((size_t)(col * 8) * 64 + n) * 512 + k4
        : vpart + ((size_t)((col - 3) * 8) * 64 + n) * 512 + k4;
    float4 sv = {0.f, 0.f, 0.f, 0.f};
#pragma unroll
    for (int dc = 0; dc < 8; ++dc) {
      float4 t = *(const float4*)(base + (size_t)dc * 32768);
      sv.x += t.x; sv.y += t.y; sv.z += t.z; sv.w += t.w;
    }
    ushort4 o;
    o.x = f2bf(sv.x); o.y = f2bf(sv.y); o.z = f2bf(sv.z); o.w = f2bf(sv.w);
    *(ushort4*)&uvbf[((size_t)n * 6 + col) * 512 + k4] = o;
  }
}

// ---------- k_lrm ----------
__global__ __launch_bounds__(256, 4) void k_lrm(const float* __restrict__ x,
                                                const unsigned short* __restrict__ uvbf,
                                                float* __restrict__ left,
                                                float* __restrict__ right,
                                                unsigned short* __restrict__ Xbf) {
  const int n  = blockIdx.y;
  const int i0 = blockIdx.x * 64;
  const int tid = threadIdx.x;
  const int lane = tid & 63, wid = tid >> 6;
  __shared__ unsigned short uvs[16][520];
  __shared__ __attribute__((aligned(16))) char As[4096];

  for (int idx = tid; idx < 16 * 64; idx += 256) {
    int col = idx >> 6, k8 = (idx & 63) * 8;
    ushort4 z0 = {0, 0, 0, 0}, z1 = {0, 0, 0, 0};
    if (col < 6) {
      const unsigned short* p = uvbf + ((size_t)n * 6 + col) * 512 + k8;
      z0 = *(const ushort4*)p;
      z1 = *(const ushort4*)(p + 4);
    }
    *(ushort4*)&uvs[col][k8]     = z0;
    *(ushort4*)&uvs[col][k8 + 4] = z1;
  }
  const int row = tid >> 2, sub = tid & 3;
  const float* gp = x + ((size_t)n * 512 + i0 + row) * 512 + sub * 8;
  unsigned short* xp = Xbf + ((size_t)n * 512 + i0 + row) * 512 + sub * 8;
  const int lds_off = row * 64 + ((sub ^ (row & 3)) << 4);
  const int arow = wid * 16 + (lane & 15);
  const int a_off = arow * 64 + (((lane >> 4) ^ (arow & 3)) << 4);
  f32x4 acc = {0.f, 0.f, 0.f, 0.f};
  float4 f0 = *(const float4*)(gp);
  float4 f1 = *(const float4*)(gp + 4);
  __syncthreads();
  for (int s = 0; s < 16; ++s) {
    uint4 pk;
    pk.x = ((unsigned)f2bf(f0.y) << 16) | f2bf(f0.x);
    pk.y = ((unsigned)f2bf(f0.w) << 16) | f2bf(f0.z);
    pk.z = ((unsigned)f2bf(f1.y) << 16) | f2bf(f1.x);
    pk.w = ((unsigned)f2bf(f1.w) << 16) | f2bf(f1.z);
    if (s < 15) {
      f0 = *(const float4*)(gp + (s + 1) * 32);
      f1 = *(const float4*)(gp + (s + 1) * 32 + 4);
    }
    *(uint4*)(xp + s * 32) = pk;
    *(uint4*)(As + lds_off) = pk;
    __syncthreads();
    short8 a = *(const short8*)(As + a_off);
    short8 b = *(const short8*)&uvs[lane & 15][s * 32 + (lane >> 4) * 8];
    acc = __builtin_amdgcn_mfma_f32_16x16x32_bf16(a, b, acc, 0, 0, 0);
    __syncthreads();
  }
  const int col = lane & 15;
  if (col < 6) {
    float* dst = (col < 3) ? left : right;
    const int t = (col < 3) ? col : col - 3;
    const int i = i0 + wid * 16 + ((lane >> 4) << 2);
    float* p = dst + ((size_t)t * 64 + n) * 512 + i;
    p[0] = acc.x; p[1] = acc.y; p[2] = acc.z; p[3] = acc.w;
  }
}

// ---------- MFMA GEMM1: h2T[n][d][i] = (X[n] @ W2)^T ; 2-phase dbuf pipeline ----------
__global__ __launch_bounds__(256) void k_gemm1(const unsigned short* __restrict__ X,
                                               const unsigned short* __restrict__ WT,
                                               unsigned short* __restrict__ h2T) {
  __shared__ __attribute__((aligned(16))) char smem[34816];
  char* A0 = smem;
  char* A1 = smem + 8192;
  char* B0 = smem + 16384;
  char* B1 = smem + 24576;
  const int s = blockIdx.x;
  const int n  = ((s >> 7) << 3) | (s & 7);
  const int jj = (s >> 3) & 15;
  const int i0 = (jj >> 2) * 128;
  const int d0 = (jj & 3) * 128;
  const int tid = threadIdx.x;
  const int lane = tid & 63, w = tid >> 6;
  const int wm = w >> 1, wn = w & 1;
  const int srow = tid >> 2;
  const int kbp  = tid & 3;
  f32x4 acc[4][4];
#pragma unroll
  for (int a = 0; a < 4; ++a)
#pragma unroll
    for (int b = 0; b < 4; ++b) acc[a][b] = (f32x4){0.f, 0.f, 0.f, 0.f};

  const size_t xbase = (size_t)n * 262144;
  int ra[4], rb[4];
#pragma unroll
  for (int f = 0; f < 4; ++f) {
    int row = wm * 64 + f * 16 + (lane & 15);
    ra[f] = row * 64 + (((lane >> 4) ^ ((row >> 1) & 3)) << 4);
    int rowb = wn * 64 + f * 16 + (lane & 15);
    rb[f] = rowb * 64 + (((lane >> 4) ^ ((rowb >> 1) & 3)) << 4);
  }
  const int kl0 = (kbp ^ ((srow >> 1) & 3)) * 8;
  const int kl1 = (kbp ^ (((64 + srow) >> 1) & 3)) * 8;
  const unsigned short* xr0 = X + xbase + (size_t)(i0 + srow) * 512 + kl0;
  const unsigned short* xr1 = X + xbase + (size_t)(i0 + 64 + srow) * 512 + kl1;
  const unsigned short* wr0 = WT + (size_t)(d0 + srow) * 512 + kl0;
  const unsigned short* wr1 = WT + (size_t)(d0 + 64 + srow) * 512 + kl1;

  GLOAD16(xr0, A0 + tid * 16);
  GLOAD16(xr1, A0 + 4096 + tid * 16);
  GLOAD16(wr0, B0 + tid * 16);
  GLOAD16(wr1, B0 + 4096 + tid * 16);

#pragma unroll 2
  for (int t = 0; t < 16; ++t) {
    char* Ac = (t & 1) ? A1 : A0;
    char* Bc = (t & 1) ? B1 : B0;
    if (t < 15) {
      char* An = (t & 1) ? A0 : A1;
      char* Bn = (t & 1) ? B0 : B1;
      const int kc = (t + 1) * 32;
      GLOAD16(xr0 + kc, An + tid * 16);
      GLOAD16(xr1 + kc, An + 4096 + tid * 16);
      GLOAD16(wr0 + kc, Bn + tid * 16);
      GLOAD16(wr1 + kc, Bn + 4096 + tid * 16);
      asm volatile("s_waitcnt vmcnt(4)" ::: "memory");
    } else {
      asm volatile("s_waitcnt vmcnt(0)" ::: "memory");
    }
    __builtin_amdgcn_s_barrier();
    short8 a[4], b[4];
#pragma unroll
    for (int f = 0; f < 4; ++f) a[f] = *(const short8*)(Ac + ra[f]);
#pragma unroll
    for (int f = 0; f < 4; ++f) b[f] = *(const short8*)(Bc + rb[f]);
#pragma unroll
    for (int mf = 0; mf < 4; ++mf)
#pragma unroll
      for (int nf = 0; nf < 4; ++nf)
        acc[mf][nf] = __builtin_amdgcn_mfma_f32_16x16x32_bf16(a[mf], b[nf], acc[mf][nf], 0, 0, 0);
    asm volatile("s_waitcnt lgkmcnt(0)" ::: "memory");
    __builtin_amdgcn_sched_barrier(0);
    __builtin_amdgcn_s_barrier();
  }
  unsigned short (*Ct)[136] = (unsigned short (*)[136])smem;
#pragma unroll
  for (int mf = 0; mf < 4; ++mf)
#pragma unroll
    for (int nf = 0; nf < 4; ++nf) {
      f32x4 vv = acc[mf][nf];
      int dl = wn * 64 + nf * 16 + (lane & 15);
      int il = wm * 64 + mf * 16 + ((lane >> 4) << 2);
      ushort4 pk;
      pk.x = f2bf(vv.x); pk.y = f2bf(vv.y); pk.z = f2bf(vv.z); pk.w = f2bf(vv.w);
      *(ushort4*)&Ct[dl][il] = pk;
    }
  __syncthreads();
  const size_t obase = xbase + (size_t)d0 * 512 + i0;
#pragma unroll
  for (int q = 0; q < 8; ++q) {
    int f = q * 2048 + tid * 8;
    int dl = f >> 7, il = f & 127;
    *(uint4*)&h2T[obase + (size_t)dl * 512 + il] = *(const uint4*)&Ct[dl][il];
  }
}

// ---------- fused masked softmax + transpose -> coefsT[n][j][i] bf16 ----------
// 512 thr / 8 waves, 32 rows per block (grid 16 x 64): 4 blocks x 8 waves = 32
// waves/CU static, double round-16's measured wave pool. Same per-row math.
__global__ __launch_bounds__(512, 2) void k_smt(const int* __restrict__ adj,
                                                const float* __restrict__ left,
                                                const float* __restrict__ right,
                                                unsigned short* __restrict__ ct) {
  const int n  = blockIdx.y;
  const int i0 = blockIdx.x * 32;
  const int tid = threadIdx.x;
  const int lane = tid & 63, wid = tid >> 6;
  const int l15 = lane & 15;
  const int il  = wid * 4 + (lane >> 4);     // row 0..31
  __shared__ float rs_s[32][49];
  __shared__ float ls[3][32];
  __shared__ unsigned short tile[32][520];
  for (int idx = tid; idx < 1536; idx += 512) {
    int t = idx >> 9, j = idx & 511;
    rs_s[j & 31][t * 16 + (j >> 5)] = right[((size_t)t * 64 + n) * 512 + j];
  }
  if (tid < 96) {
    int t = tid >> 5, ii = tid & 31;
    ls[t][ii] = left[((size_t)t * 64 + n) * 512 + i0 + ii];
  }
  __syncthreads();
  const int* adjb = adj + ((size_t)(n * 512 + i0 + il)) * 512;
  int4 A[4], B[4];
#pragma unroll
  for (int q = 0; q < 4; ++q) {
    const int* p = adjb + q * 128 + l15 * 8;
    A[q] = *(const int4*)p;
    B[q] = *(const int4*)(p + 4);
  }
  const float l0 = ls[0][il], l1 = ls[1][il], l2 = ls[2][il];
  const int base0 = ((l15 & 3) * 8) * 49 + (l15 >> 2);
  const float* rsf = (const float*)rs_s;
  float s[4][8];
  float mloc = -3.0e38f;
#pragma unroll
  for (int q = 0; q < 4; ++q) {
    int tv[8] = {A[q].x, A[q].y, A[q].z, A[q].w, B[q].x, B[q].y, B[q].z, B[q].w};
#pragma unroll
    for (int x = 0; x < 8; ++x) {
      int t = tv[x];
      int tt = (t > 0) ? (t - 1) : 0;
      float lv = (t >= 2) ? ((t == 3) ? l2 : l1) : l0;
      float r = rsf[base0 + tt * 16 + (x * 49 + q * 4)];
      float sv = lv + r;
      sv = (sv >= 0.f) ? sv : 0.2f * sv;
      sv = (t == 0) ? -9.0e15f : sv;
      s[q][x] = sv;
      mloc = fmaxf(mloc, sv);
    }
  }
  float z = 0.f;
#pragma unroll
  for (int q = 0; q < 4; ++q)
#pragma unroll
    for (int x = 0; x < 8; ++x) {
      float e = __expf(s[q][x] - mloc);
      s[q][x] = e;
      z += e;
    }
  float m = mloc;
#pragma unroll
  for (int k = 1; k <= 8; k <<= 1) {
    float mo = __shfl_xor(m, k);
    float zo = __shfl_xor(z, k);
    float mn = fmaxf(m, mo);
    z = z * __expf(m - mn) + zo * __expf(mo - mn);
    m = mn;
  }
  const float factor = __expf(mloc - m) / z;
#pragma unroll
  for (int q = 0; q < 4; ++q) {
    uint4 pk;
    pk.x = ((unsigned)f2bf(s[q][1] * factor) << 16) | f2bf(s[q][0] * factor);
    pk.y = ((unsigned)f2bf(s[q][3] * factor) << 16) | f2bf(s[q][2] * factor);
    pk.z = ((unsigned)f2bf(s[q][5] * factor) << 16) | f2bf(s[q][4] * factor);
    pk.w = ((unsigned)f2bf(s[q][7] * factor) << 16) | f2bf(s[q][6] * factor);
    *(uint4*)&tile[il][q * 128 + l15 * 8] = pk;
  }
  __syncthreads();
  unsigned short* ob = ct + (size_t)n * 262144 + i0;
#pragma unroll
  for (int pass = 0; pass < 4; ++pass) {
    int j = pass * 128 + (tid >> 2);
    int i8 = (tid & 3) * 8;
    uint4 o;
    o.x = (unsigned)tile[i8 + 0][j] | ((unsigned)tile[i8 + 1][j] << 16);
    o.y = (unsigned)tile[i8 + 2][j] | ((unsigned)tile[i8 + 3][j] << 16);
    o.z = (unsigned)tile[i8 + 4][j] | ((unsigned)tile[i8 + 5][j] << 16);
    o.w = (unsigned)tile[i8 + 6][j] | ((unsigned)tile[i8 + 7][j] << 16);
    *(uint4*)&ob[(size_t)j * 512 + i8] = o;
  }
}

// ---------- MFMA GEMM2: out[n][j][d] = coefsT[n] @ h2T[n]^T ; 2-phase dbuf ----------
__global__ __launch_bounds__(256) void k_gemm2(const unsigned short* __restrict__ CT,
                                               const unsigned short* __restrict__ H2T,
                                               float* __restrict__ out) {
  __shared__ __attribute__((aligned(16))) char smem[32768];
  char* A0 = smem;
  char* A1 = smem + 8192;
  char* B0 = smem + 16384;
  char* B1 = smem + 24576;
  const int s = blockIdx.x;
  const int n  = ((s >> 7) << 3) | (s & 7);
  const int jj = (s >> 3) & 15;
  const int j0 = (jj >> 2) * 128;
  const int d0 = (jj & 3) * 128;
  const int tid = threadIdx.x;
  const int lane = tid & 63, w = tid >> 6;
  const int wm = w >> 1, wn = w & 1;
  const int srow = tid >> 2;
  const int kbp  = tid & 3;
  f32x4 acc[4][4];
#pragma unroll
  for (int a = 0; a < 4; ++a)
#pragma unroll
    for (int b = 0; b < 4; ++b) acc[a][b] = (f32x4){0.f, 0.f, 0.f, 0.f};

  const size_t base = (size_t)n * 262144;
  int ra[4], rb[4];
#pragma unroll
  for (int f = 0; f < 4; ++f) {
    int row = wm * 64 + f * 16 + (lane & 15);
    ra[f] = row * 64 + (((lane >> 4) ^ ((row >> 1) & 3)) << 4);
    int rowb = wn * 64 + f * 16 + (lane & 15);
    rb[f] = rowb * 64 + (((lane >> 4) ^ ((rowb >> 1) & 3)) << 4);
  }
  const int kl0 = (kbp ^ ((srow >> 1) & 3)) * 8;
  const int kl1 = (kbp ^ (((64 + srow) >> 1) & 3)) * 8;
  const unsigned short* cr0 = CT + base + (size_t)(j0 + srow) * 512 + kl0;
  const unsigned short* cr1 = CT + base + (size_t)(j0 + 64 + srow) * 512 + kl1;
  const unsigned short* hr0 = H2T + base + (size_t)(d0 + srow) * 512 + kl0;
  const unsigned short* hr1 = H2T + base + (size_t)(d0 + 64 + srow) * 512 + kl1;

  GLOAD16(cr0, A0 + tid * 16);
  GLOAD16(cr1, A0 + 4096 + tid * 16);
  GLOAD16(hr0, B0 + tid * 16);
  GLOAD16(hr1, B0 + 4096 + tid * 16);

#pragma unroll 2
  for (int t = 0; t < 16; ++t) {
    char* Ac = (t & 1) ? A1 : A0;
    char* Bc = (t & 1) ? B1 : B0;
    if (t < 15) {
      char* An = (t & 1) ? A0 : A1;
      char* Bn = (t & 1) ? B0 : B1;
      const int kc = (t + 1) * 32;
      GLOAD16(cr0 + kc, An + tid * 16);
      GLOAD16(cr1 + kc, An + 4096 + tid * 16);
      GLOAD16(hr0 + kc, Bn + tid * 16);
      GLOAD16(hr1 + kc, Bn + 4096 + tid * 16);
      asm volatile("s_waitcnt vmcnt(4)" ::: "memory");
    } else {
      asm volatile("s_waitcnt vmcnt(0)" ::: "memory");
    }
    __builtin_amdgcn_s_barrier();
    short8 a[4], b[4];
#pragma unroll
    for (int f = 0; f < 4; ++f) a[f] = *(const short8*)(Ac + ra[f]);
#pragma unroll
    for (int f = 0; f < 4; ++f) b[f] = *(const short8*)(Bc + rb[f]);
#pragma unroll
    for (int mf = 0; mf < 4; ++mf)
#pragma unroll
      for (int nf = 0; nf < 4; ++nf)
        acc[mf][nf] = __builtin_amdgcn_mfma_f32_16x16x32_bf16(a[mf], b[nf], acc[mf][nf], 0, 0, 0);
    asm volatile("s_waitcnt lgkmcnt(0)" ::: "memory");
    __builtin_amdgcn_sched_barrier(0);
    __builtin_amdgcn_s_barrier();
  }
  const int jb = j0 + wm * 64 + (lane >> 4) * 4;
  const int db = d0 + wn * 64 + (lane & 15);
#pragma unroll
  for (int mf = 0; mf < 4; ++mf)
#pragma unroll
    for (int nf = 0; nf < 4; ++nf) {
      f32x4 vv = acc[mf][nf];
      float* op = out + base + (size_t)(jb + mf * 16) * 512 + db + nf * 16;
      op[0]    = vv.x;
      op[512]  = vv.y;
      op[1024] = vv.z;
      op[1536] = vv.w;
    }
}

extern "C" void kernel_launch(void* const* d_in, const int* in_sizes, int n_in,
                              void* d_out, int out_size, void* d_ws, size_t ws_size,
                              hipStream_t stream) {
  const float* input  = (const float*)d_in[0];
  const int*   adj    = (const int*)d_in[1];
  const float* query  = (const float*)d_in[3];
  const float* W_type = (const float*)d_in[4];
  const float* a_type = (const float*)d_in[5];
  const float* W1     = (const float*)d_in[6];
  const float* W2     = (const float*)d_in[7];
  float* out = (float*)d_out;

  char* ws = (char*)d_ws;
  float* galT  = (float*)(ws);                              //  393,216 B
  float* garT  = (float*)(ws + 393216);                     //  393,216 B
  unsigned short* uvbf = (unsigned short*)(ws + 786432);    //  393,216 B
  float* left  = (float*)(ws + 1179648);                    //  393,216 B
  float* right = (float*)(ws + 1572864);                    //  393,216 B
  unsigned short* Xbf = (unsigned short*)(ws + 2359296);    // 33,554,432 B (reused as coefsT)
  unsigned short* h2T = (unsigned short*)(ws + 35913728);   // 33,554,432 B
  // partials alias h2T's region: all dead before k_gemm1 writes h2T
  float* rpart = (float*)(ws + 35913728);                   //  3,145,728 B
  float* gpart = (float*)(ws + 39059456);                   //  6,291,456 B
  float* upart = (float*)(ws + 45350912);                   //  3,145,728 B
  float* vpart = (float*)(ws + 48496640);                   //  3,145,728 B
  unsigned short* WT  = (unsigned short*)(ws + 69468160);   //    524,288 B
  // total ws use: 69,992,448 B
  unsigned short* coefsT = Xbf;   // Xbf dead after k_gemm1; k_smt writes it, k_gemm2 reads it

  k_wtg1    <<<dim3(256),       256, 0, stream>>>(W_type + (size_t)2 * 262144, WT, query, W1, rpart);
  k_gate2   <<<dim3(16, 8, 3),  256, 0, stream>>>(rpart, W2, gpart);
  k_gate_fin<<<dim3(256, 3),    256, 0, stream>>>(gpart, a_type, galT, garT);
  k_uvp     <<<dim3(8, 8, 3),   256, 0, stream>>>(W_type, galT, garT, upart, vpart);
  k_uvsum   <<<dim3(64),        256, 0, stream>>>(upart, vpart, uvbf);
  k_lrm     <<<dim3(8, 64),     256, 0, stream>>>(input, uvbf, left, right, Xbf);
  k_gemm1   <<<dim3(1024),      256, 0, stream>>>(Xbf, WT, h2T);
  k_smt     <<<dim3(16, 64),    512, 0, stream>>>(adj, left, right, coefsT);
  k_gemm2   <<<dim3(1024),      256, 0, stream>>>(coefsT, h2T, out);
}

// Round 18
// 166.315 us; speedup vs baseline: 1.2551x; 1.0306x over previous
//
#include <hip/hip_runtime.h>
#include <cstdint>

typedef __attribute__((ext_vector_type(8))) short short8;
typedef __attribute__((ext_vector_type(4))) float f32x4;

// ---------- helpers ----------
__device__ __forceinline__ unsigned short f2bf(float x) {
  unsigned int u = __float_as_uint(x);
  u += 0x7FFFu + ((u >> 16) & 1u);   // round-to-nearest-even
  return (unsigned short)(u >> 16);
}

#define GLOAD16(gsrc, ldst)                                                        \
  __builtin_amdgcn_global_load_lds(                                                \
      (const __attribute__((address_space(1))) void*)(gsrc),                       \
      (__attribute__((address_space(3))) void*)(ldst), 16, 0, 0)

// ---------- merged: k_wt (blocks 0..63) + gate1 (blocks 64..255) ----------
__global__ __launch_bounds__(256, 4) void k_wtg1(const float* __restrict__ W,
                                                 unsigned short* __restrict__ WT,
                                                 const float* __restrict__ q,
                                                 const float* __restrict__ W1,
                                                 float* __restrict__ rpart) {
  __shared__ float qs[64][133];
  const int bid = blockIdx.x;
  const int tid = threadIdx.x;
  if (bid < 64) {
    float (*t)[68] = (float (*)[68])qs;
    const int d0 = (bid & 7) * 64, k0 = (bid >> 3) * 64;
    for (int idx = tid; idx < 4096; idx += 256) {
      int r = idx >> 6, c = idx & 63;
      t[r][c] = W[(size_t)(k0 + r) * 512 + d0 + c];
    }
    __syncthreads();
    for (int idx = tid; idx < 4096; idx += 256) {
      int r = idx >> 6, c = idx & 63;
      WT[(size_t)(d0 + r) * 512 + k0 + c] = f2bf(t[c][r]);
    }
    return;
  }
  const int g  = bid - 64;
  const int c0 = (g & 15) * 64;
  const int k0 = ((g >> 4) & 3) * 128;
  const int t  = g >> 6;
  const int lane = tid & 63;
  const int wcs = __builtin_amdgcn_readfirstlane(tid >> 6);
  for (int idx = tid; idx < 2048; idx += 256) {
    int r = idx >> 5, c4 = (idx & 31) * 4;
    float4 f = *(const float4*)&q[(size_t)r * 512 + k0 + c4];
    qs[r][c4 + 0] = f.x; qs[r][c4 + 1] = f.y;
    qs[r][c4 + 2] = f.z; qs[r][c4 + 3] = f.w;
  }
  __syncthreads();
  const float* Wp = W1 + ((size_t)t * 512 + k0) * 1024 + c0 + wcs * 16;
  float acc[16] = {};
  for (int k = 0; k < 128; ++k) {
    float qr = qs[lane][k];
    const float* wr = Wp + (size_t)k * 1024;
    float4 w0 = *(const float4*)(wr);
    float4 w1 = *(const float4*)(wr + 4);
    float4 w2 = *(const float4*)(wr + 8);
    float4 w3 = *(const float4*)(wr + 12);
    acc[0]  = fmaf(qr, w0.x, acc[0]);  acc[1]  = fmaf(qr, w0.y, acc[1]);
    acc[2]  = fmaf(qr, w0.z, acc[2]);  acc[3]  = fmaf(qr, w0.w, acc[3]);
    acc[4]  = fmaf(qr, w1.x, acc[4]);  acc[5]  = fmaf(qr, w1.y, acc[5]);
    acc[6]  = fmaf(qr, w1.z, acc[6]);  acc[7]  = fmaf(qr, w1.w, acc[7]);
    acc[8]  = fmaf(qr, w2.x, acc[8]);  acc[9]  = fmaf(qr, w2.y, acc[9]);
    acc[10] = fmaf(qr, w2.z, acc[10]); acc[11] = fmaf(qr, w2.w, acc[11]);
    acc[12] = fmaf(qr, w3.x, acc[12]); acc[13] = fmaf(qr, w3.y, acc[13]);
    acc[14] = fmaf(qr, w3.z, acc[14]); acc[15] = fmaf(qr, w3.w, acc[15]);
  }
  float* rp = rpart + ((size_t)(t * 4 + ((g >> 4) & 3)) * 1024 + c0 + wcs * 16) * 64 + lane;
#pragma unroll
  for (int cc = 0; cc < 16; ++cc) rp[(size_t)cc * 64] = acc[cc];
}

// ---------- gate 2 ----------
__global__ __launch_bounds__(256, 4) void k_gate2(const float* __restrict__ rpart,
                                                  const float* __restrict__ W2,
                                                  float* __restrict__ gpart) {
  const int c0 = blockIdx.x * 64;
  const int k0 = blockIdx.y * 128;
  const int t  = blockIdx.z;
  const int tid = threadIdx.x;
  const int lane = tid & 63;
  const int wcs = __builtin_amdgcn_readfirstlane(tid >> 6);
  __shared__ float qs[64][133];
  for (int idx = tid; idx < 2048; idx += 256) {
    int kl = idx >> 4, n4 = (idx & 15) * 4;
    const float* rp = rpart + ((size_t)t * 4 * 1024 + k0 + kl) * 64 + n4;
    float4 a = *(const float4*)(rp);
    float4 b = *(const float4*)(rp + 65536);
    float4 c = *(const float4*)(rp + 131072);
    float4 d = *(const float4*)(rp + 196608);
    qs[n4 + 0][kl] = fmaxf(a.x + b.x + c.x + d.x, 0.f);
    qs[n4 + 1][kl] = fmaxf(a.y + b.y + c.y + d.y, 0.f);
    qs[n4 + 2][kl] = fmaxf(a.z + b.z + c.z + d.z, 0.f);
    qs[n4 + 3][kl] = fmaxf(a.w + b.w + c.w + d.w, 0.f);
  }
  __syncthreads();
  const float* Wp = W2 + ((size_t)t << 20) + (size_t)k0 * 1024 + c0 + wcs * 16;
  float acc[16] = {};
  for (int k = 0; k < 128; ++k) {
    float qr = qs[lane][k];
    const float* wr = Wp + (size_t)k * 1024;
    float4 w0 = *(const float4*)(wr);
    float4 w1 = *(const float4*)(wr + 4);
    float4 w2 = *(const float4*)(wr + 8);
    float4 w3 = *(const float4*)(wr + 12);
    acc[0]  = fmaf(qr, w0.x, acc[0]);  acc[1]  = fmaf(qr, w0.y, acc[1]);
    acc[2]  = fmaf(qr, w0.z, acc[2]);  acc[3]  = fmaf(qr, w0.w, acc[3]);
    acc[4]  = fmaf(qr, w1.x, acc[4]);  acc[5]  = fmaf(qr, w1.y, acc[5]);
    acc[6]  = fmaf(qr, w1.z, acc[6]);  acc[7]  = fmaf(qr, w1.w, acc[7]);
    acc[8]  = fmaf(qr, w2.x, acc[8]);  acc[9]  = fmaf(qr, w2.y, acc[9]);
    acc[10] = fmaf(qr, w2.z, acc[10]); acc[11] = fmaf(qr, w2.w, acc[11]);
    acc[12] = fmaf(qr, w3.x, acc[12]); acc[13] = fmaf(qr, w3.y, acc[13]);
    acc[14] = fmaf(qr, w3.z, acc[14]); acc[15] = fmaf(qr, w3.w, acc[15]);
  }
  float* gp = gpart + ((size_t)(t * 8 + blockIdx.y) * 1024 + c0 + wcs * 16) * 64 + lane;
#pragma unroll
  for (int cc = 0; cc < 16; ++cc) gp[(size_t)cc * 64] = acc[cc];
}

// ---------- gate fin ----------
__global__ __launch_bounds__(256) void k_gate_fin(const float* __restrict__ gpart,
                                                  const float* __restrict__ a_type,
                                                  float* __restrict__ galT,
                                                  float* __restrict__ garT) {
  const int t = blockIdx.y;
  const int n = threadIdx.x & 63;
  const int mg = blockIdx.x * 4 + (threadIdx.x >> 6);
  float s = 0.f;
#pragma unroll
  for (int kc = 0; kc < 8; ++kc)
    s += gpart[((size_t)(t * 8 + kc) * 1024 + mg) * 64 + n];
  float g = 1.f / (1.f + __expf(-s));
  float ga = g * a_type[t * 1024 + mg];
  if (mg < 512) galT[((size_t)t * 512 + mg) * 64 + n] = ga;
  else          garT[((size_t)t * 512 + (mg - 512)) * 64 + n] = ga;
}

// ---------- u,v split-d partials ----------
__global__ __launch_bounds__(256, 4) void k_uvp(const float* __restrict__ W,
                                                const float* __restrict__ galT,
                                                const float* __restrict__ garT,
                                                float* __restrict__ upart,
                                                float* __restrict__ vpart) {
  const int k0 = blockIdx.x * 64;
  const int d0 = blockIdx.y * 64;
  const int t  = blockIdx.z;
  const int tid = threadIdx.x;
  const int lane = tid & 63;
  const int wk = (tid >> 6) * 16;
  __shared__ float gal_s[64][64];
  __shared__ float gar_s[64][64];
  __shared__ float W_s[64][64];
  for (int idx = tid; idx < 1024; idx += 256) {
    int d = idx >> 4, n4 = (idx & 15) * 4;
    *(float4*)&gal_s[d][n4] = *(const float4*)&galT[((size_t)t * 512 + d0 + d) * 64 + n4];
    *(float4*)&gar_s[d][n4] = *(const float4*)&garT[((size_t)t * 512 + d0 + d) * 64 + n4];
    int k = idx >> 4, d4 = (idx & 15) * 4;
    *(float4*)&W_s[k][d4] = *(const float4*)&W[((size_t)t * 512 + k0 + k) * 512 + d0 + d4];
  }
  __syncthreads();
  float au[16] = {}, av[16] = {};
  for (int dq = 0; dq < 64; dq += 4) {
    float g1[4], g2[4];
#pragma unroll
    for (int e = 0; e < 4; ++e) { g1[e] = gal_s[dq + e][lane]; g2[e] = gar_s[dq + e][lane]; }
#pragma unroll
    for (int kk = 0; kk < 16; ++kk) {
      float4 wv = *(const float4*)&W_s[wk + kk][dq];
      au[kk] = fmaf(wv.x, g1[0], fmaf(wv.y, g1[1], fmaf(wv.z, g1[2], fmaf(wv.w, g1[3], au[kk]))));
      av[kk] = fmaf(wv.x, g2[0], fmaf(wv.y, g2[1], fmaf(wv.z, g2[2], fmaf(wv.w, g2[3], av[kk]))));
    }
  }
  const size_t ob = ((size_t)((t * 8 + blockIdx.y) * 64 + lane)) * 512 + k0 + wk;
#pragma unroll
  for (int q = 0; q < 4; ++q) {
    *(float4*)&upart[ob + q * 4] = make_float4(au[q*4], au[q*4+1], au[q*4+2], au[q*4+3]);
    *(float4*)&vpart[ob + q * 4] = make_float4(av[q*4], av[q*4+1], av[q*4+2], av[q*4+3]);
  }
}

// ---------- sum uv partials -> uvbf ----------
__global__ __launch_bounds__(256) void k_uvsum(const float* __restrict__ upart,
                                               const float* __restrict__ vpart,
                                               unsigned short* __restrict__ uvbf) {
  const int n = blockIdx.x;
  for (int idx = threadIdx.x; idx < 768; idx += 256) {
    int col = idx >> 7;
    int k4 = (idx & 127) * 4;
    const float* base = (col < 3)
        ? upart + ((size_t)(col * 8) * 64 + n) * 512 + k4
        : vpart + ((size_t)((col - 3) * 8) * 64 + n) * 512 + k4;
    float4 sv = {0.f, 0.f, 0.f, 0.f};
#pragma unroll
    for (int dc = 0; dc < 8; ++dc) {
      float4 t = *(const float4*)(base + (size_t)dc * 32768);
      sv.x += t.x; sv.y += t.y; sv.z += t.z; sv.w += t.w;
    }
    ushort4 o;
    o.x = f2bf(sv.x); o.y = f2bf(sv.y); o.z = f2bf(sv.z); o.w = f2bf(sv.w);
    *(ushort4*)&uvbf[((size_t)n * 6 + col) * 512 + k4] = o;
  }
}

// ---------- k_lrm ----------
__global__ __launch_bounds__(256, 4) void k_lrm(const float* __restrict__ x,
                                                const unsigned short* __restrict__ uvbf,
                                                float* __restrict__ left,
                                                float* __restrict__ right,
                                                unsigned short* __restrict__ Xbf) {
  const int n  = blockIdx.y;
  const int i0 = blockIdx.x * 64;
  const int tid = threadIdx.x;
  const int lane = tid & 63, wid = tid >> 6;
  __shared__ unsigned short uvs[16][520];
  __shared__ __attribute__((aligned(16))) char As[4096];

  for (int idx = tid; idx < 16 * 64; idx += 256) {
    int col = idx >> 6, k8 = (idx & 63) * 8;
    ushort4 z0 = {0, 0, 0, 0}, z1 = {0, 0, 0, 0};
    if (col < 6) {
      const unsigned short* p = uvbf + ((size_t)n * 6 + col) * 512 + k8;
      z0 = *(const ushort4*)p;
      z1 = *(const ushort4*)(p + 4);
    }
    *(ushort4*)&uvs[col][k8]     = z0;
    *(ushort4*)&uvs[col][k8 + 4] = z1;
  }
  const int row = tid >> 2, sub = tid & 3;
  const float* gp = x + ((size_t)n * 512 + i0 + row) * 512 + sub * 8;
  unsigned short* xp = Xbf + ((size_t)n * 512 + i0 + row) * 512 + sub * 8;
  const int lds_off = row * 64 + ((sub ^ (row & 3)) << 4);
  const int arow = wid * 16 + (lane & 15);
  const int a_off = arow * 64 + (((lane >> 4) ^ (arow & 3)) << 4);
  f32x4 acc = {0.f, 0.f, 0.f, 0.f};
  float4 f0 = *(const float4*)(gp);
  float4 f1 = *(const float4*)(gp + 4);
  __syncthreads();
  for (int s = 0; s < 16; ++s) {
    uint4 pk;
    pk.x = ((unsigned)f2bf(f0.y) << 16) | f2bf(f0.x);
    pk.y = ((unsigned)f2bf(f0.w) << 16) | f2bf(f0.z);
    pk.z = ((unsigned)f2bf(f1.y) << 16) | f2bf(f1.x);
    pk.w = ((unsigned)f2bf(f1.w) << 16) | f2bf(f1.z);
    if (s < 15) {
      f0 = *(const float4*)(gp + (s + 1) * 32);
      f1 = *(const float4*)(gp + (s + 1) * 32 + 4);
    }
    *(uint4*)(xp + s * 32) = pk;
    *(uint4*)(As + lds_off) = pk;
    __syncthreads();
    short8 a = *(const short8*)(As + a_off);
    short8 b = *(const short8*)&uvs[lane & 15][s * 32 + (lane >> 4) * 8];
    acc = __builtin_amdgcn_mfma_f32_16x16x32_bf16(a, b, acc, 0, 0, 0);
    __syncthreads();
  }
  const int col = lane & 15;
  if (col < 6) {
    float* dst = (col < 3) ? left : right;
    const int t = (col < 3) ? col : col - 3;
    const int i = i0 + wid * 16 + ((lane >> 4) << 2);
    float* p = dst + ((size_t)t * 64 + n) * 512 + i;
    p[0] = acc.x; p[1] = acc.y; p[2] = acc.z; p[3] = acc.w;
  }
}

// ---------- MFMA GEMM1: h2T[n][d][i] = (X[n] @ W2)^T ; 3-buffer ring pipeline ----------
__global__ __launch_bounds__(256) void k_gemm1(const unsigned short* __restrict__ X,
                                               const unsigned short* __restrict__ WT,
                                               unsigned short* __restrict__ h2T) {
  __shared__ __attribute__((aligned(16))) char smem[49152];  // 3 x (A 8K | B 8K); Ct union
  const int s = blockIdx.x;
  const int n  = ((s >> 7) << 3) | (s & 7);
  const int jj = (s >> 3) & 15;
  const int i0 = (jj >> 2) * 128;
  const int d0 = (jj & 3) * 128;
  const int tid = threadIdx.x;
  const int lane = tid & 63, w = tid >> 6;
  const int wm = w >> 1, wn = w & 1;
  const int srow = tid >> 2;
  const int kbp  = tid & 3;
  f32x4 acc[4][4];
#pragma unroll
  for (int a = 0; a < 4; ++a)
#pragma unroll
    for (int b = 0; b < 4; ++b) acc[a][b] = (f32x4){0.f, 0.f, 0.f, 0.f};

  const size_t xbase = (size_t)n * 262144;
  int ra[4], rb[4];
#pragma unroll
  for (int f = 0; f < 4; ++f) {
    int row = wm * 64 + f * 16 + (lane & 15);
    ra[f] = row * 64 + (((lane >> 4) ^ ((row >> 1) & 3)) << 4);
    int rowb = wn * 64 + f * 16 + (lane & 15);
    rb[f] = rowb * 64 + (((lane >> 4) ^ ((rowb >> 1) & 3)) << 4);
  }
  const int kl0 = (kbp ^ ((srow >> 1) & 3)) * 8;
  const int kl1 = (kbp ^ (((64 + srow) >> 1) & 3)) * 8;
  const unsigned short* xr0 = X + xbase + (size_t)(i0 + srow) * 512 + kl0;
  const unsigned short* xr1 = X + xbase + (size_t)(i0 + 64 + srow) * 512 + kl1;
  const unsigned short* wr0 = WT + (size_t)(d0 + srow) * 512 + kl0;
  const unsigned short* wr1 = WT + (size_t)(d0 + 64 + srow) * 512 + kl1;

#define G1_STAGE(tt, buf)                                               \
  do {                                                                  \
    char* Ab = smem + (buf) * 16384;                                    \
    char* Bb = Ab + 8192;                                               \
    const int kc_ = (tt) * 32;                                          \
    GLOAD16(xr0 + kc_, Ab + tid * 16);                                  \
    GLOAD16(xr1 + kc_, Ab + 4096 + tid * 16);                           \
    GLOAD16(wr0 + kc_, Bb + tid * 16);                                  \
    GLOAD16(wr1 + kc_, Bb + 4096 + tid * 16);                           \
  } while (0)

  G1_STAGE(0, 0);
  G1_STAGE(1, 1);
  int cur = 0;
  for (int t = 0; t < 16; ++t) {
    if (t < 15) asm volatile("s_waitcnt vmcnt(4)" ::: "memory");
    else        asm volatile("s_waitcnt vmcnt(0)" ::: "memory");
    __builtin_amdgcn_s_barrier();
    if (t < 14) {
      int nb = cur;                     // ring: t+2 reuses buffer (cur+2)%3 == just-freed? no: use (cur+2)%3
      nb = cur == 0 ? 2 : (cur == 1 ? 0 : 1);
      G1_STAGE(t + 2, nb);
    }
    char* Ac = smem + cur * 16384;
    char* Bc = Ac + 8192;
    short8 a[4], b[4];
#pragma unroll
    for (int f = 0; f < 4; ++f) a[f] = *(const short8*)(Ac + ra[f]);
#pragma unroll
    for (int f = 0; f < 4; ++f) b[f] = *(const short8*)(Bc + rb[f]);
#pragma unroll
    for (int mf = 0; mf < 4; ++mf)
#pragma unroll
      for (int nf = 0; nf < 4; ++nf)
        acc[mf][nf] = __builtin_amdgcn_mfma_f32_16x16x32_bf16(a[mf], b[nf], acc[mf][nf], 0, 0, 0);
    asm volatile("s_waitcnt lgkmcnt(0)" ::: "memory");
    __builtin_amdgcn_sched_barrier(0);
    __builtin_amdgcn_s_barrier();
    cur = cur == 2 ? 0 : cur + 1;
  }
#undef G1_STAGE
  unsigned short (*Ct)[136] = (unsigned short (*)[136])smem;
#pragma unroll
  for (int mf = 0; mf < 4; ++mf)
#pragma unroll
    for (int nf = 0; nf < 4; ++nf) {
      f32x4 vv = acc[mf][nf];
      int dl = wn * 64 + nf * 16 + (lane & 15);
      int il = wm * 64 + mf * 16 + ((lane >> 4) << 2);
      ushort4 pk;
      pk.x = f2bf(vv.x); pk.y = f2bf(vv.y); pk.z = f2bf(vv.z); pk.w = f2bf(vv.w);
      *(ushort4*)&Ct[dl][il] = pk;
    }
  __syncthreads();
  const size_t obase = xbase + (size_t)d0 * 512 + i0;
#pragma unroll
  for (int q = 0; q < 8; ++q) {
    int f = q * 2048 + tid * 8;
    int dl = f >> 7, il = f & 127;
    *(uint4*)&h2T[obase + (size_t)dl * 512 + il] = *(const uint4*)&Ct[dl][il];
  }
}

// ---------- fused masked softmax + transpose (512 thr / 8 waves, 32 rows) ----------
__global__ __launch_bounds__(512, 2) void k_smt(const int* __restrict__ adj,
                                                const float* __restrict__ left,
                                                const float* __restrict__ right,
                                                unsigned short* __restrict__ ct) {
  const int n  = blockIdx.y;
  const int i0 = blockIdx.x * 32;
  const int tid = threadIdx.x;
  const int lane = tid & 63, wid = tid >> 6;
  const int l15 = lane & 15;
  const int il  = wid * 4 + (lane >> 4);     // row 0..31
  __shared__ float rs_s[32][49];
  __shared__ float ls[3][32];
  __shared__ unsigned short tile[32][520];
  for (int idx = tid; idx < 1536; idx += 512) {
    int t = idx >> 9, j = idx & 511;
    rs_s[j & 31][t * 16 + (j >> 5)] = right[((size_t)t * 64 + n) * 512 + j];
  }
  if (tid < 96) {
    int t = tid >> 5, ii = tid & 31;
    ls[t][ii] = left[((size_t)t * 64 + n) * 512 + i0 + ii];
  }
  __syncthreads();
  const int* adjb = adj + ((size_t)(n * 512 + i0 + il)) * 512;
  int4 A[4], B[4];
#pragma unroll
  for (int q = 0; q < 4; ++q) {
    const int* p = adjb + q * 128 + l15 * 8;
    A[q] = *(const int4*)p;
    B[q] = *(const int4*)(p + 4);
  }
  const float l0 = ls[0][il], l1 = ls[1][il], l2 = ls[2][il];
  const int base0 = ((l15 & 3) * 8) * 49 + (l15 >> 2);
  const float* rsf = (const float*)rs_s;
  float s[4][8];
  float mloc = -3.0e38f;
#pragma unroll
  for (int q = 0; q < 4; ++q) {
    int tv[8] = {A[q].x, A[q].y, A[q].z, A[q].w, B[q].x, B[q].y, B[q].z, B[q].w};
#pragma unroll
    for (int x = 0; x < 8; ++x) {
      int t = tv[x];
      int tt = (t > 0) ? (t - 1) : 0;
      float lv = (t >= 2) ? ((t == 3) ? l2 : l1) : l0;
      float r = rsf[base0 + tt * 16 + (x * 49 + q * 4)];
      float sv = lv + r;
      sv = (sv >= 0.f) ? sv : 0.2f * sv;
      sv = (t == 0) ? -9.0e15f : sv;
      s[q][x] = sv;
      mloc = fmaxf(mloc, sv);
    }
  }
  float z = 0.f;
#pragma unroll
  for (int q = 0; q < 4; ++q)
#pragma unroll
    for (int x = 0; x < 8; ++x) {
      float e = __expf(s[q][x] - mloc);
      s[q][x] = e;
      z += e;
    }
  float m = mloc;
#pragma unroll
  for (int k = 1; k <= 8; k <<= 1) {
    float mo = __shfl_xor(m, k);
    float zo = __shfl_xor(z, k);
    float mn = fmaxf(m, mo);
    z = z * __expf(m - mn) + zo * __expf(mo - mn);
    m = mn;
  }
  const float factor = __expf(mloc - m) / z;
#pragma unroll
  for (int q = 0; q < 4; ++q) {
    uint4 pk;
    pk.x = ((unsigned)f2bf(s[q][1] * factor) << 16) | f2bf(s[q][0] * factor);
    pk.y = ((unsigned)f2bf(s[q][3] * factor) << 16) | f2bf(s[q][2] * factor);
    pk.z = ((unsigned)f2bf(s[q][5] * factor) << 16) | f2bf(s[q][4] * factor);
    pk.w = ((unsigned)f2bf(s[q][7] * factor) << 16) | f2bf(s[q][6] * factor);
    *(uint4*)&tile[il][q * 128 + l15 * 8] = pk;
  }
  __syncthreads();
  unsigned short* ob = ct + (size_t)n * 262144 + i0;
#pragma unroll
  for (int pass = 0; pass < 4; ++pass) {
    int j = pass * 128 + (tid >> 2);
    int i8 = (tid & 3) * 8;
    uint4 o;
    o.x = (unsigned)tile[i8 + 0][j] | ((unsigned)tile[i8 + 1][j] << 16);
    o.y = (unsigned)tile[i8 + 2][j] | ((unsigned)tile[i8 + 3][j] << 16);
    o.z = (unsigned)tile[i8 + 4][j] | ((unsigned)tile[i8 + 5][j] << 16);
    o.w = (unsigned)tile[i8 + 6][j] | ((unsigned)tile[i8 + 7][j] << 16);
    *(uint4*)&ob[(size_t)j * 512 + i8] = o;
  }
}

// ---------- MFMA GEMM2: out[n][j][d] = coefsT[n] @ h2T[n]^T ; 3-buffer ring ----------
__global__ __launch_bounds__(256) void k_gemm2(const unsigned short* __restrict__ CT,
                                               const unsigned short* __restrict__ H2T,
                                               float* __restrict__ out) {
  __shared__ __attribute__((aligned(16))) char smem[49152];
  const int s = blockIdx.x;
  const int n  = ((s >> 7) << 3) | (s & 7);
  const int jj = (s >> 3) & 15;
  const int j0 = (jj >> 2) * 128;
  const int d0 = (jj & 3) * 128;
  const int tid = threadIdx.x;
  const int lane = tid & 63, w = tid >> 6;
  const int wm = w >> 1, wn = w & 1;
  const int srow = tid >> 2;
  const int kbp  = tid & 3;
  f32x4 acc[4][4];
#pragma unroll
  for (int a = 0; a < 4; ++a)
#pragma unroll
    for (int b = 0; b < 4; ++b) acc[a][b] = (f32x4){0.f, 0.f, 0.f, 0.f};

  const size_t base = (size_t)n * 262144;
  int ra[4], rb[4];
#pragma unroll
  for (int f = 0; f < 4; ++f) {
    int row = wm * 64 + f * 16 + (lane & 15);
    ra[f] = row * 64 + (((lane >> 4) ^ ((row >> 1) & 3)) << 4);
    int rowb = wn * 64 + f * 16 + (lane & 15);
    rb[f] = rowb * 64 + (((lane >> 4) ^ ((rowb >> 1) & 3)) << 4);
  }
  const int kl0 = (kbp ^ ((srow >> 1) & 3)) * 8;
  const int kl1 = (kbp ^ (((64 + srow) >> 1) & 3)) * 8;
  const unsigned short* cr0 = CT + base + (size_t)(j0 + srow) * 512 + kl0;
  const unsigned short* cr1 = CT + base + (size_t)(j0 + 64 + srow) * 512 + kl1;
  const unsigned short* hr0 = H2T + base + (size_t)(d0 + srow) * 512 + kl0;
  const unsigned short* hr1 = H2T + base + (size_t)(d0 + 64 + srow) * 512 + kl1;

#define G2_STAGE(tt, buf)                                               \
  do {                                                                  \
    char* Ab = smem + (buf) * 16384;                                    \
    char* Bb = Ab + 8192;                                               \
    const int kc_ = (tt) * 32;                                          \
    GLOAD16(cr0 + kc_, Ab + tid * 16);                                  \
    GLOAD16(cr1 + kc_, Ab + 4096 + tid * 16);                           \
    GLOAD16(hr0 + kc_, Bb + tid * 16);                                  \
    GLOAD16(hr1 + kc_, Bb + 4096 + tid * 16);                           \
  } while (0)

  G2_STAGE(0, 0);
  G2_STAGE(1, 1);
  int cur = 0;
  for (int t = 0; t < 16; ++t) {
    if (t < 15) asm volatile("s_waitcnt vmcnt(4)" ::: "memory");
    else        asm volatile("s_waitcnt vmcnt(0)" ::: "memory");
    __builtin_amdgcn_s_barrier();
    if (t < 14) {
      int nb = cur == 0 ? 2 : (cur == 1 ? 0 : 1);
      G2_STAGE(t + 2, nb);
    }
    char* Ac = smem + cur * 16384;
    char* Bc = Ac + 8192;
    short8 a[4], b[4];
#pragma unroll
    for (int f = 0; f < 4; ++f) a[f] = *(const short8*)(Ac + ra[f]);
#pragma unroll
    for (int f = 0; f < 4; ++f) b[f] = *(const short8*)(Bc + rb[f]);
#pragma unroll
    for (int mf = 0; mf < 4; ++mf)
#pragma unroll
      for (int nf = 0; nf < 4; ++nf)
        acc[mf][nf] = __builtin_amdgcn_mfma_f32_16x16x32_bf16(a[mf], b[nf], acc[mf][nf], 0, 0, 0);
    asm volatile("s_waitcnt lgkmcnt(0)" ::: "memory");
    __builtin_amdgcn_sched_barrier(0);
    __builtin_amdgcn_s_barrier();
    cur = cur == 2 ? 0 : cur + 1;
  }
#undef G2_STAGE
  const int jb = j0 + wm * 64 + (lane >> 4) * 4;
  const int db = d0 + wn * 64 + (lane & 15);
#pragma unroll
  for (int mf = 0; mf < 4; ++mf)
#pragma unroll
    for (int nf = 0; nf < 4; ++nf) {
      f32x4 vv = acc[mf][nf];
      float* op = out + base + (size_t)(jb + mf * 16) * 512 + db + nf * 16;
      op[0]    = vv.x;
      op[512]  = vv.y;
      op[1024] = vv.z;
      op[1536] = vv.w;
    }
}

extern "C" void kernel_launch(void* const* d_in, const int* in_sizes, int n_in,
                              void* d_out, int out_size, void* d_ws, size_t ws_size,
                              hipStream_t stream) {
  const float* input  = (const float*)d_in[0];
  const int*   adj    = (const int*)d_in[1];
  const float* query  = (const float*)d_in[3];
  const float* W_type = (const float*)d_in[4];
  const float* a_type = (const float*)d_in[5];
  const float* W1     = (const float*)d_in[6];
  const float* W2     = (const float*)d_in[7];
  float* out = (float*)d_out;

  char* ws = (char*)d_ws;
  float* galT  = (float*)(ws);                              //  393,216 B
  float* garT  = (float*)(ws + 393216);                     //  393,216 B
  unsigned short* uvbf = (unsigned short*)(ws + 786432);    //  393,216 B
  float* left  = (float*)(ws + 1179648);                    //  393,216 B
  float* right = (float*)(ws + 1572864);                    //  393,216 B
  unsigned short* Xbf = (unsigned short*)(ws + 2359296);    // 33,554,432 B (reused as coefsT)
  unsigned short* h2T = (unsigned short*)(ws + 35913728);   // 33,554,432 B
  // partials alias h2T's region: all dead before k_gemm1 writes h2T
  float* rpart = (float*)(ws + 35913728);                   //  3,145,728 B
  float* gpart = (float*)(ws + 39059456);                   //  6,291,456 B
  float* upart = (float*)(ws + 45350912);                   //  3,145,728 B
  float* vpart = (float*)(ws + 48496640);                   //  3,145,728 B
  unsigned short* WT  = (unsigned short*)(ws + 69468160);   //    524,288 B
  // total ws use: 69,992,448 B
  unsigned short* coefsT = Xbf;   // Xbf dead after k_gemm1; k_smt writes it, k_gemm2 reads it

  k_wtg1    <<<dim3(256),       256, 0, stream>>>(W_type + (size_t)2 * 262144, WT, query, W1, rpart);
  k_gate2   <<<dim3(16, 8, 3),  256, 0, stream>>>(rpart, W2, gpart);
  k_gate_fin<<<dim3(256, 3),    256, 0, stream>>>(gpart, a_type, galT, garT);
  k_uvp     <<<dim3(8, 8, 3),   256, 0, stream>>>(W_type, galT, garT, upart, vpart);
  k_uvsum   <<<dim3(64),        256, 0, stream>>>(upart, vpart, uvbf);
  k_lrm     <<<dim3(8, 64),     256, 0, stream>>>(input, uvbf, left, right, Xbf);
  k_gemm1   <<<dim3(1024),      256, 0, stream>>>(Xbf, WT, h2T);
  k_smt     <<<dim3(16, 64),    512, 0, stream>>>(adj, left, right, coefsT);
  k_gemm2   <<<dim3(1024),      256, 0, stream>>>(coefsT, h2T, out);
}

// Round 19
// 164.560 us; speedup vs baseline: 1.2685x; 1.0107x over previous
//
#include <hip/hip_runtime.h>
#include <cstdint>

typedef __attribute__((ext_vector_type(8))) short short8;
typedef __attribute__((ext_vector_type(4))) float f32x4;

// ---------- helpers ----------
__device__ __forceinline__ unsigned short f2bf(float x) {
  unsigned int u = __float_as_uint(x);
  u += 0x7FFFu + ((u >> 16) & 1u);   // round-to-nearest-even
  return (unsigned short)(u >> 16);
}

#define GLOAD16(gsrc, ldst)                                                        \
  __builtin_amdgcn_global_load_lds(                                                \
      (const __attribute__((address_space(1))) void*)(gsrc),                       \
      (__attribute__((address_space(3))) void*)(ldst), 16, 0, 0)

// ---------- merged: k_wt (blocks 0..63) + gate1 (blocks 64..255) ----------
__global__ __launch_bounds__(256, 4) void k_wtg1(const float* __restrict__ W,
                                                 unsigned short* __restrict__ WT,
                                                 const float* __restrict__ q,
                                                 const float* __restrict__ W1,
                                                 float* __restrict__ rpart) {
  __shared__ float qs[64][133];
  const int bid = blockIdx.x;
  const int tid = threadIdx.x;
  if (bid < 64) {
    float (*t)[68] = (float (*)[68])qs;
    const int d0 = (bid & 7) * 64, k0 = (bid >> 3) * 64;
    for (int idx = tid; idx < 4096; idx += 256) {
      int r = idx >> 6, c = idx & 63;
      t[r][c] = W[(size_t)(k0 + r) * 512 + d0 + c];
    }
    __syncthreads();
    for (int idx = tid; idx < 4096; idx += 256) {
      int r = idx >> 6, c = idx & 63;
      WT[(size_t)(d0 + r) * 512 + k0 + c] = f2bf(t[c][r]);
    }
    return;
  }
  const int g  = bid - 64;
  const int c0 = (g & 15) * 64;
  const int k0 = ((g >> 4) & 3) * 128;
  const int t  = g >> 6;
  const int lane = tid & 63;
  const int wcs = __builtin_amdgcn_readfirstlane(tid >> 6);
  for (int idx = tid; idx < 2048; idx += 256) {
    int r = idx >> 5, c4 = (idx & 31) * 4;
    float4 f = *(const float4*)&q[(size_t)r * 512 + k0 + c4];
    qs[r][c4 + 0] = f.x; qs[r][c4 + 1] = f.y;
    qs[r][c4 + 2] = f.z; qs[r][c4 + 3] = f.w;
  }
  __syncthreads();
  const float* Wp = W1 + ((size_t)t * 512 + k0) * 1024 + c0 + wcs * 16;
  float acc[16] = {};
  for (int k = 0; k < 128; ++k) {
    float qr = qs[lane][k];
    const float* wr = Wp + (size_t)k * 1024;
    float4 w0 = *(const float4*)(wr);
    float4 w1 = *(const float4*)(wr + 4);
    float4 w2 = *(const float4*)(wr + 8);
    float4 w3 = *(const float4*)(wr + 12);
    acc[0]  = fmaf(qr, w0.x, acc[0]);  acc[1]  = fmaf(qr, w0.y, acc[1]);
    acc[2]  = fmaf(qr, w0.z, acc[2]);  acc[3]  = fmaf(qr, w0.w, acc[3]);
    acc[4]  = fmaf(qr, w1.x, acc[4]);  acc[5]  = fmaf(qr, w1.y, acc[5]);
    acc[6]  = fmaf(qr, w1.z, acc[6]);  acc[7]  = fmaf(qr, w1.w, acc[7]);
    acc[8]  = fmaf(qr, w2.x, acc[8]);  acc[9]  = fmaf(qr, w2.y, acc[9]);
    acc[10] = fmaf(qr, w2.z, acc[10]); acc[11] = fmaf(qr, w2.w, acc[11]);
    acc[12] = fmaf(qr, w3.x, acc[12]); acc[13] = fmaf(qr, w3.y, acc[13]);
    acc[14] = fmaf(qr, w3.z, acc[14]); acc[15] = fmaf(qr, w3.w, acc[15]);
  }
  float* rp = rpart + ((size_t)(t * 4 + ((g >> 4) & 3)) * 1024 + c0 + wcs * 16) * 64 + lane;
#pragma unroll
  for (int cc = 0; cc < 16; ++cc) rp[(size_t)cc * 64] = acc[cc];
}

// ---------- gate 2 ----------
__global__ __launch_bounds__(256, 4) void k_gate2(const float* __restrict__ rpart,
                                                  const float* __restrict__ W2,
                                                  float* __restrict__ gpart) {
  const int c0 = blockIdx.x * 64;
  const int k0 = blockIdx.y * 128;
  const int t  = blockIdx.z;
  const int tid = threadIdx.x;
  const int lane = tid & 63;
  const int wcs = __builtin_amdgcn_readfirstlane(tid >> 6);
  __shared__ float qs[64][133];
  for (int idx = tid; idx < 2048; idx += 256) {
    int kl = idx >> 4, n4 = (idx & 15) * 4;
    const float* rp = rpart + ((size_t)t * 4 * 1024 + k0 + kl) * 64 + n4;
    float4 a = *(const float4*)(rp);
    float4 b = *(const float4*)(rp + 65536);
    float4 c = *(const float4*)(rp + 131072);
    float4 d = *(const float4*)(rp + 196608);
    qs[n4 + 0][kl] = fmaxf(a.x + b.x + c.x + d.x, 0.f);
    qs[n4 + 1][kl] = fmaxf(a.y + b.y + c.y + d.y, 0.f);
    qs[n4 + 2][kl] = fmaxf(a.z + b.z + c.z + d.z, 0.f);
    qs[n4 + 3][kl] = fmaxf(a.w + b.w + c.w + d.w, 0.f);
  }
  __syncthreads();
  const float* Wp = W2 + ((size_t)t << 20) + (size_t)k0 * 1024 + c0 + wcs * 16;
  float acc[16] = {};
  for (int k = 0; k < 128; ++k) {
    float qr = qs[lane][k];
    const float* wr = Wp + (size_t)k * 1024;
    float4 w0 = *(const float4*)(wr);
    float4 w1 = *(const float4*)(wr + 4);
    float4 w2 = *(const float4*)(wr + 8);
    float4 w3 = *(const float4*)(wr + 12);
    acc[0]  = fmaf(qr, w0.x, acc[0]);  acc[1]  = fmaf(qr, w0.y, acc[1]);
    acc[2]  = fmaf(qr, w0.z, acc[2]);  acc[3]  = fmaf(qr, w0.w, acc[3]);
    acc[4]  = fmaf(qr, w1.x, acc[4]);  acc[5]  = fmaf(qr, w1.y, acc[5]);
    acc[6]  = fmaf(qr, w1.z, acc[6]);  acc[7]  = fmaf(qr, w1.w, acc[7]);
    acc[8]  = fmaf(qr, w2.x, acc[8]);  acc[9]  = fmaf(qr, w2.y, acc[9]);
    acc[10] = fmaf(qr, w2.z, acc[10]); acc[11] = fmaf(qr, w2.w, acc[11]);
    acc[12] = fmaf(qr, w3.x, acc[12]); acc[13] = fmaf(qr, w3.y, acc[13]);
    acc[14] = fmaf(qr, w3.z, acc[14]); acc[15] = fmaf(qr, w3.w, acc[15]);
  }
  float* gp = gpart + ((size_t)(t * 8 + blockIdx.y) * 1024 + c0 + wcs * 16) * 64 + lane;
#pragma unroll
  for (int cc = 0; cc < 16; ++cc) gp[(size_t)cc * 64] = acc[cc];
}

// ---------- gate fin ----------
__global__ __launch_bounds__(256) void k_gate_fin(const float* __restrict__ gpart,
                                                  const float* __restrict__ a_type,
                                                  float* __restrict__ galT,
                                                  float* __restrict__ garT) {
  const int t = blockIdx.y;
  const int n = threadIdx.x & 63;
  const int mg = blockIdx.x * 4 + (threadIdx.x >> 6);
  float s = 0.f;
#pragma unroll
  for (int kc = 0; kc < 8; ++kc)
    s += gpart[((size_t)(t * 8 + kc) * 1024 + mg) * 64 + n];
  float g = 1.f / (1.f + __expf(-s));
  float ga = g * a_type[t * 1024 + mg];
  if (mg < 512) galT[((size_t)t * 512 + mg) * 64 + n] = ga;
  else          garT[((size_t)t * 512 + (mg - 512)) * 64 + n] = ga;
}

// ---------- u,v split-d partials ----------
__global__ __launch_bounds__(256, 4) void k_uvp(const float* __restrict__ W,
                                                const float* __restrict__ galT,
                                                const float* __restrict__ garT,
                                                float* __restrict__ upart,
                                                float* __restrict__ vpart) {
  const int k0 = blockIdx.x * 64;
  const int d0 = blockIdx.y * 64;
  const int t  = blockIdx.z;
  const int tid = threadIdx.x;
  const int lane = tid & 63;
  const int wk = (tid >> 6) * 16;
  __shared__ float gal_s[64][64];
  __shared__ float gar_s[64][64];
  __shared__ float W_s[64][64];
  for (int idx = tid; idx < 1024; idx += 256) {
    int d = idx >> 4, n4 = (idx & 15) * 4;
    *(float4*)&gal_s[d][n4] = *(const float4*)&galT[((size_t)t * 512 + d0 + d) * 64 + n4];
    *(float4*)&gar_s[d][n4] = *(const float4*)&garT[((size_t)t * 512 + d0 + d) * 64 + n4];
    int k = idx >> 4, d4 = (idx & 15) * 4;
    *(float4*)&W_s[k][d4] = *(const float4*)&W[((size_t)t * 512 + k0 + k) * 512 + d0 + d4];
  }
  __syncthreads();
  float au[16] = {}, av[16] = {};
  for (int dq = 0; dq < 64; dq += 4) {
    float g1[4], g2[4];
#pragma unroll
    for (int e = 0; e < 4; ++e) { g1[e] = gal_s[dq + e][lane]; g2[e] = gar_s[dq + e][lane]; }
#pragma unroll
    for (int kk = 0; kk < 16; ++kk) {
      float4 wv = *(const float4*)&W_s[wk + kk][dq];
      au[kk] = fmaf(wv.x, g1[0], fmaf(wv.y, g1[1], fmaf(wv.z, g1[2], fmaf(wv.w, g1[3], au[kk]))));
      av[kk] = fmaf(wv.x, g2[0], fmaf(wv.y, g2[1], fmaf(wv.z, g2[2], fmaf(wv.w, g2[3], av[kk]))));
    }
  }
  const size_t ob = ((size_t)((t * 8 + blockIdx.y) * 64 + lane)) * 512 + k0 + wk;
#pragma unroll
  for (int q = 0; q < 4; ++q) {
    *(float4*)&upart[ob + q * 4] = make_float4(au[q*4], au[q*4+1], au[q*4+2], au[q*4+3]);
    *(float4*)&vpart[ob + q * 4] = make_float4(av[q*4], av[q*4+1], av[q*4+2], av[q*4+3]);
  }
}

// ---------- sum uv partials -> uvbf ----------
__global__ __launch_bounds__(256) void k_uvsum(const float* __restrict__ upart,
                                               const float* __restrict__ vpart,
                                               unsigned short* __restrict__ uvbf) {
  const int n = blockIdx.x;
  for (int idx = threadIdx.x; idx < 768; idx += 256) {
    int col = idx >> 7;
    int k4 = (idx & 127) * 4;
    const float* base = (col < 3)
        ? upart + ((size_t)(col * 8) * 64 + n) * 512 + k4
        : vpart + ((size_t)((col - 3) * 8) * 64 + n) * 512 + k4;
    float4 sv = {0.f, 0.f, 0.f, 0.f};
#pragma unroll
    for (int dc = 0; dc < 8; ++dc) {
      float4 t = *(const float4*)(base + (size_t)dc * 32768);
      sv.x += t.x; sv.y += t.y; sv.z += t.z; sv.w += t.w;
    }
    ushort4 o;
    o.x = f2bf(sv.x); o.y = f2bf(sv.y); o.z = f2bf(sv.z); o.w = f2bf(sv.w);
    *(ushort4*)&uvbf[((size_t)n * 6 + col) * 512 + k4] = o;
  }
}

// ---------- k_lrm: double-buffered A tile -> ONE barrier per k-step ----------
__global__ __launch_bounds__(256, 4) void k_lrm(const float* __restrict__ x,
                                                const unsigned short* __restrict__ uvbf,
                                                float* __restrict__ left,
                                                float* __restrict__ right,
                                                unsigned short* __restrict__ Xbf) {
  const int n  = blockIdx.y;
  const int i0 = blockIdx.x * 64;
  const int tid = threadIdx.x;
  const int lane = tid & 63, wid = tid >> 6;
  __shared__ unsigned short uvs[16][520];
  __shared__ __attribute__((aligned(16))) char As[8192];   // 2 x 4096 dbuf

  for (int idx = tid; idx < 16 * 64; idx += 256) {
    int col = idx >> 6, k8 = (idx & 63) * 8;
    ushort4 z0 = {0, 0, 0, 0}, z1 = {0, 0, 0, 0};
    if (col < 6) {
      const unsigned short* p = uvbf + ((size_t)n * 6 + col) * 512 + k8;
      z0 = *(const ushort4*)p;
      z1 = *(const ushort4*)(p + 4);
    }
    *(ushort4*)&uvs[col][k8]     = z0;
    *(ushort4*)&uvs[col][k8 + 4] = z1;
  }
  const int row = tid >> 2, sub = tid & 3;
  const float* gp = x + ((size_t)n * 512 + i0 + row) * 512 + sub * 8;
  unsigned short* xp = Xbf + ((size_t)n * 512 + i0 + row) * 512 + sub * 8;
  const int lds_off = row * 64 + ((sub ^ (row & 3)) << 4);
  const int arow = wid * 16 + (lane & 15);
  const int a_off = arow * 64 + (((lane >> 4) ^ (arow & 3)) << 4);
  f32x4 acc = {0.f, 0.f, 0.f, 0.f};
  float4 f0 = *(const float4*)(gp);
  float4 f1 = *(const float4*)(gp + 4);
  __syncthreads();                              // uvs staged
  for (int s = 0; s < 16; ++s) {
    const int buf = (s & 1) * 4096;
    uint4 pk;
    pk.x = ((unsigned)f2bf(f0.y) << 16) | f2bf(f0.x);
    pk.y = ((unsigned)f2bf(f0.w) << 16) | f2bf(f0.z);
    pk.z = ((unsigned)f2bf(f1.y) << 16) | f2bf(f1.x);
    pk.w = ((unsigned)f2bf(f1.w) << 16) | f2bf(f1.z);
    if (s < 15) {
      f0 = *(const float4*)(gp + (s + 1) * 32);
      f1 = *(const float4*)(gp + (s + 1) * 32 + 4);
    }
    *(uint4*)(xp + s * 32) = pk;
    *(uint4*)(As + buf + lds_off) = pk;
    __syncthreads();                            // tile s visible; prev buf reads done
    short8 a = *(const short8*)(As + buf + a_off);
    short8 b = *(const short8*)&uvs[lane & 15][s * 32 + (lane >> 4) * 8];
    acc = __builtin_amdgcn_mfma_f32_16x16x32_bf16(a, b, acc, 0, 0, 0);
    // no trailing barrier: next iter writes the OTHER buffer; by the time any
    // thread passes the NEXT sync, this iter's ds_reads have completed (MFMA
    // consumed them), so buf reuse at s+2 is safe.
  }
  const int col = lane & 15;
  if (col < 6) {
    float* dst = (col < 3) ? left : right;
    const int t = (col < 3) ? col : col - 3;
    const int i = i0 + wid * 16 + ((lane >> 4) << 2);
    float* p = dst + ((size_t)t * 64 + n) * 512 + i;
    p[0] = acc.x; p[1] = acc.y; p[2] = acc.z; p[3] = acc.w;
  }
}

// ---------- MFMA GEMM1: h2T[n][d][i] = (X[n] @ W2)^T ; 3-buffer ring pipeline ----------
__global__ __launch_bounds__(256) void k_gemm1(const unsigned short* __restrict__ X,
                                               const unsigned short* __restrict__ WT,
                                               unsigned short* __restrict__ h2T) {
  __shared__ __attribute__((aligned(16))) char smem[49152];  // 3 x (A 8K | B 8K); Ct union
  const int s = blockIdx.x;
  const int n  = ((s >> 7) << 3) | (s & 7);
  const int jj = (s >> 3) & 15;
  const int i0 = (jj >> 2) * 128;
  const int d0 = (jj & 3) * 128;
  const int tid = threadIdx.x;
  const int lane = tid & 63, w = tid >> 6;
  const int wm = w >> 1, wn = w & 1;
  const int srow = tid >> 2;
  const int kbp  = tid & 3;
  f32x4 acc[4][4];
#pragma unroll
  for (int a = 0; a < 4; ++a)
#pragma unroll
    for (int b = 0; b < 4; ++b) acc[a][b] = (f32x4){0.f, 0.f, 0.f, 0.f};

  const size_t xbase = (size_t)n * 262144;
  int ra[4], rb[4];
#pragma unroll
  for (int f = 0; f < 4; ++f) {
    int row = wm * 64 + f * 16 + (lane & 15);
    ra[f] = row * 64 + (((lane >> 4) ^ ((row >> 1) & 3)) << 4);
    int rowb = wn * 64 + f * 16 + (lane & 15);
    rb[f] = rowb * 64 + (((lane >> 4) ^ ((rowb >> 1) & 3)) << 4);
  }
  const int kl0 = (kbp ^ ((srow >> 1) & 3)) * 8;
  const int kl1 = (kbp ^ (((64 + srow) >> 1) & 3)) * 8;
  const unsigned short* xr0 = X + xbase + (size_t)(i0 + srow) * 512 + kl0;
  const unsigned short* xr1 = X + xbase + (size_t)(i0 + 64 + srow) * 512 + kl1;
  const unsigned short* wr0 = WT + (size_t)(d0 + srow) * 512 + kl0;
  const unsigned short* wr1 = WT + (size_t)(d0 + 64 + srow) * 512 + kl1;

#define G1_STAGE(tt, buf)                                               \
  do {                                                                  \
    char* Ab = smem + (buf) * 16384;                                    \
    char* Bb = Ab + 8192;                                               \
    const int kc_ = (tt) * 32;                                          \
    GLOAD16(xr0 + kc_, Ab + tid * 16);                                  \
    GLOAD16(xr1 + kc_, Ab + 4096 + tid * 16);                           \
    GLOAD16(wr0 + kc_, Bb + tid * 16);                                  \
    GLOAD16(wr1 + kc_, Bb + 4096 + tid * 16);                           \
  } while (0)

  G1_STAGE(0, 0);
  G1_STAGE(1, 1);
  int cur = 0;
  for (int t = 0; t < 16; ++t) {
    if (t < 15) asm volatile("s_waitcnt vmcnt(4)" ::: "memory");
    else        asm volatile("s_waitcnt vmcnt(0)" ::: "memory");
    __builtin_amdgcn_s_barrier();
    if (t < 14) {
      int nb = cur == 0 ? 2 : (cur == 1 ? 0 : 1);
      G1_STAGE(t + 2, nb);
    }
    char* Ac = smem + cur * 16384;
    char* Bc = Ac + 8192;
    short8 a[4], b[4];
#pragma unroll
    for (int f = 0; f < 4; ++f) a[f] = *(const short8*)(Ac + ra[f]);
#pragma unroll
    for (int f = 0; f < 4; ++f) b[f] = *(const short8*)(Bc + rb[f]);
#pragma unroll
    for (int mf = 0; mf < 4; ++mf)
#pragma unroll
      for (int nf = 0; nf < 4; ++nf)
        acc[mf][nf] = __builtin_amdgcn_mfma_f32_16x16x32_bf16(a[mf], b[nf], acc[mf][nf], 0, 0, 0);
    asm volatile("s_waitcnt lgkmcnt(0)" ::: "memory");
    __builtin_amdgcn_sched_barrier(0);
    __builtin_amdgcn_s_barrier();
    cur = cur == 2 ? 0 : cur + 1;
  }
#undef G1_STAGE
  unsigned short (*Ct)[136] = (unsigned short (*)[136])smem;
#pragma unroll
  for (int mf = 0; mf < 4; ++mf)
#pragma unroll
    for (int nf = 0; nf < 4; ++nf) {
      f32x4 vv = acc[mf][nf];
      int dl = wn * 64 + nf * 16 + (lane & 15);
      int il = wm * 64 + mf * 16 + ((lane >> 4) << 2);
      ushort4 pk;
      pk.x = f2bf(vv.x); pk.y = f2bf(vv.y); pk.z = f2bf(vv.z); pk.w = f2bf(vv.w);
      *(ushort4*)&Ct[dl][il] = pk;
    }
  __syncthreads();
  const size_t obase = xbase + (size_t)d0 * 512 + i0;
#pragma unroll
  for (int q = 0; q < 8; ++q) {
    int f = q * 2048 + tid * 8;
    int dl = f >> 7, il = f & 127;
    *(uint4*)&h2T[obase + (size_t)dl * 512 + il] = *(const uint4*)&Ct[dl][il];
  }
}

// ---------- fused masked softmax + transpose (512 thr / 8 waves, 32 rows) ----------
__global__ __launch_bounds__(512, 2) void k_smt(const int* __restrict__ adj,
                                                const float* __restrict__ left,
                                                const float* __restrict__ right,
                                                unsigned short* __restrict__ ct) {
  const int n  = blockIdx.y;
  const int i0 = blockIdx.x * 32;
  const int tid = threadIdx.x;
  const int lane = tid & 63, wid = tid >> 6;
  const int l15 = lane & 15;
  const int il  = wid * 4 + (lane >> 4);     // row 0..31
  __shared__ float rs_s[32][49];
  __shared__ float ls[3][32];
  __shared__ unsigned short tile[32][520];
  for (int idx = tid; idx < 1536; idx += 512) {
    int t = idx >> 9, j = idx & 511;
    rs_s[j & 31][t * 16 + (j >> 5)] = right[((size_t)t * 64 + n) * 512 + j];
  }
  if (tid < 96) {
    int t = tid >> 5, ii = tid & 31;
    ls[t][ii] = left[((size_t)t * 64 + n) * 512 + i0 + ii];
  }
  __syncthreads();
  const int* adjb = adj + ((size_t)(n * 512 + i0 + il)) * 512;
  int4 A[4], B[4];
#pragma unroll
  for (int q = 0; q < 4; ++q) {
    const int* p = adjb + q * 128 + l15 * 8;
    A[q] = *(const int4*)p;
    B[q] = *(const int4*)(p + 4);
  }
  const float l0 = ls[0][il], l1 = ls[1][il], l2 = ls[2][il];
  const int base0 = ((l15 & 3) * 8) * 49 + (l15 >> 2);
  const float* rsf = (const float*)rs_s;
  float s[4][8];
  float mloc = -3.0e38f;
#pragma unroll
  for (int q = 0; q < 4; ++q) {
    int tv[8] = {A[q].x, A[q].y, A[q].z, A[q].w, B[q].x, B[q].y, B[q].z, B[q].w};
#pragma unroll
    for (int x = 0; x < 8; ++x) {
      int t = tv[x];
      int tt = (t > 0) ? (t - 1) : 0;
      float lv = (t >= 2) ? ((t == 3) ? l2 : l1) : l0;
      float r = rsf[base0 + tt * 16 + (x * 49 + q * 4)];
      float sv = lv + r;
      sv = (sv >= 0.f) ? sv : 0.2f * sv;
      sv = (t == 0) ? -9.0e15f : sv;
      s[q][x] = sv;
      mloc = fmaxf(mloc, sv);
    }
  }
  float z = 0.f;
#pragma unroll
  for (int q = 0; q < 4; ++q)
#pragma unroll
    for (int x = 0; x < 8; ++x) {
      float e = __expf(s[q][x] - mloc);
      s[q][x] = e;
      z += e;
    }
  float m = mloc;
#pragma unroll
  for (int k = 1; k <= 8; k <<= 1) {
    float mo = __shfl_xor(m, k);
    float zo = __shfl_xor(z, k);
    float mn = fmaxf(m, mo);
    z = z * __expf(m - mn) + zo * __expf(mo - mn);
    m = mn;
  }
  const float factor = __expf(mloc - m) / z;
#pragma unroll
  for (int q = 0; q < 4; ++q) {
    uint4 pk;
    pk.x = ((unsigned)f2bf(s[q][1] * factor) << 16) | f2bf(s[q][0] * factor);
    pk.y = ((unsigned)f2bf(s[q][3] * factor) << 16) | f2bf(s[q][2] * factor);
    pk.z = ((unsigned)f2bf(s[q][5] * factor) << 16) | f2bf(s[q][4] * factor);
    pk.w = ((unsigned)f2bf(s[q][7] * factor) << 16) | f2bf(s[q][6] * factor);
    *(uint4*)&tile[il][q * 128 + l15 * 8] = pk;
  }
  __syncthreads();
  unsigned short* ob = ct + (size_t)n * 262144 + i0;
#pragma unroll
  for (int pass = 0; pass < 4; ++pass) {
    int j = pass * 128 + (tid >> 2);
    int i8 = (tid & 3) * 8;
    uint4 o;
    o.x = (unsigned)tile[i8 + 0][j] | ((unsigned)tile[i8 + 1][j] << 16);
    o.y = (unsigned)tile[i8 + 2][j] | ((unsigned)tile[i8 + 3][j] << 16);
    o.z = (unsigned)tile[i8 + 4][j] | ((unsigned)tile[i8 + 5][j] << 16);
    o.w = (unsigned)tile[i8 + 6][j] | ((unsigned)tile[i8 + 7][j] << 16);
    *(uint4*)&ob[(size_t)j * 512 + i8] = o;
  }
}

// ---------- MFMA GEMM2: out[n][j][d] = coefsT[n] @ h2T[n]^T ; 3-buffer ring ----------
__global__ __launch_bounds__(256) void k_gemm2(const unsigned short* __restrict__ CT,
                                               const unsigned short* __restrict__ H2T,
                                               float* __restrict__ out) {
  __shared__ __attribute__((aligned(16))) char smem[49152];
  const int s = blockIdx.x;
  const int n  = ((s >> 7) << 3) | (s & 7);
  const int jj = (s >> 3) & 15;
  const int j0 = (jj >> 2) * 128;
  const int d0 = (jj & 3) * 128;
  const int tid = threadIdx.x;
  const int lane = tid & 63, w = tid >> 6;
  const int wm = w >> 1, wn = w & 1;
  const int srow = tid >> 2;
  const int kbp  = tid & 3;
  f32x4 acc[4][4];
#pragma unroll
  for (int a = 0; a < 4; ++a)
#pragma unroll
    for (int b = 0; b < 4; ++b) acc[a][b] = (f32x4){0.f, 0.f, 0.f, 0.f};

  const size_t base = (size_t)n * 262144;
  int ra[4], rb[4];
#pragma unroll
  for (int f = 0; f < 4; ++f) {
    int row = wm * 64 + f * 16 + (lane & 15);
    ra[f] = row * 64 + (((lane >> 4) ^ ((row >> 1) & 3)) << 4);
    int rowb = wn * 64 + f * 16 + (lane & 15);
    rb[f] = rowb * 64 + (((lane >> 4) ^ ((rowb >> 1) & 3)) << 4);
  }
  const int kl0 = (kbp ^ ((srow >> 1) & 3)) * 8;
  const int kl1 = (kbp ^ (((64 + srow) >> 1) & 3)) * 8;
  const unsigned short* cr0 = CT + base + (size_t)(j0 + srow) * 512 + kl0;
  const unsigned short* cr1 = CT + base + (size_t)(j0 + 64 + srow) * 512 + kl1;
  const unsigned short* hr0 = H2T + base + (size_t)(d0 + srow) * 512 + kl0;
  const unsigned short* hr1 = H2T + base + (size_t)(d0 + 64 + srow) * 512 + kl1;

#define G2_STAGE(tt, buf)                                               \
  do {                                                                  \
    char* Ab = smem + (buf) * 16384;                                    \
    char* Bb = Ab + 8192;                                               \
    const int kc_ = (tt) * 32;                                          \
    GLOAD16(cr0 + kc_, Ab + tid * 16);                                  \
    GLOAD16(cr1 + kc_, Ab + 4096 + tid * 16);                           \
    GLOAD16(hr0 + kc_, Bb + tid * 16);                                  \
    GLOAD16(hr1 + kc_, Bb + 4096 + tid * 16);                           \
  } while (0)

  G2_STAGE(0, 0);
  G2_STAGE(1, 1);
  int cur = 0;
  for (int t = 0; t < 16; ++t) {
    if (t < 15) asm volatile("s_waitcnt vmcnt(4)" ::: "memory");
    else        asm volatile("s_waitcnt vmcnt(0)" ::: "memory");
    __builtin_amdgcn_s_barrier();
    if (t < 14) {
      int nb = cur == 0 ? 2 : (cur == 1 ? 0 : 1);
      G2_STAGE(t + 2, nb);
    }
    char* Ac = smem + cur * 16384;
    char* Bc = Ac + 8192;
    short8 a[4], b[4];
#pragma unroll
    for (int f = 0; f < 4; ++f) a[f] = *(const short8*)(Ac + ra[f]);
#pragma unroll
    for (int f = 0; f < 4; ++f) b[f] = *(const short8*)(Bc + rb[f]);
#pragma unroll
    for (int mf = 0; mf < 4; ++mf)
#pragma unroll
      for (int nf = 0; nf < 4; ++nf)
        acc[mf][nf] = __builtin_amdgcn_mfma_f32_16x16x32_bf16(a[mf], b[nf], acc[mf][nf], 0, 0, 0);
    asm volatile("s_waitcnt lgkmcnt(0)" ::: "memory");
    __builtin_amdgcn_sched_barrier(0);
    __builtin_amdgcn_s_barrier();
    cur = cur == 2 ? 0 : cur + 1;
  }
#undef G2_STAGE
  const int jb = j0 + wm * 64 + (lane >> 4) * 4;
  const int db = d0 + wn * 64 + (lane & 15);
#pragma unroll
  for (int mf = 0; mf < 4; ++mf)
#pragma unroll
    for (int nf = 0; nf < 4; ++nf) {
      f32x4 vv = acc[mf][nf];
      float* op = out + base + (size_t)(jb + mf * 16) * 512 + db + nf * 16;
      op[0]    = vv.x;
      op[512]  = vv.y;
      op[1024] = vv.z;
      op[1536] = vv.w;
    }
}

extern "C" void kernel_launch(void* const* d_in, const int* in_sizes, int n_in,
                              void* d_out, int out_size, void* d_ws, size_t ws_size,
                              hipStream_t stream) {
  const float* input  = (const float*)d_in[0];
  const int*   adj    = (const int*)d_in[1];
  const float* query  = (const float*)d_in[3];
  const float* W_type = (const float*)d_in[4];
  const float* a_type = (const float*)d_in[5];
  const float* W1     = (const float*)d_in[6];
  const float* W2     = (const float*)d_in[7];
  float* out = (float*)d_out;

  char* ws = (char*)d_ws;
  float* galT  = (float*)(ws);                              //  393,216 B
  float* garT  = (float*)(ws + 393216);                     //  393,216 B
  unsigned short* uvbf = (unsigned short*)(ws + 786432);    //  393,216 B
  float* left  = (float*)(ws + 1179648);                    //  393,216 B
  float* right = (float*)(ws + 1572864);                    //  393,216 B
  unsigned short* Xbf = (unsigned short*)(ws + 2359296);    // 33,554,432 B (reused as coefsT)
  unsigned short* h2T = (unsigned short*)(ws + 35913728);   // 33,554,432 B
  // partials alias h2T's region: all dead before k_gemm1 writes h2T
  float* rpart = (float*)(ws + 35913728);                   //  3,145,728 B
  float* gpart = (float*)(ws + 39059456);                   //  6,291,456 B
  float* upart = (float*)(ws + 45350912);                   //  3,145,728 B
  float* vpart = (float*)(ws + 48496640);                   //  3,145,728 B
  unsigned short* WT  = (unsigned short*)(ws + 69468160);   //    524,288 B
  // total ws use: 69,992,448 B
  unsigned short* coefsT = Xbf;   // Xbf dead after k_gemm1; k_smt writes it, k_gemm2 reads it

  k_wtg1    <<<dim3(256),       256, 0, stream>>>(W_type + (size_t)2 * 262144, WT, query, W1, rpart);
  k_gate2   <<<dim3(16, 8, 3),  256, 0, stream>>>(rpart, W2, gpart);
  k_gate_fin<<<dim3(256, 3),    256, 0, stream>>>(gpart, a_type, galT, garT);
  k_uvp     <<<dim3(8, 8, 3),   256, 0, stream>>>(W_type, galT, garT, upart, vpart);
  k_uvsum   <<<dim3(64),        256, 0, stream>>>(upart, vpart, uvbf);
  k_lrm     <<<dim3(8, 64),     256, 0, stream>>>(input, uvbf, left, right, Xbf);
  k_gemm1   <<<dim3(1024),      256, 0, stream>>>(Xbf, WT, h2T);
  k_smt     <<<dim3(16, 64),    512, 0, stream>>>(adj, left, right, coefsT);
  k_gemm2   <<<dim3(1024),      256, 0, stream>>>(coefsT, h2T, out);
}